// Round 7
// baseline (669.833 us; speedup 1.0000x reference)
//
#include <hip/hip_runtime.h>
#include <stdint.h>

typedef _Float16 f16x8 __attribute__((ext_vector_type(8)));
typedef _Float16 f16x4 __attribute__((ext_vector_type(4)));
typedef float    f32x4 __attribute__((ext_vector_type(4)));

__device__ __forceinline__ void load16_lds(const _Float16* g, _Float16* l) {
    __builtin_amdgcn_global_load_lds(
        (const __attribute__((address_space(1))) void*)g,
        (__attribute__((address_space(3))) void*)l, 16, 0, 0);
}

// ---------------------------------------------------------------- casts

__global__ void k_cast(const float* __restrict__ in, _Float16* __restrict__ out, int n) {
    int i = (blockIdx.x * 256 + threadIdx.x) * 4;
    if (i < n) {
        float4 v = *reinterpret_cast<const float4*>(in + i);
        f16x4 o = { (_Float16)v.x, (_Float16)v.y, (_Float16)v.z, (_Float16)v.w };
        *reinterpret_cast<f16x4*>(out + i) = o;
    }
}

// edw[e][dm][mi] (f32) -> dwc[dm][e*128+mi] (f16)
__global__ void k_cast_dw(const float* __restrict__ edw, _Float16* __restrict__ dwc) {
    int t = blockIdx.x * 256 + threadIdx.x;
    int mi4 = (t & 31) * 4;
    int dm = (t >> 5) & 2047;
    int e = t >> 16;
    float4 v = *reinterpret_cast<const float4*>(edw + (((size_t)e * 2048 + dm) << 7) + mi4);
    f16x4 o = { (_Float16)v.x, (_Float16)v.y, (_Float16)v.z, (_Float16)v.w };
    *reinterpret_cast<f16x4*>(dwc + ((size_t)dm << 11) + e * 128 + mi4) = o;
}

// egw/euw[e][mi][k] -> guw[e*256 + half*128 + mi][k] (f16)
__global__ __launch_bounds__(256) void k_cast_guw(
    const float* __restrict__ eg, const float* __restrict__ eu,
    _Float16* __restrict__ out)
{
    const int row = blockIdx.x;                // 0..4095
    const int e = row >> 8, rem = row & 255, half = rem >> 7, mi = rem & 127;
    const float* src = (half ? eu : eg) + ((size_t)(e * 128 + mi)) * 2048;
    const int c = threadIdx.x * 8;
    float4 v0 = *reinterpret_cast<const float4*>(src + c);
    float4 v1 = *reinterpret_cast<const float4*>(src + c + 4);
    f16x8 o = { (_Float16)v0.x,(_Float16)v0.y,(_Float16)v0.z,(_Float16)v0.w,
                (_Float16)v1.x,(_Float16)v1.y,(_Float16)v1.z,(_Float16)v1.w };
    *reinterpret_cast<f16x8*>(out + (size_t)row * 2048 + c) = o;
}

// ---------------------------------------------------------------- rmsnorm
__global__ __launch_bounds__(256) void k_rmsnorm(
    const float* __restrict__ x, const float* __restrict__ w,
    _Float16* __restrict__ oh, float* __restrict__ of)
{
    const int row = blockIdx.x, tid = threadIdx.x;
    const float* xr = x + (size_t)row * 2048;
    float4 a = *reinterpret_cast<const float4*>(xr + tid * 8);
    float4 b = *reinterpret_cast<const float4*>(xr + tid * 8 + 4);
    float ss = a.x*a.x + a.y*a.y + a.z*a.z + a.w*a.w
             + b.x*b.x + b.y*b.y + b.z*b.z + b.w*b.w;
    #pragma unroll
    for (int m = 1; m < 64; m <<= 1) ss += __shfl_xor(ss, m);
    __shared__ float red[4];
    if ((tid & 63) == 0) red[tid >> 6] = ss;
    __syncthreads();
    float tot = red[0] + red[1] + red[2] + red[3];
    float r = rsqrtf(tot * (1.f / 2048.f) + 1e-6f);
    float4 wa = *reinterpret_cast<const float4*>(w + tid * 8);
    float4 wb = *reinterpret_cast<const float4*>(w + tid * 8 + 4);
    float o0 = a.x*r*wa.x, o1 = a.y*r*wa.y, o2 = a.z*r*wa.z, o3 = a.w*r*wa.w;
    float o4 = b.x*r*wb.x, o5 = b.y*r*wb.y, o6 = b.z*r*wb.z, o7 = b.w*r*wb.w;
    f16x8 hv = { (_Float16)o0,(_Float16)o1,(_Float16)o2,(_Float16)o3,
                 (_Float16)o4,(_Float16)o5,(_Float16)o6,(_Float16)o7 };
    *reinterpret_cast<f16x8*>(oh + (size_t)row * 2048 + tid * 8) = hv;
    if (of) {
        float4 f0 = { o0, o1, o2, o3 }, f1 = { o4, o5, o6, o7 };
        *reinterpret_cast<float4*>(of + (size_t)row * 2048 + tid * 8) = f0;
        *reinterpret_cast<float4*>(of + (size_t)row * 2048 + tid * 8 + 4) = f1;
    }
}

// ---------------------------------------------------------------- GEMM 128x128 tile
// (512-block grids: O-proj, down).  3-buf counted-vmcnt, swizzled.
__global__ __launch_bounds__(256) void k_gemm(
    const _Float16* __restrict__ A, int lda,
    const _Float16* __restrict__ W, int ldw,
    float* __restrict__ Cf, _Float16* __restrict__ Ch, int ldc,
    const float* __restrict__ resid, int K)
{
    __shared__ __align__(16) _Float16 As[3][128][32];
    __shared__ __align__(16) _Float16 Ws[3][128][32];
    const int r0 = blockIdx.x * 128, c0 = blockIdx.y * 128;
    const int tid = threadIdx.x, lane = tid & 63, wid = tid >> 6;
    const int wr = wid >> 1, wc = wid & 1;
    const int sr = lane >> 2;
    const int scs = ((lane & 3) ^ ((lane >> 3) & 3)) * 8;
    const int fr = lane & 15;
    const int rks = (((lane >> 4) ^ ((fr >> 1) & 3))) * 8;
    const f32x4 z4 = { 0.f, 0.f, 0.f, 0.f };
    f32x4 acc[4][4];
    #pragma unroll
    for (int i = 0; i < 4; i++)
        #pragma unroll
        for (int j = 0; j < 4; j++) acc[i][j] = z4;

    auto stage = [&](int bf, int k0) {
        #pragma unroll
        for (int i = 0; i < 2; i++) {
            int chunk = wid * 2 + i;
            load16_lds(A + (size_t)(r0 + chunk * 16 + sr) * lda + k0 + scs, &As[bf][chunk * 16][0]);
            load16_lds(W + (size_t)(c0 + chunk * 16 + sr) * ldw + k0 + scs, &Ws[bf][chunk * 16][0]);
        }
    };

    const int nt = K >> 5;
    stage(0, 0);
    if (nt > 1) stage(1, 32);
    int cur = 0;
    for (int t = 0; t < nt; t++) {
        if (t < nt - 1) asm volatile("s_waitcnt vmcnt(4)" ::: "memory");
        else            asm volatile("s_waitcnt vmcnt(0)" ::: "memory");
        __builtin_amdgcn_s_barrier();
        f16x8 af[4], bf4[4];
        #pragma unroll
        for (int i = 0; i < 4; i++)
            af[i] = *reinterpret_cast<const f16x8*>(&As[cur][wr * 64 + i * 16 + fr][rks]);
        #pragma unroll
        for (int j = 0; j < 4; j++)
            bf4[j] = *reinterpret_cast<const f16x8*>(&Ws[cur][wc * 64 + j * 16 + fr][rks]);
        if (t + 2 < nt) stage((t + 2) % 3, (t + 2) << 5);
        #pragma unroll
        for (int i = 0; i < 4; i++)
            #pragma unroll
            for (int j = 0; j < 4; j++)
                acc[i][j] = __builtin_amdgcn_mfma_f32_16x16x32_f16(af[i], bf4[j], acc[i][j], 0, 0, 0);
        cur = (cur + 1) % 3;
    }
    #pragma unroll
    for (int i = 0; i < 4; i++) {
        const int rowb = r0 + wr * 64 + i * 16 + (lane >> 4) * 4;
        #pragma unroll
        for (int j = 0; j < 4; j++) {
            const int col = c0 + wc * 64 + j * 16 + fr;
            #pragma unroll
            for (int r = 0; r < 4; r++) {
                size_t idx = (size_t)(rowb + r) * ldc + col;
                float v = acc[i][j][r];
                if (resid) v += resid[idx];
                if (Ch) Ch[idx] = (_Float16)v;
                else    Cf[idx] = v;
            }
        }
    }
}

// ---------------------------------------------------------------- GEMM 128x256 tile
// 4 waves, wave-tile 128x64 (43.7 FLOP/LDS-byte). 2-buf, stage-after-barrier.
// f16 output. Used for QKV (32x20) and gate/up (32x16).
__global__ __launch_bounds__(256) void k_gemm2(
    const _Float16* __restrict__ A, int lda,
    const _Float16* __restrict__ W, int ldw,
    _Float16* __restrict__ Ch, int ldc, int K)
{
    __shared__ __align__(16) _Float16 As[2][128][32];
    __shared__ __align__(16) _Float16 Ws[2][256][32];
    const int r0 = blockIdx.x * 128, c0 = blockIdx.y * 256;
    const int tid = threadIdx.x, lane = tid & 63, wid = tid >> 6;
    const int sr4 = lane >> 2;
    const int scs = ((lane & 3) ^ ((lane >> 3) & 3)) * 8;
    const int fr = lane & 15;
    const int rks = (((lane >> 4) ^ ((fr >> 1) & 3))) * 8;
    const f32x4 z4 = { 0.f, 0.f, 0.f, 0.f };
    f32x4 acc[8][4];
    #pragma unroll
    for (int i = 0; i < 8; i++)
        #pragma unroll
        for (int j = 0; j < 4; j++) acc[i][j] = z4;

    auto stage = [&](int bf, int k0) {
        #pragma unroll
        for (int i = 0; i < 2; i++) {
            int rowb = wid * 32 + i * 16;
            load16_lds(A + (size_t)(r0 + rowb + sr4) * lda + k0 + scs, &As[bf][rowb][0]);
        }
        #pragma unroll
        for (int i = 0; i < 4; i++) {
            int rowb = wid * 64 + i * 16;
            load16_lds(W + (size_t)(c0 + rowb + sr4) * ldw + k0 + scs, &Ws[bf][rowb][0]);
        }
    };

    const int nt = K >> 5;
    stage(0, 0);
    int cur = 0;
    for (int t = 0; t < nt; t++) {
        asm volatile("s_waitcnt vmcnt(0)" ::: "memory");
        __builtin_amdgcn_s_barrier();
        if (t + 1 < nt) stage(cur ^ 1, (t + 1) << 5);
        f16x8 af[8], bf4[4];
        #pragma unroll
        for (int i = 0; i < 8; i++)
            af[i] = *reinterpret_cast<const f16x8*>(&As[cur][i * 16 + fr][rks]);
        #pragma unroll
        for (int j = 0; j < 4; j++)
            bf4[j] = *reinterpret_cast<const f16x8*>(&Ws[cur][wid * 64 + j * 16 + fr][rks]);
        #pragma unroll
        for (int i = 0; i < 8; i++)
            #pragma unroll
            for (int j = 0; j < 4; j++)
                acc[i][j] = __builtin_amdgcn_mfma_f32_16x16x32_f16(af[i], bf4[j], acc[i][j], 0, 0, 0);
        cur ^= 1;
    }
    #pragma unroll
    for (int i = 0; i < 8; i++) {
        const int rowb = r0 + i * 16 + (lane >> 4) * 4;
        #pragma unroll
        for (int j = 0; j < 4; j++) {
            const int col = c0 + wid * 64 + j * 16 + fr;
            #pragma unroll
            for (int r = 0; r < 4; r++)
                Ch[(size_t)(rowb + r) * ldc + col] = (_Float16)acc[i][j][r];
        }
    }
}

// ---------------------------------------------------------------- gate/up combine
// ab[tok][e*128+mi] = wdense[e][tok] * silu(g) * u, g/u from gucat[tok][e*256+...]
__global__ __launch_bounds__(256) void k_gu_comb(
    const _Float16* __restrict__ gucat, const float* __restrict__ wdense,
    _Float16* __restrict__ ab)
{
    const int tok = blockIdx.x;
    const int idx = threadIdx.x;          // e = idx>>4, group = idx&15
    const int e = idx >> 4, mi8 = (idx & 15) * 8;
    const _Float16* gp = gucat + (size_t)tok * 4096 + e * 256 + mi8;
    f16x8 gv = *reinterpret_cast<const f16x8*>(gp);
    f16x8 uv = *reinterpret_cast<const f16x8*>(gp + 128);
    float wv = wdense[(size_t)e * 4096 + tok];
    f16x8 o;
    #pragma unroll
    for (int j = 0; j < 8; j++) {
        float g = (float)gv[j], u = (float)uv[j];
        float sil = g / (1.f + __expf(-g));
        o[j] = (_Float16)(sil * u * wv);
    }
    *reinterpret_cast<f16x8*>(ab + (size_t)tok * 2048 + e * 128 + mi8) = o;
}

// ------------------------------------------- per-head RMSNorm + RoPE (wave-per-head)
__global__ __launch_bounds__(256) void k_qkv_post(
    const _Float16* __restrict__ qkv,
    const float* __restrict__ cosb, const float* __restrict__ sinb,
    const float* __restrict__ qn_w, const float* __restrict__ kn_w,
    _Float16* __restrict__ qh, _Float16* __restrict__ kh)
{
    const int tok = blockIdx.x;
    const int u = blockIdx.y * 4 + (threadIdx.x >> 6);
    const int lane = threadIdx.x & 63;
    const int b = tok >> 10, l = tok & 1023;
    const float c0 = cosb[(size_t)tok * 128 + lane];
    const float c1 = cosb[(size_t)tok * 128 + lane + 64];
    const float s0 = sinb[(size_t)tok * 128 + lane];
    const float s1 = sinb[(size_t)tok * 128 + lane + 64];
    if (u < 32) {
        const _Float16* base = qkv + (size_t)tok * 5120 + u * 128;
        float v0 = (float)base[lane], v1 = (float)base[lane + 64];
        float ss = v0 * v0 + v1 * v1;
        #pragma unroll
        for (int m = 1; m < 64; m <<= 1) ss += __shfl_xor(ss, m);
        float rms = rsqrtf(ss * (1.f / 128.f) + 1e-6f);
        float n0 = v0 * rms * qn_w[lane], n1 = v1 * rms * qn_w[lane + 64];
        _Float16* o = qh + (size_t)tok * 4096 + u * 128;
        o[lane]      = (_Float16)(c0 * n0 - s0 * n1);
        o[lane + 64] = (_Float16)(c1 * n1 + s1 * n0);
    } else {
        const int kvh = u - 32;
        const _Float16* base = qkv + (size_t)tok * 5120 + 4096 + kvh * 128;
        float v0 = (float)base[lane], v1 = (float)base[lane + 64];
        float ss = v0 * v0 + v1 * v1;
        #pragma unroll
        for (int m = 1; m < 64; m <<= 1) ss += __shfl_xor(ss, m);
        float rms = rsqrtf(ss * (1.f / 128.f) + 1e-6f);
        float n0 = v0 * rms * kn_w[lane], n1 = v1 * rms * kn_w[lane + 64];
        _Float16* o = kh + (((size_t)(b * 4 + kvh)) * 1024 + l) * 128;
        o[lane]      = (_Float16)(c0 * n0 - s0 * n1);
        o[lane + 64] = (_Float16)(c1 * n1 + s1 * n0);
    }
}

// ---------------------------------------------------------------- V transpose
__global__ __launch_bounds__(256) void k_vt(
    const _Float16* __restrict__ qkv, _Float16* __restrict__ vth)
{
    const int bkv = blockIdx.x;
    const int b = bkv >> 2, kv = bkv & 3;
    const int l0 = blockIdx.y * 64, d0 = blockIdx.z * 64;
    __shared__ _Float16 T[64][72];
    const int t = threadIdx.x;
    const int r = t >> 3, c8 = (t & 7) * 8;
    #pragma unroll
    for (int rr = 0; rr < 2; rr++) {
        int l = l0 + r + rr * 32;
        *reinterpret_cast<f16x8*>(&T[r + rr * 32][c8]) =
            *reinterpret_cast<const f16x8*>(
                qkv + (size_t)(b * 1024 + l) * 5120 + 4608 + kv * 128 + d0 + c8);
    }
    __syncthreads();
    #pragma unroll
    for (int rr = 0; rr < 2; rr++) {
        int d = d0 + r + rr * 32;
        f16x8 v;
        #pragma unroll
        for (int j = 0; j < 8; j++) v[j] = T[c8 + j][r + rr * 32];
        *reinterpret_cast<f16x8*>(vth + ((size_t)(bkv * 128 + d)) * 1024 + l0 + c8) = v;
    }
}

// ---------------------------------------------------------------- attention
__global__ __launch_bounds__(256) void k_attn(
    const _Float16* __restrict__ qh, const _Float16* __restrict__ kh,
    const _Float16* __restrict__ vth, _Float16* __restrict__ oh)
{
    const int bh = blockIdx.x;
    const int g = 15 - blockIdx.y;
    const int b = bh >> 5, h = bh & 31, kv = h >> 3;
    const int tid = threadIdx.x, lane = tid & 63, wid = tid >> 6;
    const int fr = lane & 15, fg = lane >> 4;
    const int q0w = g * 64 + wid * 16;

    __shared__ __align__(16) _Float16 Ks[64][128];
    __shared__ __align__(16) _Float16 Vs[128][64];
    __shared__ __align__(16) _Float16 Ps[4][16][72];

    const _Float16* kb = kh + ((size_t)(b * 4 + kv)) * 1024 * 128;
    const _Float16* vb = vth + ((size_t)(b * 4 + kv)) * 128 * 1024;

    f16x8 aq[4];
    {
        const _Float16* qbase = qh + ((size_t)(b * 1024 + q0w + fr)) * 4096 + h * 128;
        #pragma unroll
        for (int kk = 0; kk < 4; kk++)
            aq[kk] = *reinterpret_cast<const f16x8*>(qbase + kk * 32 + fg * 8);
    }

    float m_r[4] = { -1e30f, -1e30f, -1e30f, -1e30f };
    float l_r[4] = { 0.f, 0.f, 0.f, 0.f };
    const f32x4 z4 = { 0.f, 0.f, 0.f, 0.f };
    f32x4 oacc[8];
    #pragma unroll
    for (int dj = 0; dj < 8; dj++) oacc[dj] = z4;

    const int ntiles = g + 1;
    for (int kt = 0; kt < ntiles; kt++) {
        const int key0 = kt * 64;
        #pragma unroll
        for (int i = 0; i < 4; i++) {
            int rr = 16 * wid + 4 * i + (lane >> 4);
            int c16 = (lane & 15) ^ (rr & 7);
            load16_lds(kb + (size_t)(key0 + rr) * 128 + c16 * 8,
                       &Ks[0][0] + (16 * wid + 4 * i) * 128);
        }
        #pragma unroll
        for (int i = 0; i < 4; i++) {
            int rr = 32 * wid + 8 * i + (lane >> 3);
            int c16 = (lane & 7) ^ (rr & 7);
            load16_lds(vb + (size_t)rr * 1024 + key0 + c16 * 8,
                       &Vs[0][0] + (32 * wid + 8 * i) * 64);
        }
        __syncthreads();

        f32x4 sc[4];
        #pragma unroll
        for (int j = 0; j < 4; j++) sc[j] = z4;
        #pragma unroll
        for (int j = 0; j < 4; j++) {
            #pragma unroll
            for (int kk = 0; kk < 4; kk++) {
                f16x8 bk = *reinterpret_cast<const f16x8*>(
                    &Ks[0][0] + (j * 16 + fr) * 128 + (((kk * 4 + fg) ^ (fr & 7)) * 8));
                sc[j] = __builtin_amdgcn_mfma_f32_16x16x32_f16(aq[kk], bk, sc[j], 0, 0, 0);
            }
        }

        const bool lastt = (kt == ntiles - 1);
        float pmax[4] = { -1e30f, -1e30f, -1e30f, -1e30f };
        #pragma unroll
        for (int j = 0; j < 4; j++) {
            const int key = key0 + j * 16 + fr;
            #pragma unroll
            for (int r = 0; r < 4; r++) {
                float v = sc[j][r] * 0.08838834764831845f;
                if (lastt && key > q0w + fg * 4 + r) v = -1e30f;
                sc[j][r] = v;
                pmax[r] = fmaxf(pmax[r], v);
            }
        }
        #pragma unroll
        for (int m = 1; m < 16; m <<= 1)
            #pragma unroll
            for (int r = 0; r < 4; r++) pmax[r] = fmaxf(pmax[r], __shfl_xor(pmax[r], m));
        float alpha[4];
        #pragma unroll
        for (int r = 0; r < 4; r++) {
            float mn = fmaxf(m_r[r], pmax[r]);
            alpha[r] = __expf(m_r[r] - mn);
            m_r[r] = mn;
        }
        float rs[4] = { 0.f, 0.f, 0.f, 0.f };
        #pragma unroll
        for (int j = 0; j < 4; j++)
            #pragma unroll
            for (int r = 0; r < 4; r++) {
                float p = __expf(sc[j][r] - m_r[r]);
                sc[j][r] = p;
                rs[r] += p;
            }
        #pragma unroll
        for (int m = 1; m < 16; m <<= 1)
            #pragma unroll
            for (int r = 0; r < 4; r++) rs[r] += __shfl_xor(rs[r], m);
        #pragma unroll
        for (int r = 0; r < 4; r++) l_r[r] = l_r[r] * alpha[r] + rs[r];
        #pragma unroll
        for (int dj = 0; dj < 8; dj++)
            #pragma unroll
            for (int r = 0; r < 4; r++) oacc[dj][r] *= alpha[r];

        #pragma unroll
        for (int j = 0; j < 4; j++)
            #pragma unroll
            for (int r = 0; r < 4; r++)
                Ps[wid][fg * 4 + r][j * 16 + fr] = (_Float16)sc[j][r];

        #pragma unroll
        for (int ks = 0; ks < 2; ks++) {
            f16x8 ap = *reinterpret_cast<const f16x8*>(&Ps[wid][fr][ks * 32 + fg * 8]);
            #pragma unroll
            for (int dj = 0; dj < 8; dj++) {
                f16x8 bv = *reinterpret_cast<const f16x8*>(
                    &Vs[0][0] + (dj * 16 + fr) * 64 + (((ks * 4 + fg) ^ (fr & 7)) * 8));
                oacc[dj] = __builtin_amdgcn_mfma_f32_16x16x32_f16(ap, bv, oacc[dj], 0, 0, 0);
            }
        }
        __syncthreads();
    }

    float inv[4];
    #pragma unroll
    for (int r = 0; r < 4; r++) inv[r] = 1.f / l_r[r];
    #pragma unroll
    for (int dj = 0; dj < 8; dj++)
        #pragma unroll
        for (int r = 0; r < 4; r++)
            oh[((size_t)(b * 1024 + q0w + fg * 4 + r)) * 4096 + h * 128 + dj * 16 + fr] =
                (_Float16)(oacc[dj][r] * inv[r]);
}

// ---------------------------------------------------------------- router
__global__ __launch_bounds__(256) void k_router(
    const float* __restrict__ hm, const float* __restrict__ rw,
    float* __restrict__ wdense)
{
    const int tok = blockIdx.x * 4 + (threadIdx.x >> 6);
    const int lane = threadIdx.x & 63;
    __shared__ float lg[4][16];
    const float* hr = hm + (size_t)tok * 2048;
    for (int e = 0; e < 16; e++) {
        float acc = 0.f;
        #pragma unroll
        for (int i = 0; i < 32; i++) acc += hr[i * 64 + lane] * rw[(size_t)e * 2048 + i * 64 + lane];
        #pragma unroll
        for (int m = 1; m < 64; m <<= 1) acc += __shfl_xor(acc, m);
        if (lane == 0) lg[threadIdx.x >> 6][e] = acc;
    }
    __syncthreads();
    if (lane == 0) {
        float* l = lg[threadIdx.x >> 6];
        float mx = l[0];
        for (int e = 1; e < 16; e++) mx = fmaxf(mx, l[e]);
        float p[16]; float sum = 0.f;
        for (int e = 0; e < 16; e++) { p[e] = expf(l[e] - mx); sum += p[e]; }
        for (int e = 0; e < 16; e++) p[e] /= sum;
        bool sel[16]; for (int e = 0; e < 16; e++) sel[e] = false;
        float ssum = 0.f;
        for (int t = 0; t < 8; t++) {
            int bi = -1; float bv = -1.f;
            for (int e = 0; e < 16; e++) if (!sel[e] && p[e] > bv) { bv = p[e]; bi = e; }
            sel[bi] = true; ssum += bv;
        }
        for (int e = 0; e < 16; e++)
            wdense[(size_t)e * 4096 + tok] = sel[e] ? p[e] / ssum : 0.f;
    }
}

// ---------------------------------------------------------------- launch

extern "C" void kernel_launch(void* const* d_in, const int* in_sizes, int n_in,
                              void* d_out, int out_size, void* d_ws, size_t ws_size,
                              hipStream_t stream)
{
    const float* x        = (const float*)d_in[0];
    const float* cosb     = (const float*)d_in[1];
    const float* sinb     = (const float*)d_in[2];
    const float* nattn    = (const float*)d_in[3];
    const float* q_w      = (const float*)d_in[4];
    const float* k_w      = (const float*)d_in[5];
    const float* v_w      = (const float*)d_in[6];
    const float* qn_w     = (const float*)d_in[7];
    const float* kn_w     = (const float*)d_in[8];
    const float* o_w      = (const float*)d_in[9];
    const float* nmlp     = (const float*)d_in[10];
    const float* router_w = (const float*)d_in[11];
    const float* egw      = (const float*)d_in[12];
    const float* euw      = (const float*)d_in[13];
    const float* edw      = (const float*)d_in[14];

    char* w = (char*)d_ws;
    _Float16* qkvw_h = (_Float16*)(w + 0);          // 20.97 MB
    _Float16* ow_h   = (_Float16*)(w + 20971520);   // 16.78 MB
    _Float16* guw_h  = (_Float16*)(w + 37748736);   // 16.78 MB (interleaved g/u rows)
    _Float16* dwc_h  = (_Float16*)(w + 54525952);   //  8.39 MB
    _Float16* h_h    = (_Float16*)(w + 62914560);   // 16.78 MB (aliased hm_h)
    _Float16* hm_h   = h_h;
    float*    x2     = (float*)(w + 79691776);      // 33.55 MB
    _Float16* qkv_h  = (_Float16*)(w + 113246208);  // 41.94 MB (alias o_h, ab_h)
    _Float16* o_h    = qkv_h;
    _Float16* ab_h   = qkv_h;
    _Float16* q_h    = (_Float16*)(w + 155189248);  // 33.55 MB (alias hm_f, gucat)
    float*    hm_f   = (float*)(w + 155189248);
    _Float16* gucat  = (_Float16*)(w + 155189248);  // 33.55 MB (after router)
    _Float16* k_h    = (_Float16*)(w + 188743680);  //  4.19 MB
    _Float16* vt_h   = (_Float16*)(w + 192937984);  //  4.19 MB
    float*    wdense = (float*)(w + 197132288);     //  0.26 MB

    k_cast<<<8192, 256, 0, stream>>>(q_w, qkvw_h, 8388608);
    k_cast<<<1024, 256, 0, stream>>>(k_w, qkvw_h + (size_t)4096 * 2048, 1048576);
    k_cast<<<1024, 256, 0, stream>>>(v_w, qkvw_h + (size_t)4608 * 2048, 1048576);
    k_cast<<<8192, 256, 0, stream>>>(o_w, ow_h, 8388608);
    k_cast_guw<<<4096, 256, 0, stream>>>(egw, euw, guw_h);
    k_cast_dw<<<4096, 256, 0, stream>>>(edw, dwc_h);

    k_rmsnorm<<<4096, 256, 0, stream>>>(x, nattn, h_h, nullptr);
    // merged QKV projection (128x256 tile kernel)
    k_gemm2<<<dim3(32, 20), 256, 0, stream>>>(h_h, 2048, qkvw_h, 2048, qkv_h, 5120, 2048);
    k_qkv_post<<<dim3(4096, 9), 256, 0, stream>>>(qkv_h, cosb, sinb, qn_w, kn_w, q_h, k_h);
    k_vt<<<dim3(16, 16, 2), 256, 0, stream>>>(qkv_h, vt_h);
    k_attn<<<dim3(128, 16), 256, 0, stream>>>(q_h, k_h, vt_h, o_h);
    // O projection + residual -> x2 (f32)
    k_gemm<<<dim3(32, 16), 256, 0, stream>>>(o_h, 4096, ow_h, 4096,
                                             x2, nullptr, 2048, x, 4096);
    k_rmsnorm<<<4096, 256, 0, stream>>>(x2, nmlp, hm_h, hm_f);
    k_router<<<1024, 256, 0, stream>>>(hm_f, router_w, wdense);
    // gate/up as one GEMM -> gucat, then combine -> ab
    k_gemm2<<<dim3(32, 16), 256, 0, stream>>>(hm_h, 2048, guw_h, 2048, gucat, 4096, 2048);
    k_gu_comb<<<4096, 256, 0, stream>>>(gucat, wdense, ab_h);
    // down projection + residual -> out
    k_gemm<<<dim3(32, 16), 256, 0, stream>>>(ab_h, 2048, dwc_h, 2048,
                                             (float*)d_out, nullptr, 2048, x2, 2048);

    (void)in_sizes; (void)n_in; (void)out_size; (void)ws_size;
}

// Round 8
// 598.576 us; speedup vs baseline: 1.1190x; 1.1190x over previous
//
#include <hip/hip_runtime.h>
#include <stdint.h>

typedef _Float16 f16x8 __attribute__((ext_vector_type(8)));
typedef _Float16 f16x4 __attribute__((ext_vector_type(4)));
typedef float    f32x4 __attribute__((ext_vector_type(4)));

__device__ __forceinline__ void load16_lds(const _Float16* g, _Float16* l) {
    __builtin_amdgcn_global_load_lds(
        (const __attribute__((address_space(1))) void*)g,
        (__attribute__((address_space(3))) void*)l, 16, 0, 0);
}

// ---------------------------------------------------------------- casts

// fused q/k/v/o weight cast (q||k||v contiguous into qkvw)
__global__ void k_cast4(const float* __restrict__ q, const float* __restrict__ k,
                        const float* __restrict__ v, const float* __restrict__ o,
                        _Float16* __restrict__ qkvw, _Float16* __restrict__ ow)
{
    size_t i = ((size_t)blockIdx.x * 256 + threadIdx.x) * 4;
    const float* src; _Float16* dst;
    if (i < 8388608)        { src = q + i;            dst = qkvw + i; }
    else if (i < 9437184)   { src = k + (i - 8388608); dst = qkvw + i; }
    else if (i < 10485760)  { src = v + (i - 9437184); dst = qkvw + i; }
    else                    { src = o + (i - 10485760); dst = ow + (i - 10485760); }
    float4 x = *reinterpret_cast<const float4*>(src);
    f16x4 y = { (_Float16)x.x, (_Float16)x.y, (_Float16)x.z, (_Float16)x.w };
    *reinterpret_cast<f16x4*>(dst) = y;
}

// edw[e][dm][mi] (f32) -> dwc[dm][e*128+mi] (f16)
__global__ void k_cast_dw(const float* __restrict__ edw, _Float16* __restrict__ dwc) {
    int t = blockIdx.x * 256 + threadIdx.x;
    int mi4 = (t & 31) * 4;
    int dm = (t >> 5) & 2047;
    int e = t >> 16;
    float4 v = *reinterpret_cast<const float4*>(edw + (((size_t)e * 2048 + dm) << 7) + mi4);
    f16x4 o = { (_Float16)v.x, (_Float16)v.y, (_Float16)v.z, (_Float16)v.w };
    *reinterpret_cast<f16x4*>(dwc + ((size_t)dm << 11) + e * 128 + mi4) = o;
}

// egw/euw[e][mi][k] -> guw[e*256 + half*128 + mi][k] (f16)
__global__ __launch_bounds__(256) void k_cast_guw(
    const float* __restrict__ eg, const float* __restrict__ eu,
    _Float16* __restrict__ out)
{
    const int row = blockIdx.x;                // 0..4095
    const int e = row >> 8, rem = row & 255, half = rem >> 7, mi = rem & 127;
    const float* src = (half ? eu : eg) + ((size_t)(e * 128 + mi)) * 2048;
    const int c = threadIdx.x * 8;
    float4 v0 = *reinterpret_cast<const float4*>(src + c);
    float4 v1 = *reinterpret_cast<const float4*>(src + c + 4);
    f16x8 o = { (_Float16)v0.x,(_Float16)v0.y,(_Float16)v0.z,(_Float16)v0.w,
                (_Float16)v1.x,(_Float16)v1.y,(_Float16)v1.z,(_Float16)v1.w };
    *reinterpret_cast<f16x8*>(out + (size_t)row * 2048 + c) = o;
}

// ---------------------------------------------------------------- rmsnorm (f16 out)
__global__ __launch_bounds__(256) void k_rmsnorm(
    const float* __restrict__ x, const float* __restrict__ w,
    _Float16* __restrict__ oh)
{
    const int row = blockIdx.x, tid = threadIdx.x;
    const float* xr = x + (size_t)row * 2048;
    float4 a = *reinterpret_cast<const float4*>(xr + tid * 8);
    float4 b = *reinterpret_cast<const float4*>(xr + tid * 8 + 4);
    float ss = a.x*a.x + a.y*a.y + a.z*a.z + a.w*a.w
             + b.x*b.x + b.y*b.y + b.z*b.z + b.w*b.w;
    #pragma unroll
    for (int m = 1; m < 64; m <<= 1) ss += __shfl_xor(ss, m);
    __shared__ float red[4];
    if ((tid & 63) == 0) red[tid >> 6] = ss;
    __syncthreads();
    float tot = red[0] + red[1] + red[2] + red[3];
    float r = rsqrtf(tot * (1.f / 2048.f) + 1e-6f);
    float4 wa = *reinterpret_cast<const float4*>(w + tid * 8);
    float4 wb = *reinterpret_cast<const float4*>(w + tid * 8 + 4);
    f16x8 hv = { (_Float16)(a.x*r*wa.x), (_Float16)(a.y*r*wa.y),
                 (_Float16)(a.z*r*wa.z), (_Float16)(a.w*r*wa.w),
                 (_Float16)(b.x*r*wb.x), (_Float16)(b.y*r*wb.y),
                 (_Float16)(b.z*r*wb.z), (_Float16)(b.w*r*wb.w) };
    *reinterpret_cast<f16x8*>(oh + (size_t)row * 2048 + tid * 8) = hv;
}

// ---------------------------------------------------------------- GEMM 128x128
// 3-buf counted-vmcnt, XOR-swizzled both sides, XCD-chunked block remap.
__global__ __launch_bounds__(256) void k_gemm(
    const _Float16* __restrict__ A, int lda,
    const _Float16* __restrict__ W, int ldw,
    float* __restrict__ Cf, _Float16* __restrict__ Ch, int ldc,
    const float* __restrict__ resid, int K)
{
    __shared__ __align__(16) _Float16 As[3][128][32];
    __shared__ __align__(16) _Float16 Ws[3][128][32];
    // XCD-aware bijective remap (all grids have nwg % 8 == 0)
    const int bid = blockIdx.y * gridDim.x + blockIdx.x;
    const int chunk = (gridDim.x * gridDim.y) >> 3;
    const int swz = (bid & 7) * chunk + (bid >> 3);
    const int r0 = (swz % gridDim.x) * 128, c0 = (swz / gridDim.x) * 128;
    const int tid = threadIdx.x, lane = tid & 63, wid = tid >> 6;
    const int wr = wid >> 1, wc = wid & 1;
    const int sr = lane >> 2;
    const int scs = ((lane & 3) ^ ((lane >> 3) & 3)) * 8;
    const int fr = lane & 15;
    const int rks = (((lane >> 4) ^ ((fr >> 1) & 3))) * 8;
    const f32x4 z4 = { 0.f, 0.f, 0.f, 0.f };
    f32x4 acc[4][4];
    #pragma unroll
    for (int i = 0; i < 4; i++)
        #pragma unroll
        for (int j = 0; j < 4; j++) acc[i][j] = z4;

    auto stage = [&](int bf, int k0) {
        #pragma unroll
        for (int i = 0; i < 2; i++) {
            int ch = wid * 2 + i;
            load16_lds(A + (size_t)(r0 + ch * 16 + sr) * lda + k0 + scs, &As[bf][ch * 16][0]);
            load16_lds(W + (size_t)(c0 + ch * 16 + sr) * ldw + k0 + scs, &Ws[bf][ch * 16][0]);
        }
    };

    const int nt = K >> 5;
    stage(0, 0);
    if (nt > 1) stage(1, 32);
    int cur = 0;
    for (int t = 0; t < nt; t++) {
        if (t < nt - 1) asm volatile("s_waitcnt vmcnt(4)" ::: "memory");
        else            asm volatile("s_waitcnt vmcnt(0)" ::: "memory");
        __builtin_amdgcn_s_barrier();
        f16x8 af[4], bf4[4];
        #pragma unroll
        for (int i = 0; i < 4; i++)
            af[i] = *reinterpret_cast<const f16x8*>(&As[cur][wr * 64 + i * 16 + fr][rks]);
        #pragma unroll
        for (int j = 0; j < 4; j++)
            bf4[j] = *reinterpret_cast<const f16x8*>(&Ws[cur][wc * 64 + j * 16 + fr][rks]);
        if (t + 2 < nt) stage((t + 2) % 3, (t + 2) << 5);
        #pragma unroll
        for (int i = 0; i < 4; i++)
            #pragma unroll
            for (int j = 0; j < 4; j++)
                acc[i][j] = __builtin_amdgcn_mfma_f32_16x16x32_f16(af[i], bf4[j], acc[i][j], 0, 0, 0);
        cur = (cur + 1) % 3;
    }
    #pragma unroll
    for (int i = 0; i < 4; i++) {
        const int rowb = r0 + wr * 64 + i * 16 + (lane >> 4) * 4;
        #pragma unroll
        for (int j = 0; j < 4; j++) {
            const int col = c0 + wc * 64 + j * 16 + fr;
            #pragma unroll
            for (int r = 0; r < 4; r++) {
                size_t idx = (size_t)(rowb + r) * ldc + col;
                float v = acc[i][j][r];
                if (resid) v += resid[idx];
                if (Ch) Ch[idx] = (_Float16)v;
                else    Cf[idx] = v;
            }
        }
    }
}

// ---------------------------------------------------------------- gate/up combine
__global__ __launch_bounds__(256) void k_gu_comb(
    const _Float16* __restrict__ gucat, const float* __restrict__ wdense,
    _Float16* __restrict__ ab)
{
    const int tok = blockIdx.x;
    const int idx = threadIdx.x;
    const int e = idx >> 4, mi8 = (idx & 15) * 8;
    const _Float16* gp = gucat + (size_t)tok * 4096 + e * 256 + mi8;
    f16x8 gv = *reinterpret_cast<const f16x8*>(gp);
    f16x8 uv = *reinterpret_cast<const f16x8*>(gp + 128);
    float wv = wdense[(size_t)e * 4096 + tok];
    f16x8 o;
    #pragma unroll
    for (int j = 0; j < 8; j++) {
        float g = (float)gv[j], u = (float)uv[j];
        float sil = g / (1.f + __expf(-g));
        o[j] = (_Float16)(sil * u * wv);
    }
    *reinterpret_cast<f16x8*>(ab + (size_t)tok * 2048 + e * 128 + mi8) = o;
}

// ------------------------------------------- per-head RMSNorm + RoPE (wave-per-head)
__global__ __launch_bounds__(256) void k_qkv_post(
    const _Float16* __restrict__ qkv,
    const float* __restrict__ cosb, const float* __restrict__ sinb,
    const float* __restrict__ qn_w, const float* __restrict__ kn_w,
    _Float16* __restrict__ qh, _Float16* __restrict__ kh)
{
    const int tok = blockIdx.x;
    const int u = blockIdx.y * 4 + (threadIdx.x >> 6);
    const int lane = threadIdx.x & 63;
    const int b = tok >> 10, l = tok & 1023;
    const float c0 = cosb[(size_t)tok * 128 + lane];
    const float c1 = cosb[(size_t)tok * 128 + lane + 64];
    const float s0 = sinb[(size_t)tok * 128 + lane];
    const float s1 = sinb[(size_t)tok * 128 + lane + 64];
    if (u < 32) {
        const _Float16* base = qkv + (size_t)tok * 5120 + u * 128;
        float v0 = (float)base[lane], v1 = (float)base[lane + 64];
        float ss = v0 * v0 + v1 * v1;
        #pragma unroll
        for (int m = 1; m < 64; m <<= 1) ss += __shfl_xor(ss, m);
        float rms = rsqrtf(ss * (1.f / 128.f) + 1e-6f);
        float n0 = v0 * rms * qn_w[lane], n1 = v1 * rms * qn_w[lane + 64];
        _Float16* o = qh + (size_t)tok * 4096 + u * 128;
        o[lane]      = (_Float16)(c0 * n0 - s0 * n1);
        o[lane + 64] = (_Float16)(c1 * n1 + s1 * n0);
    } else {
        const int kvh = u - 32;
        const _Float16* base = qkv + (size_t)tok * 5120 + 4096 + kvh * 128;
        float v0 = (float)base[lane], v1 = (float)base[lane + 64];
        float ss = v0 * v0 + v1 * v1;
        #pragma unroll
        for (int m = 1; m < 64; m <<= 1) ss += __shfl_xor(ss, m);
        float rms = rsqrtf(ss * (1.f / 128.f) + 1e-6f);
        float n0 = v0 * rms * kn_w[lane], n1 = v1 * rms * kn_w[lane + 64];
        _Float16* o = kh + (((size_t)(b * 4 + kvh)) * 1024 + l) * 128;
        o[lane]      = (_Float16)(c0 * n0 - s0 * n1);
        o[lane + 64] = (_Float16)(c1 * n1 + s1 * n0);
    }
}

// ---------------------------------------------------------------- V transpose
__global__ __launch_bounds__(256) void k_vt(
    const _Float16* __restrict__ qkv, _Float16* __restrict__ vth)
{
    const int bkv = blockIdx.x;
    const int b = bkv >> 2, kv = bkv & 3;
    const int l0 = blockIdx.y * 64, d0 = blockIdx.z * 64;
    __shared__ _Float16 T[64][72];
    const int t = threadIdx.x;
    const int r = t >> 3, c8 = (t & 7) * 8;
    #pragma unroll
    for (int rr = 0; rr < 2; rr++) {
        int l = l0 + r + rr * 32;
        *reinterpret_cast<f16x8*>(&T[r + rr * 32][c8]) =
            *reinterpret_cast<const f16x8*>(
                qkv + (size_t)(b * 1024 + l) * 5120 + 4608 + kv * 128 + d0 + c8);
    }
    __syncthreads();
    #pragma unroll
    for (int rr = 0; rr < 2; rr++) {
        int d = d0 + r + rr * 32;
        f16x8 v;
        #pragma unroll
        for (int j = 0; j < 8; j++) v[j] = T[c8 + j][r + rr * 32];
        *reinterpret_cast<f16x8*>(vth + ((size_t)(bkv * 128 + d)) * 1024 + l0 + c8) = v;
    }
}

// ---------------------------------------------------------------- attention
__global__ __launch_bounds__(256) void k_attn(
    const _Float16* __restrict__ qh, const _Float16* __restrict__ kh,
    const _Float16* __restrict__ vth, _Float16* __restrict__ oh)
{
    const int bh = blockIdx.x;
    const int g = 15 - blockIdx.y;
    const int b = bh >> 5, h = bh & 31, kv = h >> 3;
    const int tid = threadIdx.x, lane = tid & 63, wid = tid >> 6;
    const int fr = lane & 15, fg = lane >> 4;
    const int q0w = g * 64 + wid * 16;

    __shared__ __align__(16) _Float16 Ks[64][128];
    __shared__ __align__(16) _Float16 Vs[128][64];
    __shared__ __align__(16) _Float16 Ps[4][16][72];

    const _Float16* kb = kh + ((size_t)(b * 4 + kv)) * 1024 * 128;
    const _Float16* vb = vth + ((size_t)(b * 4 + kv)) * 128 * 1024;

    f16x8 aq[4];
    {
        const _Float16* qbase = qh + ((size_t)(b * 1024 + q0w + fr)) * 4096 + h * 128;
        #pragma unroll
        for (int kk = 0; kk < 4; kk++)
            aq[kk] = *reinterpret_cast<const f16x8*>(qbase + kk * 32 + fg * 8);
    }

    float m_r[4] = { -1e30f, -1e30f, -1e30f, -1e30f };
    float l_r[4] = { 0.f, 0.f, 0.f, 0.f };
    const f32x4 z4 = { 0.f, 0.f, 0.f, 0.f };
    f32x4 oacc[8];
    #pragma unroll
    for (int dj = 0; dj < 8; dj++) oacc[dj] = z4;

    const int ntiles = g + 1;
    for (int kt = 0; kt < ntiles; kt++) {
        const int key0 = kt * 64;
        #pragma unroll
        for (int i = 0; i < 4; i++) {
            int rr = 16 * wid + 4 * i + (lane >> 4);
            int c16 = (lane & 15) ^ (rr & 7);
            load16_lds(kb + (size_t)(key0 + rr) * 128 + c16 * 8,
                       &Ks[0][0] + (16 * wid + 4 * i) * 128);
        }
        #pragma unroll
        for (int i = 0; i < 4; i++) {
            int rr = 32 * wid + 8 * i + (lane >> 3);
            int c16 = (lane & 7) ^ (rr & 7);
            load16_lds(vb + (size_t)rr * 1024 + key0 + c16 * 8,
                       &Vs[0][0] + (32 * wid + 8 * i) * 64);
        }
        __syncthreads();

        f32x4 sc[4];
        #pragma unroll
        for (int j = 0; j < 4; j++) sc[j] = z4;
        #pragma unroll
        for (int j = 0; j < 4; j++) {
            #pragma unroll
            for (int kk = 0; kk < 4; kk++) {
                f16x8 bk = *reinterpret_cast<const f16x8*>(
                    &Ks[0][0] + (j * 16 + fr) * 128 + (((kk * 4 + fg) ^ (fr & 7)) * 8));
                sc[j] = __builtin_amdgcn_mfma_f32_16x16x32_f16(aq[kk], bk, sc[j], 0, 0, 0);
            }
        }

        const bool lastt = (kt == ntiles - 1);
        float pmax[4] = { -1e30f, -1e30f, -1e30f, -1e30f };
        #pragma unroll
        for (int j = 0; j < 4; j++) {
            const int key = key0 + j * 16 + fr;
            #pragma unroll
            for (int r = 0; r < 4; r++) {
                float v = sc[j][r] * 0.08838834764831845f;
                if (lastt && key > q0w + fg * 4 + r) v = -1e30f;
                sc[j][r] = v;
                pmax[r] = fmaxf(pmax[r], v);
            }
        }
        #pragma unroll
        for (int m = 1; m < 16; m <<= 1)
            #pragma unroll
            for (int r = 0; r < 4; r++) pmax[r] = fmaxf(pmax[r], __shfl_xor(pmax[r], m));
        float alpha[4];
        #pragma unroll
        for (int r = 0; r < 4; r++) {
            float mn = fmaxf(m_r[r], pmax[r]);
            alpha[r] = __expf(m_r[r] - mn);
            m_r[r] = mn;
        }
        float rs[4] = { 0.f, 0.f, 0.f, 0.f };
        #pragma unroll
        for (int j = 0; j < 4; j++)
            #pragma unroll
            for (int r = 0; r < 4; r++) {
                float p = __expf(sc[j][r] - m_r[r]);
                sc[j][r] = p;
                rs[r] += p;
            }
        #pragma unroll
        for (int m = 1; m < 16; m <<= 1)
            #pragma unroll
            for (int r = 0; r < 4; r++) rs[r] += __shfl_xor(rs[r], m);
        #pragma unroll
        for (int r = 0; r < 4; r++) l_r[r] = l_r[r] * alpha[r] + rs[r];
        #pragma unroll
        for (int dj = 0; dj < 8; dj++)
            #pragma unroll
            for (int r = 0; r < 4; r++) oacc[dj][r] *= alpha[r];

        #pragma unroll
        for (int j = 0; j < 4; j++)
            #pragma unroll
            for (int r = 0; r < 4; r++)
                Ps[wid][fg * 4 + r][j * 16 + fr] = (_Float16)sc[j][r];

        #pragma unroll
        for (int ks = 0; ks < 2; ks++) {
            f16x8 ap = *reinterpret_cast<const f16x8*>(&Ps[wid][fr][ks * 32 + fg * 8]);
            #pragma unroll
            for (int dj = 0; dj < 8; dj++) {
                f16x8 bv = *reinterpret_cast<const f16x8*>(
                    &Vs[0][0] + (dj * 16 + fr) * 64 + (((ks * 4 + fg) ^ (fr & 7)) * 8));
                oacc[dj] = __builtin_amdgcn_mfma_f32_16x16x32_f16(ap, bv, oacc[dj], 0, 0, 0);
            }
        }
        __syncthreads();
    }

    float inv[4];
    #pragma unroll
    for (int r = 0; r < 4; r++) inv[r] = 1.f / l_r[r];
    #pragma unroll
    for (int dj = 0; dj < 8; dj++)
        #pragma unroll
        for (int r = 0; r < 4; r++)
            oh[((size_t)(b * 1024 + q0w + fg * 4 + r)) * 4096 + h * 128 + dj * 16 + fr] =
                (_Float16)(oacc[dj][r] * inv[r]);
}

// ---------------------------------------------------------------- router (inline rmsnorm from x2)
__global__ __launch_bounds__(256) void k_router(
    const float* __restrict__ x2, const float* __restrict__ wm,
    const float* __restrict__ rw, float* __restrict__ wdense)
{
    const int tok = blockIdx.x * 4 + (threadIdx.x >> 6);
    const int lane = threadIdx.x & 63;
    __shared__ float lg[4][16];
    const float* hr = x2 + (size_t)tok * 2048;
    float vals[32];
    float ss = 0.f;
    #pragma unroll
    for (int i = 0; i < 32; i++) { float v = hr[i * 64 + lane]; vals[i] = v; ss += v * v; }
    #pragma unroll
    for (int m = 1; m < 64; m <<= 1) ss += __shfl_xor(ss, m);
    float r = rsqrtf(ss * (1.f / 2048.f) + 1e-6f);
    #pragma unroll
    for (int i = 0; i < 32; i++) vals[i] *= r * wm[i * 64 + lane];
    for (int e = 0; e < 16; e++) {
        float acc = 0.f;
        #pragma unroll
        for (int i = 0; i < 32; i++) acc += vals[i] * rw[(size_t)e * 2048 + i * 64 + lane];
        #pragma unroll
        for (int m = 1; m < 64; m <<= 1) acc += __shfl_xor(acc, m);
        if (lane == 0) lg[threadIdx.x >> 6][e] = acc;
    }
    __syncthreads();
    if (lane == 0) {
        float* l = lg[threadIdx.x >> 6];
        float mx = l[0];
        for (int e = 1; e < 16; e++) mx = fmaxf(mx, l[e]);
        float p[16]; float sum = 0.f;
        for (int e = 0; e < 16; e++) { p[e] = expf(l[e] - mx); sum += p[e]; }
        for (int e = 0; e < 16; e++) p[e] /= sum;
        bool sel[16]; for (int e = 0; e < 16; e++) sel[e] = false;
        float ssum = 0.f;
        for (int t = 0; t < 8; t++) {
            int bi = -1; float bv = -1.f;
            for (int e = 0; e < 16; e++) if (!sel[e] && p[e] > bv) { bv = p[e]; bi = e; }
            sel[bi] = true; ssum += bv;
        }
        for (int e = 0; e < 16; e++)
            wdense[(size_t)e * 4096 + tok] = sel[e] ? p[e] / ssum : 0.f;
    }
}

// ---------------------------------------------------------------- launch

extern "C" void kernel_launch(void* const* d_in, const int* in_sizes, int n_in,
                              void* d_out, int out_size, void* d_ws, size_t ws_size,
                              hipStream_t stream)
{
    const float* x        = (const float*)d_in[0];
    const float* cosb     = (const float*)d_in[1];
    const float* sinb     = (const float*)d_in[2];
    const float* nattn    = (const float*)d_in[3];
    const float* q_w      = (const float*)d_in[4];
    const float* k_w      = (const float*)d_in[5];
    const float* v_w      = (const float*)d_in[6];
    const float* qn_w     = (const float*)d_in[7];
    const float* kn_w     = (const float*)d_in[8];
    const float* o_w      = (const float*)d_in[9];
    const float* nmlp     = (const float*)d_in[10];
    const float* router_w = (const float*)d_in[11];
    const float* egw      = (const float*)d_in[12];
    const float* euw      = (const float*)d_in[13];
    const float* edw      = (const float*)d_in[14];

    char* w = (char*)d_ws;
    _Float16* qkvw_h = (_Float16*)(w + 0);          // 20.97 MB
    _Float16* ow_h   = (_Float16*)(w + 20971520);   // 16.78 MB
    _Float16* guw_h  = (_Float16*)(w + 37748736);   // 16.78 MB
    _Float16* dwc_h  = (_Float16*)(w + 54525952);   //  8.39 MB
    _Float16* h_h    = (_Float16*)(w + 62914560);   // 16.78 MB (aliased hm_h)
    _Float16* hm_h   = h_h;
    float*    x2     = (float*)(w + 79691776);      // 33.55 MB
    _Float16* qkv_h  = (_Float16*)(w + 113246208);  // 41.94 MB (alias o_h, ab_h)
    _Float16* o_h    = qkv_h;
    _Float16* ab_h   = qkv_h;
    _Float16* q_h    = (_Float16*)(w + 155189248);  // 33.55 MB (alias gucat)
    _Float16* gucat  = (_Float16*)(w + 155189248);
    _Float16* k_h    = (_Float16*)(w + 188743680);  //  4.19 MB
    _Float16* vt_h   = (_Float16*)(w + 192937984);  //  4.19 MB
    float*    wdense = (float*)(w + 197132288);     //  0.26 MB

    k_cast4<<<18432, 256, 0, stream>>>(q_w, k_w, v_w, o_w, qkvw_h, ow_h);
    k_cast_guw<<<4096, 256, 0, stream>>>(egw, euw, guw_h);
    k_cast_dw<<<4096, 256, 0, stream>>>(edw, dwc_h);

    k_rmsnorm<<<4096, 256, 0, stream>>>(x, nattn, h_h);
    k_gemm<<<dim3(32, 40), 256, 0, stream>>>(h_h, 2048, qkvw_h, 2048,
                                             nullptr, qkv_h, 5120, nullptr, 2048);
    k_qkv_post<<<dim3(4096, 9), 256, 0, stream>>>(qkv_h, cosb, sinb, qn_w, kn_w, q_h, k_h);
    k_vt<<<dim3(16, 16, 2), 256, 0, stream>>>(qkv_h, vt_h);
    k_attn<<<dim3(128, 16), 256, 0, stream>>>(q_h, k_h, vt_h, o_h);
    k_gemm<<<dim3(32, 16), 256, 0, stream>>>(o_h, 4096, ow_h, 4096,
                                             x2, nullptr, 2048, x, 4096);
    k_rmsnorm<<<4096, 256, 0, stream>>>(x2, nmlp, hm_h);
    k_router<<<1024, 256, 0, stream>>>(x2, nmlp, router_w, wdense);
    k_gemm<<<dim3(32, 32), 256, 0, stream>>>(hm_h, 2048, guw_h, 2048,
                                             nullptr, gucat, 4096, nullptr, 2048);
    k_gu_comb<<<4096, 256, 0, stream>>>(gucat, wdense, ab_h);
    k_gemm<<<dim3(32, 16), 256, 0, stream>>>(ab_h, 2048, dwc_h, 2048,
                                             (float*)d_out, nullptr, 2048, x2, 2048);

    (void)in_sizes; (void)n_in; (void)out_size; (void)ws_size;
}

// Round 9
// 544.788 us; speedup vs baseline: 1.2295x; 1.0987x over previous
//
#include <hip/hip_runtime.h>
#include <stdint.h>

typedef _Float16 f16x8 __attribute__((ext_vector_type(8)));
typedef _Float16 f16x4 __attribute__((ext_vector_type(4)));
typedef float    f32x4 __attribute__((ext_vector_type(4)));

__device__ __forceinline__ void load16_lds(const _Float16* g, _Float16* l) {
    __builtin_amdgcn_global_load_lds(
        (const __attribute__((address_space(1))) void*)g,
        (__attribute__((address_space(3))) void*)l, 16, 0, 0);
}

// ---------------------------------------------------------------- casts

__global__ void k_cast4(const float* __restrict__ q, const float* __restrict__ k,
                        const float* __restrict__ v, const float* __restrict__ o,
                        _Float16* __restrict__ qkvw, _Float16* __restrict__ ow)
{
    size_t i = ((size_t)blockIdx.x * 256 + threadIdx.x) * 4;
    const float* src; _Float16* dst;
    if (i < 8388608)        { src = q + i;            dst = qkvw + i; }
    else if (i < 9437184)   { src = k + (i - 8388608); dst = qkvw + i; }
    else if (i < 10485760)  { src = v + (i - 9437184); dst = qkvw + i; }
    else                    { src = o + (i - 10485760); dst = ow + (i - 10485760); }
    float4 x = *reinterpret_cast<const float4*>(src);
    f16x4 y = { (_Float16)x.x, (_Float16)x.y, (_Float16)x.z, (_Float16)x.w };
    *reinterpret_cast<f16x4*>(dst) = y;
}

// edw[e][dm][mi] (f32) -> dwc[dm][e*128+mi] (f16)
__global__ void k_cast_dw(const float* __restrict__ edw, _Float16* __restrict__ dwc) {
    int t = blockIdx.x * 256 + threadIdx.x;
    int mi4 = (t & 31) * 4;
    int dm = (t >> 5) & 2047;
    int e = t >> 16;
    float4 v = *reinterpret_cast<const float4*>(edw + (((size_t)e * 2048 + dm) << 7) + mi4);
    f16x4 o = { (_Float16)v.x, (_Float16)v.y, (_Float16)v.z, (_Float16)v.w };
    *reinterpret_cast<f16x4*>(dwc + ((size_t)dm << 11) + e * 128 + mi4) = o;
}

// egw/euw[e][mi][k] -> guw[e*256 + half*128 + mi][k] (f16)
__global__ __launch_bounds__(256) void k_cast_guw(
    const float* __restrict__ eg, const float* __restrict__ eu,
    _Float16* __restrict__ out)
{
    const int row = blockIdx.x;                // 0..4095
    const int e = row >> 8, rem = row & 255, half = rem >> 7, mi = rem & 127;
    const float* src = (half ? eu : eg) + ((size_t)(e * 128 + mi)) * 2048;
    const int c = threadIdx.x * 8;
    float4 v0 = *reinterpret_cast<const float4*>(src + c);
    float4 v1 = *reinterpret_cast<const float4*>(src + c + 4);
    f16x8 o = { (_Float16)v0.x,(_Float16)v0.y,(_Float16)v0.z,(_Float16)v0.w,
                (_Float16)v1.x,(_Float16)v1.y,(_Float16)v1.z,(_Float16)v1.w };
    *reinterpret_cast<f16x8*>(out + (size_t)row * 2048 + c) = o;
}

// ---------------------------------------------------------------- rmsnorm (f16 out)
__global__ __launch_bounds__(256) void k_rmsnorm(
    const float* __restrict__ x, const float* __restrict__ w,
    _Float16* __restrict__ oh)
{
    const int row = blockIdx.x, tid = threadIdx.x;
    const float* xr = x + (size_t)row * 2048;
    float4 a = *reinterpret_cast<const float4*>(xr + tid * 8);
    float4 b = *reinterpret_cast<const float4*>(xr + tid * 8 + 4);
    float ss = a.x*a.x + a.y*a.y + a.z*a.z + a.w*a.w
             + b.x*b.x + b.y*b.y + b.z*b.z + b.w*b.w;
    #pragma unroll
    for (int m = 1; m < 64; m <<= 1) ss += __shfl_xor(ss, m);
    __shared__ float red[4];
    if ((tid & 63) == 0) red[tid >> 6] = ss;
    __syncthreads();
    float tot = red[0] + red[1] + red[2] + red[3];
    float r = rsqrtf(tot * (1.f / 2048.f) + 1e-6f);
    float4 wa = *reinterpret_cast<const float4*>(w + tid * 8);
    float4 wb = *reinterpret_cast<const float4*>(w + tid * 8 + 4);
    f16x8 hv = { (_Float16)(a.x*r*wa.x), (_Float16)(a.y*r*wa.y),
                 (_Float16)(a.z*r*wa.z), (_Float16)(a.w*r*wa.w),
                 (_Float16)(b.x*r*wb.x), (_Float16)(b.y*r*wb.y),
                 (_Float16)(b.z*r*wb.z), (_Float16)(b.w*r*wb.w) };
    *reinterpret_cast<f16x8*>(oh + (size_t)row * 2048 + tid * 8) = hv;
}

// ---------------------------------------------------------------- GEMM 128x128
// 3-buf counted-vmcnt, XOR-swizzled both sides (proven structure, no remap).
__global__ __launch_bounds__(256) void k_gemm(
    const _Float16* __restrict__ A, int lda,
    const _Float16* __restrict__ W, int ldw,
    float* __restrict__ Cf, _Float16* __restrict__ Ch, int ldc,
    const float* __restrict__ resid, int K)
{
    __shared__ __align__(16) _Float16 As[3][128][32];
    __shared__ __align__(16) _Float16 Ws[3][128][32];
    const int r0 = blockIdx.x * 128, c0 = blockIdx.y * 128;
    const int tid = threadIdx.x, lane = tid & 63, wid = tid >> 6;
    const int wr = wid >> 1, wc = wid & 1;
    const int sr = lane >> 2;
    const int scs = ((lane & 3) ^ ((lane >> 3) & 3)) * 8;
    const int fr = lane & 15;
    const int rks = (((lane >> 4) ^ ((fr >> 1) & 3))) * 8;
    const f32x4 z4 = { 0.f, 0.f, 0.f, 0.f };
    f32x4 acc[4][4];
    #pragma unroll
    for (int i = 0; i < 4; i++)
        #pragma unroll
        for (int j = 0; j < 4; j++) acc[i][j] = z4;

    auto stage = [&](int bf, int k0) {
        #pragma unroll
        for (int i = 0; i < 2; i++) {
            int ch = wid * 2 + i;
            load16_lds(A + (size_t)(r0 + ch * 16 + sr) * lda + k0 + scs, &As[bf][ch * 16][0]);
            load16_lds(W + (size_t)(c0 + ch * 16 + sr) * ldw + k0 + scs, &Ws[bf][ch * 16][0]);
        }
    };

    const int nt = K >> 5;
    stage(0, 0);
    if (nt > 1) stage(1, 32);
    int cur = 0;
    for (int t = 0; t < nt; t++) {
        if (t < nt - 1) asm volatile("s_waitcnt vmcnt(4)" ::: "memory");
        else            asm volatile("s_waitcnt vmcnt(0)" ::: "memory");
        __builtin_amdgcn_s_barrier();
        f16x8 af[4], bf4[4];
        #pragma unroll
        for (int i = 0; i < 4; i++)
            af[i] = *reinterpret_cast<const f16x8*>(&As[cur][wr * 64 + i * 16 + fr][rks]);
        #pragma unroll
        for (int j = 0; j < 4; j++)
            bf4[j] = *reinterpret_cast<const f16x8*>(&Ws[cur][wc * 64 + j * 16 + fr][rks]);
        if (t + 2 < nt) stage((t + 2) % 3, (t + 2) << 5);
        __builtin_amdgcn_s_setprio(1);
        #pragma unroll
        for (int i = 0; i < 4; i++)
            #pragma unroll
            for (int j = 0; j < 4; j++)
                acc[i][j] = __builtin_amdgcn_mfma_f32_16x16x32_f16(af[i], bf4[j], acc[i][j], 0, 0, 0);
        __builtin_amdgcn_s_setprio(0);
        cur = (cur + 1) % 3;
    }
    #pragma unroll
    for (int i = 0; i < 4; i++) {
        const int rowb = r0 + wr * 64 + i * 16 + (lane >> 4) * 4;
        #pragma unroll
        for (int j = 0; j < 4; j++) {
            const int col = c0 + wc * 64 + j * 16 + fr;
            #pragma unroll
            for (int r = 0; r < 4; r++) {
                size_t idx = (size_t)(rowb + r) * ldc + col;
                float v = acc[i][j][r];
                if (resid) v += resid[idx];
                if (Ch) Ch[idx] = (_Float16)v;
                else    Cf[idx] = v;
            }
        }
    }
}

// ---------------------------------------------------------------- GEMM 256x256, 8 waves
// Wave-tile 128x64 (32 MFMA / 12 ds_read per K-step). Same 3-ring counted-vmcnt
// + both-sides swizzle discipline as k_gemm. f16 output. Grid must be (M/256, N/256).
__global__ __launch_bounds__(512, 2) void k_gemm8(
    const _Float16* __restrict__ A, int lda,
    const _Float16* __restrict__ W, int ldw,
    _Float16* __restrict__ Ch, int ldc, int K)
{
    __shared__ __align__(16) _Float16 As[3][256][32];   // 48 KB
    __shared__ __align__(16) _Float16 Ws[3][256][32];   // 48 KB
    const int r0 = blockIdx.x * 256, c0 = blockIdx.y * 256;
    const int tid = threadIdx.x, lane = tid & 63, wid = tid >> 6;
    const int wr = wid >> 2, wc = wid & 3;              // 2M x 4N wave grid
    const int rA = lane >> 2;                            // row within wave's 16-row stripe
    const int scs = ((lane & 3) ^ ((lane >> 3) & 3)) * 8;
    const int fr = lane & 15;
    const int rks = (((lane >> 4) ^ ((fr >> 1) & 3))) * 8;
    const f32x4 z4 = { 0.f, 0.f, 0.f, 0.f };
    f32x4 acc[8][4];
    #pragma unroll
    for (int i = 0; i < 8; i++)
        #pragma unroll
        for (int j = 0; j < 4; j++) acc[i][j] = z4;

    auto stage = [&](int bf, int k0) {
        #pragma unroll
        for (int i = 0; i < 2; i++) {
            load16_lds(A + (size_t)(r0 + i * 128 + wid * 16 + rA) * lda + k0 + scs,
                       &As[bf][i * 128 + wid * 16][0]);
            load16_lds(W + (size_t)(c0 + i * 128 + wid * 16 + rA) * ldw + k0 + scs,
                       &Ws[bf][i * 128 + wid * 16][0]);
        }
    };

    const int nt = K >> 5;
    stage(0, 0);
    if (nt > 1) stage(1, 32);
    int cur = 0;
    for (int t = 0; t < nt; t++) {
        if (t < nt - 1) asm volatile("s_waitcnt vmcnt(4)" ::: "memory");
        else            asm volatile("s_waitcnt vmcnt(0)" ::: "memory");
        __builtin_amdgcn_s_barrier();
        f16x8 af[8], bf4[4];
        #pragma unroll
        for (int i = 0; i < 8; i++)
            af[i] = *reinterpret_cast<const f16x8*>(&As[cur][wr * 128 + i * 16 + fr][rks]);
        #pragma unroll
        for (int j = 0; j < 4; j++)
            bf4[j] = *reinterpret_cast<const f16x8*>(&Ws[cur][wc * 64 + j * 16 + fr][rks]);
        if (t + 2 < nt) stage((t + 2) % 3, (t + 2) << 5);
        __builtin_amdgcn_s_setprio(1);
        #pragma unroll
        for (int i = 0; i < 8; i++)
            #pragma unroll
            for (int j = 0; j < 4; j++)
                acc[i][j] = __builtin_amdgcn_mfma_f32_16x16x32_f16(af[i], bf4[j], acc[i][j], 0, 0, 0);
        __builtin_amdgcn_s_setprio(0);
        cur = (cur + 1) % 3;
    }
    #pragma unroll
    for (int i = 0; i < 8; i++) {
        const int rowb = r0 + wr * 128 + i * 16 + (lane >> 4) * 4;
        #pragma unroll
        for (int j = 0; j < 4; j++) {
            const int col = c0 + wc * 64 + j * 16 + fr;
            #pragma unroll
            for (int r = 0; r < 4; r++)
                Ch[(size_t)(rowb + r) * ldc + col] = (_Float16)acc[i][j][r];
        }
    }
}

// ---------------------------------------------------------------- gate/up combine
__global__ __launch_bounds__(256) void k_gu_comb(
    const _Float16* __restrict__ gucat, const float* __restrict__ wdense,
    _Float16* __restrict__ ab)
{
    const int tok = blockIdx.x;
    const int idx = threadIdx.x;
    const int e = idx >> 4, mi8 = (idx & 15) * 8;
    const _Float16* gp = gucat + (size_t)tok * 4096 + e * 256 + mi8;
    f16x8 gv = *reinterpret_cast<const f16x8*>(gp);
    f16x8 uv = *reinterpret_cast<const f16x8*>(gp + 128);
    float wv = wdense[(size_t)e * 4096 + tok];
    f16x8 o;
    #pragma unroll
    for (int j = 0; j < 8; j++) {
        float g = (float)gv[j], u = (float)uv[j];
        float sil = g / (1.f + __expf(-g));
        o[j] = (_Float16)(sil * u * wv);
    }
    *reinterpret_cast<f16x8*>(ab + (size_t)tok * 2048 + e * 128 + mi8) = o;
}

// ------------------------------------------- per-head RMSNorm + RoPE (wave-per-head)
__global__ __launch_bounds__(256) void k_qkv_post(
    const _Float16* __restrict__ qkv,
    const float* __restrict__ cosb, const float* __restrict__ sinb,
    const float* __restrict__ qn_w, const float* __restrict__ kn_w,
    _Float16* __restrict__ qh, _Float16* __restrict__ kh)
{
    const int tok = blockIdx.x;
    const int u = blockIdx.y * 4 + (threadIdx.x >> 6);
    const int lane = threadIdx.x & 63;
    const int b = tok >> 10, l = tok & 1023;
    const float c0 = cosb[(size_t)tok * 128 + lane];
    const float c1 = cosb[(size_t)tok * 128 + lane + 64];
    const float s0 = sinb[(size_t)tok * 128 + lane];
    const float s1 = sinb[(size_t)tok * 128 + lane + 64];
    if (u < 32) {
        const _Float16* base = qkv + (size_t)tok * 5120 + u * 128;
        float v0 = (float)base[lane], v1 = (float)base[lane + 64];
        float ss = v0 * v0 + v1 * v1;
        #pragma unroll
        for (int m = 1; m < 64; m <<= 1) ss += __shfl_xor(ss, m);
        float rms = rsqrtf(ss * (1.f / 128.f) + 1e-6f);
        float n0 = v0 * rms * qn_w[lane], n1 = v1 * rms * qn_w[lane + 64];
        _Float16* o = qh + (size_t)tok * 4096 + u * 128;
        o[lane]      = (_Float16)(c0 * n0 - s0 * n1);
        o[lane + 64] = (_Float16)(c1 * n1 + s1 * n0);
    } else {
        const int kvh = u - 32;
        const _Float16* base = qkv + (size_t)tok * 5120 + 4096 + kvh * 128;
        float v0 = (float)base[lane], v1 = (float)base[lane + 64];
        float ss = v0 * v0 + v1 * v1;
        #pragma unroll
        for (int m = 1; m < 64; m <<= 1) ss += __shfl_xor(ss, m);
        float rms = rsqrtf(ss * (1.f / 128.f) + 1e-6f);
        float n0 = v0 * rms * kn_w[lane], n1 = v1 * rms * kn_w[lane + 64];
        _Float16* o = kh + (((size_t)(b * 4 + kvh)) * 1024 + l) * 128;
        o[lane]      = (_Float16)(c0 * n0 - s0 * n1);
        o[lane + 64] = (_Float16)(c1 * n1 + s1 * n0);
    }
}

// ---------------------------------------------------------------- V transpose
__global__ __launch_bounds__(256) void k_vt(
    const _Float16* __restrict__ qkv, _Float16* __restrict__ vth)
{
    const int bkv = blockIdx.x;
    const int b = bkv >> 2, kv = bkv & 3;
    const int l0 = blockIdx.y * 64, d0 = blockIdx.z * 64;
    __shared__ _Float16 T[64][72];
    const int t = threadIdx.x;
    const int r = t >> 3, c8 = (t & 7) * 8;
    #pragma unroll
    for (int rr = 0; rr < 2; rr++) {
        int l = l0 + r + rr * 32;
        *reinterpret_cast<f16x8*>(&T[r + rr * 32][c8]) =
            *reinterpret_cast<const f16x8*>(
                qkv + (size_t)(b * 1024 + l) * 5120 + 4608 + kv * 128 + d0 + c8);
    }
    __syncthreads();
    #pragma unroll
    for (int rr = 0; rr < 2; rr++) {
        int d = d0 + r + rr * 32;
        f16x8 v;
        #pragma unroll
        for (int j = 0; j < 8; j++) v[j] = T[c8 + j][r + rr * 32];
        *reinterpret_cast<f16x8*>(vth + ((size_t)(bkv * 128 + d)) * 1024 + l0 + c8) = v;
    }
}

// ---------------------------------------------------------------- attention
__global__ __launch_bounds__(256) void k_attn(
    const _Float16* __restrict__ qh, const _Float16* __restrict__ kh,
    const _Float16* __restrict__ vth, _Float16* __restrict__ oh)
{
    const int bh = blockIdx.x;
    const int g = 15 - blockIdx.y;
    const int b = bh >> 5, h = bh & 31, kv = h >> 3;
    const int tid = threadIdx.x, lane = tid & 63, wid = tid >> 6;
    const int fr = lane & 15, fg = lane >> 4;
    const int q0w = g * 64 + wid * 16;

    __shared__ __align__(16) _Float16 Ks[64][128];
    __shared__ __align__(16) _Float16 Vs[128][64];
    __shared__ __align__(16) _Float16 Ps[4][16][72];

    const _Float16* kb = kh + ((size_t)(b * 4 + kv)) * 1024 * 128;
    const _Float16* vb = vth + ((size_t)(b * 4 + kv)) * 128 * 1024;

    f16x8 aq[4];
    {
        const _Float16* qbase = qh + ((size_t)(b * 1024 + q0w + fr)) * 4096 + h * 128;
        #pragma unroll
        for (int kk = 0; kk < 4; kk++)
            aq[kk] = *reinterpret_cast<const f16x8*>(qbase + kk * 32 + fg * 8);
    }

    float m_r[4] = { -1e30f, -1e30f, -1e30f, -1e30f };
    float l_r[4] = { 0.f, 0.f, 0.f, 0.f };
    const f32x4 z4 = { 0.f, 0.f, 0.f, 0.f };
    f32x4 oacc[8];
    #pragma unroll
    for (int dj = 0; dj < 8; dj++) oacc[dj] = z4;

    const int ntiles = g + 1;
    for (int kt = 0; kt < ntiles; kt++) {
        const int key0 = kt * 64;
        #pragma unroll
        for (int i = 0; i < 4; i++) {
            int rr = 16 * wid + 4 * i + (lane >> 4);
            int c16 = (lane & 15) ^ (rr & 7);
            load16_lds(kb + (size_t)(key0 + rr) * 128 + c16 * 8,
                       &Ks[0][0] + (16 * wid + 4 * i) * 128);
        }
        #pragma unroll
        for (int i = 0; i < 4; i++) {
            int rr = 32 * wid + 8 * i + (lane >> 3);
            int c16 = (lane & 7) ^ (rr & 7);
            load16_lds(vb + (size_t)rr * 1024 + key0 + c16 * 8,
                       &Vs[0][0] + (32 * wid + 8 * i) * 64);
        }
        __syncthreads();

        f32x4 sc[4];
        #pragma unroll
        for (int j = 0; j < 4; j++) sc[j] = z4;
        #pragma unroll
        for (int j = 0; j < 4; j++) {
            #pragma unroll
            for (int kk = 0; kk < 4; kk++) {
                f16x8 bk = *reinterpret_cast<const f16x8*>(
                    &Ks[0][0] + (j * 16 + fr) * 128 + (((kk * 4 + fg) ^ (fr & 7)) * 8));
                sc[j] = __builtin_amdgcn_mfma_f32_16x16x32_f16(aq[kk], bk, sc[j], 0, 0, 0);
            }
        }

        const bool lastt = (kt == ntiles - 1);
        float pmax[4] = { -1e30f, -1e30f, -1e30f, -1e30f };
        #pragma unroll
        for (int j = 0; j < 4; j++) {
            const int key = key0 + j * 16 + fr;
            #pragma unroll
            for (int r = 0; r < 4; r++) {
                float v = sc[j][r] * 0.08838834764831845f;
                if (lastt && key > q0w + fg * 4 + r) v = -1e30f;
                sc[j][r] = v;
                pmax[r] = fmaxf(pmax[r], v);
            }
        }
        #pragma unroll
        for (int m = 1; m < 16; m <<= 1)
            #pragma unroll
            for (int r = 0; r < 4; r++) pmax[r] = fmaxf(pmax[r], __shfl_xor(pmax[r], m));
        float alpha[4];
        #pragma unroll
        for (int r = 0; r < 4; r++) {
            float mn = fmaxf(m_r[r], pmax[r]);
            alpha[r] = __expf(m_r[r] - mn);
            m_r[r] = mn;
        }
        float rs[4] = { 0.f, 0.f, 0.f, 0.f };
        #pragma unroll
        for (int j = 0; j < 4; j++)
            #pragma unroll
            for (int r = 0; r < 4; r++) {
                float p = __expf(sc[j][r] - m_r[r]);
                sc[j][r] = p;
                rs[r] += p;
            }
        #pragma unroll
        for (int m = 1; m < 16; m <<= 1)
            #pragma unroll
            for (int r = 0; r < 4; r++) rs[r] += __shfl_xor(rs[r], m);
        #pragma unroll
        for (int r = 0; r < 4; r++) l_r[r] = l_r[r] * alpha[r] + rs[r];
        #pragma unroll
        for (int dj = 0; dj < 8; dj++)
            #pragma unroll
            for (int r = 0; r < 4; r++) oacc[dj][r] *= alpha[r];

        #pragma unroll
        for (int j = 0; j < 4; j++)
            #pragma unroll
            for (int r = 0; r < 4; r++)
                Ps[wid][fg * 4 + r][j * 16 + fr] = (_Float16)sc[j][r];

        #pragma unroll
        for (int ks = 0; ks < 2; ks++) {
            f16x8 ap = *reinterpret_cast<const f16x8*>(&Ps[wid][fr][ks * 32 + fg * 8]);
            #pragma unroll
            for (int dj = 0; dj < 8; dj++) {
                f16x8 bv = *reinterpret_cast<const f16x8*>(
                    &Vs[0][0] + (dj * 16 + fr) * 64 + (((ks * 4 + fg) ^ (fr & 7)) * 8));
                oacc[dj] = __builtin_amdgcn_mfma_f32_16x16x32_f16(ap, bv, oacc[dj], 0, 0, 0);
            }
        }
        __syncthreads();
    }

    float inv[4];
    #pragma unroll
    for (int r = 0; r < 4; r++) inv[r] = 1.f / l_r[r];
    #pragma unroll
    for (int dj = 0; dj < 8; dj++)
        #pragma unroll
        for (int r = 0; r < 4; r++)
            oh[((size_t)(b * 1024 + q0w + fg * 4 + r)) * 4096 + h * 128 + dj * 16 + fr] =
                (_Float16)(oacc[dj][r] * inv[r]);
}

// ---------------------------------------------------------------- router (inline rmsnorm from x2)
__global__ __launch_bounds__(256) void k_router(
    const float* __restrict__ x2, const float* __restrict__ wm,
    const float* __restrict__ rw, float* __restrict__ wdense)
{
    const int tok = blockIdx.x * 4 + (threadIdx.x >> 6);
    const int lane = threadIdx.x & 63;
    __shared__ float lg[4][16];
    const float* hr = x2 + (size_t)tok * 2048;
    float vals[32];
    float ss = 0.f;
    #pragma unroll
    for (int i = 0; i < 32; i++) { float v = hr[i * 64 + lane]; vals[i] = v; ss += v * v; }
    #pragma unroll
    for (int m = 1; m < 64; m <<= 1) ss += __shfl_xor(ss, m);
    float r = rsqrtf(ss * (1.f / 2048.f) + 1e-6f);
    #pragma unroll
    for (int i = 0; i < 32; i++) vals[i] *= r * wm[i * 64 + lane];
    for (int e = 0; e < 16; e++) {
        float acc = 0.f;
        #pragma unroll
        for (int i = 0; i < 32; i++) acc += vals[i] * rw[(size_t)e * 2048 + i * 64 + lane];
        #pragma unroll
        for (int m = 1; m < 64; m <<= 1) acc += __shfl_xor(acc, m);
        if (lane == 0) lg[threadIdx.x >> 6][e] = acc;
    }
    __syncthreads();
    if (lane == 0) {
        float* l = lg[threadIdx.x >> 6];
        float mx = l[0];
        for (int e = 1; e < 16; e++) mx = fmaxf(mx, l[e]);
        float p[16]; float sum = 0.f;
        for (int e = 0; e < 16; e++) { p[e] = expf(l[e] - mx); sum += p[e]; }
        for (int e = 0; e < 16; e++) p[e] /= sum;
        bool sel[16]; for (int e = 0; e < 16; e++) sel[e] = false;
        float ssum = 0.f;
        for (int t = 0; t < 8; t++) {
            int bi = -1; float bv = -1.f;
            for (int e = 0; e < 16; e++) if (!sel[e] && p[e] > bv) { bv = p[e]; bi = e; }
            sel[bi] = true; ssum += bv;
        }
        for (int e = 0; e < 16; e++)
            wdense[(size_t)e * 4096 + tok] = sel[e] ? p[e] / ssum : 0.f;
    }
}

// ---------------------------------------------------------------- launch

extern "C" void kernel_launch(void* const* d_in, const int* in_sizes, int n_in,
                              void* d_out, int out_size, void* d_ws, size_t ws_size,
                              hipStream_t stream)
{
    const float* x        = (const float*)d_in[0];
    const float* cosb     = (const float*)d_in[1];
    const float* sinb     = (const float*)d_in[2];
    const float* nattn    = (const float*)d_in[3];
    const float* q_w      = (const float*)d_in[4];
    const float* k_w      = (const float*)d_in[5];
    const float* v_w      = (const float*)d_in[6];
    const float* qn_w     = (const float*)d_in[7];
    const float* kn_w     = (const float*)d_in[8];
    const float* o_w      = (const float*)d_in[9];
    const float* nmlp     = (const float*)d_in[10];
    const float* router_w = (const float*)d_in[11];
    const float* egw      = (const float*)d_in[12];
    const float* euw      = (const float*)d_in[13];
    const float* edw      = (const float*)d_in[14];

    char* w = (char*)d_ws;
    _Float16* qkvw_h = (_Float16*)(w + 0);          // 20.97 MB
    _Float16* ow_h   = (_Float16*)(w + 20971520);   // 16.78 MB
    _Float16* guw_h  = (_Float16*)(w + 37748736);   // 16.78 MB
    _Float16* dwc_h  = (_Float16*)(w + 54525952);   //  8.39 MB
    _Float16* h_h    = (_Float16*)(w + 62914560);   // 16.78 MB (aliased hm_h)
    _Float16* hm_h   = h_h;
    float*    x2     = (float*)(w + 79691776);      // 33.55 MB
    _Float16* qkv_h  = (_Float16*)(w + 113246208);  // 41.94 MB (alias o_h, ab_h)
    _Float16* o_h    = qkv_h;
    _Float16* ab_h   = qkv_h;
    _Float16* q_h    = (_Float16*)(w + 155189248);  // 33.55 MB (alias gucat)
    _Float16* gucat  = (_Float16*)(w + 155189248);
    _Float16* k_h    = (_Float16*)(w + 188743680);  //  4.19 MB
    _Float16* vt_h   = (_Float16*)(w + 192937984);  //  4.19 MB
    float*    wdense = (float*)(w + 197132288);     //  0.26 MB

    k_cast4<<<18432, 256, 0, stream>>>(q_w, k_w, v_w, o_w, qkvw_h, ow_h);
    k_cast_guw<<<4096, 256, 0, stream>>>(egw, euw, guw_h);
    k_cast_dw<<<4096, 256, 0, stream>>>(edw, dwc_h);

    k_rmsnorm<<<4096, 256, 0, stream>>>(x, nattn, h_h);
    k_gemm<<<dim3(32, 40), 256, 0, stream>>>(h_h, 2048, qkvw_h, 2048,
                                             nullptr, qkv_h, 5120, nullptr, 2048);
    k_qkv_post<<<dim3(4096, 9), 256, 0, stream>>>(qkv_h, cosb, sinb, qn_w, kn_w, q_h, k_h);
    k_vt<<<dim3(16, 16, 2), 256, 0, stream>>>(qkv_h, vt_h);
    k_attn<<<dim3(128, 16), 256, 0, stream>>>(q_h, k_h, vt_h, o_h);
    k_gemm<<<dim3(32, 16), 256, 0, stream>>>(o_h, 4096, ow_h, 4096,
                                             x2, nullptr, 2048, x, 4096);
    k_rmsnorm<<<4096, 256, 0, stream>>>(x2, nmlp, hm_h);
    k_router<<<1024, 256, 0, stream>>>(x2, nmlp, router_w, wdense);
    // gate/up as one 256^2-tile GEMM (grid 16x16 = 256 blocks = 1/CU)
    k_gemm8<<<dim3(16, 16), 512, 0, stream>>>(hm_h, 2048, guw_h, 2048, gucat, 4096, 2048);
    k_gu_comb<<<4096, 256, 0, stream>>>(gucat, wdense, ab_h);
    k_gemm<<<dim3(32, 16), 256, 0, stream>>>(ab_h, 2048, dwc_h, 2048,
                                             (float*)d_out, nullptr, 2048, x2, 2048);

    (void)in_sizes; (void)n_in; (void)out_size; (void)ws_size;
}

// Round 10
// 528.394 us; speedup vs baseline: 1.2677x; 1.0310x over previous
//
#include <hip/hip_runtime.h>
#include <stdint.h>

typedef _Float16 f16x8 __attribute__((ext_vector_type(8)));
typedef _Float16 f16x4 __attribute__((ext_vector_type(4)));
typedef float    f32x4 __attribute__((ext_vector_type(4)));

__device__ __forceinline__ void load16_lds(const _Float16* g, _Float16* l) {
    __builtin_amdgcn_global_load_lds(
        (const __attribute__((address_space(1))) void*)g,
        (__attribute__((address_space(3))) void*)l, 16, 0, 0);
}

// ---------------------------------------------------------------- casts

__global__ void k_cast4(const float* __restrict__ q, const float* __restrict__ k,
                        const float* __restrict__ v, const float* __restrict__ o,
                        _Float16* __restrict__ qkvw, _Float16* __restrict__ ow)
{
    size_t i = ((size_t)blockIdx.x * 256 + threadIdx.x) * 4;
    const float* src; _Float16* dst;
    if (i < 8388608)        { src = q + i;            dst = qkvw + i; }
    else if (i < 9437184)   { src = k + (i - 8388608); dst = qkvw + i; }
    else if (i < 10485760)  { src = v + (i - 9437184); dst = qkvw + i; }
    else                    { src = o + (i - 10485760); dst = ow + (i - 10485760); }
    float4 x = *reinterpret_cast<const float4*>(src);
    f16x4 y = { (_Float16)x.x, (_Float16)x.y, (_Float16)x.z, (_Float16)x.w };
    *reinterpret_cast<f16x4*>(dst) = y;
}

// edw[e][dm][mi] (f32) -> dwc[dm][e*128+mi] (f16)
__global__ void k_cast_dw(const float* __restrict__ edw, _Float16* __restrict__ dwc) {
    int t = blockIdx.x * 256 + threadIdx.x;
    int mi4 = (t & 31) * 4;
    int dm = (t >> 5) & 2047;
    int e = t >> 16;
    float4 v = *reinterpret_cast<const float4*>(edw + (((size_t)e * 2048 + dm) << 7) + mi4);
    f16x4 o = { (_Float16)v.x, (_Float16)v.y, (_Float16)v.z, (_Float16)v.w };
    *reinterpret_cast<f16x4*>(dwc + ((size_t)dm << 11) + e * 128 + mi4) = o;
}

// egw/euw[e][mi][k] -> guw[e*256 + half*128 + mi][k] (f16)
__global__ __launch_bounds__(256) void k_cast_guw(
    const float* __restrict__ eg, const float* __restrict__ eu,
    _Float16* __restrict__ out)
{
    const int row = blockIdx.x;                // 0..4095
    const int e = row >> 8, rem = row & 255, half = rem >> 7, mi = rem & 127;
    const float* src = (half ? eu : eg) + ((size_t)(e * 128 + mi)) * 2048;
    const int c = threadIdx.x * 8;
    float4 v0 = *reinterpret_cast<const float4*>(src + c);
    float4 v1 = *reinterpret_cast<const float4*>(src + c + 4);
    f16x8 o = { (_Float16)v0.x,(_Float16)v0.y,(_Float16)v0.z,(_Float16)v0.w,
                (_Float16)v1.x,(_Float16)v1.y,(_Float16)v1.z,(_Float16)v1.w };
    *reinterpret_cast<f16x8*>(out + (size_t)row * 2048 + c) = o;
}

// ---------------------------------------------------------------- rmsnorm (f16 out)
__global__ __launch_bounds__(256) void k_rmsnorm(
    const float* __restrict__ x, const float* __restrict__ w,
    _Float16* __restrict__ oh)
{
    const int row = blockIdx.x, tid = threadIdx.x;
    const float* xr = x + (size_t)row * 2048;
    float4 a = *reinterpret_cast<const float4*>(xr + tid * 8);
    float4 b = *reinterpret_cast<const float4*>(xr + tid * 8 + 4);
    float ss = a.x*a.x + a.y*a.y + a.z*a.z + a.w*a.w
             + b.x*b.x + b.y*b.y + b.z*b.z + b.w*b.w;
    #pragma unroll
    for (int m = 1; m < 64; m <<= 1) ss += __shfl_xor(ss, m);
    __shared__ float red[4];
    if ((tid & 63) == 0) red[tid >> 6] = ss;
    __syncthreads();
    float tot = red[0] + red[1] + red[2] + red[3];
    float r = rsqrtf(tot * (1.f / 2048.f) + 1e-6f);
    float4 wa = *reinterpret_cast<const float4*>(w + tid * 8);
    float4 wb = *reinterpret_cast<const float4*>(w + tid * 8 + 4);
    f16x8 hv = { (_Float16)(a.x*r*wa.x), (_Float16)(a.y*r*wa.y),
                 (_Float16)(a.z*r*wa.z), (_Float16)(a.w*r*wa.w),
                 (_Float16)(b.x*r*wb.x), (_Float16)(b.y*r*wb.y),
                 (_Float16)(b.z*r*wb.z), (_Float16)(b.w*r*wb.w) };
    *reinterpret_cast<f16x8*>(oh + (size_t)row * 2048 + tid * 8) = hv;
}

// ---------------------------------------------------------------- GEMM 128x128
// 3-buf counted-vmcnt, XOR-swizzled both sides (proven structure).
__global__ __launch_bounds__(256) void k_gemm(
    const _Float16* __restrict__ A, int lda,
    const _Float16* __restrict__ W, int ldw,
    float* __restrict__ Cf, _Float16* __restrict__ Ch, int ldc,
    const float* __restrict__ resid, int K)
{
    __shared__ __align__(16) _Float16 As[3][128][32];
    __shared__ __align__(16) _Float16 Ws[3][128][32];
    const int r0 = blockIdx.x * 128, c0 = blockIdx.y * 128;
    const int tid = threadIdx.x, lane = tid & 63, wid = tid >> 6;
    const int wr = wid >> 1, wc = wid & 1;
    const int sr = lane >> 2;
    const int scs = ((lane & 3) ^ ((lane >> 3) & 3)) * 8;
    const int fr = lane & 15;
    const int rks = (((lane >> 4) ^ ((fr >> 1) & 3))) * 8;
    const f32x4 z4 = { 0.f, 0.f, 0.f, 0.f };
    f32x4 acc[4][4];
    #pragma unroll
    for (int i = 0; i < 4; i++)
        #pragma unroll
        for (int j = 0; j < 4; j++) acc[i][j] = z4;

    auto stage = [&](int bf, int k0) {
        #pragma unroll
        for (int i = 0; i < 2; i++) {
            int ch = wid * 2 + i;
            load16_lds(A + (size_t)(r0 + ch * 16 + sr) * lda + k0 + scs, &As[bf][ch * 16][0]);
            load16_lds(W + (size_t)(c0 + ch * 16 + sr) * ldw + k0 + scs, &Ws[bf][ch * 16][0]);
        }
    };

    const int nt = K >> 5;
    stage(0, 0);
    if (nt > 1) stage(1, 32);
    int cur = 0;
    for (int t = 0; t < nt; t++) {
        if (t < nt - 1) asm volatile("s_waitcnt vmcnt(4)" ::: "memory");
        else            asm volatile("s_waitcnt vmcnt(0)" ::: "memory");
        __builtin_amdgcn_s_barrier();
        f16x8 af[4], bf4[4];
        #pragma unroll
        for (int i = 0; i < 4; i++)
            af[i] = *reinterpret_cast<const f16x8*>(&As[cur][wr * 64 + i * 16 + fr][rks]);
        #pragma unroll
        for (int j = 0; j < 4; j++)
            bf4[j] = *reinterpret_cast<const f16x8*>(&Ws[cur][wc * 64 + j * 16 + fr][rks]);
        if (t + 2 < nt) stage((t + 2) % 3, (t + 2) << 5);
        __builtin_amdgcn_s_setprio(1);
        #pragma unroll
        for (int i = 0; i < 4; i++)
            #pragma unroll
            for (int j = 0; j < 4; j++)
                acc[i][j] = __builtin_amdgcn_mfma_f32_16x16x32_f16(af[i], bf4[j], acc[i][j], 0, 0, 0);
        __builtin_amdgcn_s_setprio(0);
        cur = (cur + 1) % 3;
    }
    #pragma unroll
    for (int i = 0; i < 4; i++) {
        const int rowb = r0 + wr * 64 + i * 16 + (lane >> 4) * 4;
        #pragma unroll
        for (int j = 0; j < 4; j++) {
            const int col = c0 + wc * 64 + j * 16 + fr;
            #pragma unroll
            for (int r = 0; r < 4; r++) {
                size_t idx = (size_t)(rowb + r) * ldc + col;
                float v = acc[i][j][r];
                if (resid) v += resid[idx];
                if (Ch) Ch[idx] = (_Float16)v;
                else    Cf[idx] = v;
            }
        }
    }
}

// ---------------------------------------------------------------- GEMM 256x256, 8 waves
// Wave-tile 128x64. 3-ring counted-vmcnt + both-sides swizzle. f16 out.
__global__ __launch_bounds__(512, 2) void k_gemm8(
    const _Float16* __restrict__ A, int lda,
    const _Float16* __restrict__ W, int ldw,
    _Float16* __restrict__ Ch, int ldc, int K)
{
    __shared__ __align__(16) _Float16 As[3][256][32];   // 48 KB
    __shared__ __align__(16) _Float16 Ws[3][256][32];   // 48 KB
    const int r0 = blockIdx.x * 256, c0 = blockIdx.y * 256;
    const int tid = threadIdx.x, lane = tid & 63, wid = tid >> 6;
    const int wr = wid >> 2, wc = wid & 3;              // 2M x 4N wave grid
    const int rA = lane >> 2;
    const int scs = ((lane & 3) ^ ((lane >> 3) & 3)) * 8;
    const int fr = lane & 15;
    const int rks = (((lane >> 4) ^ ((fr >> 1) & 3))) * 8;
    const f32x4 z4 = { 0.f, 0.f, 0.f, 0.f };
    f32x4 acc[8][4];
    #pragma unroll
    for (int i = 0; i < 8; i++)
        #pragma unroll
        for (int j = 0; j < 4; j++) acc[i][j] = z4;

    auto stage = [&](int bf, int k0) {
        #pragma unroll
        for (int i = 0; i < 2; i++) {
            load16_lds(A + (size_t)(r0 + i * 128 + wid * 16 + rA) * lda + k0 + scs,
                       &As[bf][i * 128 + wid * 16][0]);
            load16_lds(W + (size_t)(c0 + i * 128 + wid * 16 + rA) * ldw + k0 + scs,
                       &Ws[bf][i * 128 + wid * 16][0]);
        }
    };

    const int nt = K >> 5;
    stage(0, 0);
    if (nt > 1) stage(1, 32);
    int cur = 0;
    for (int t = 0; t < nt; t++) {
        if (t < nt - 1) asm volatile("s_waitcnt vmcnt(4)" ::: "memory");
        else            asm volatile("s_waitcnt vmcnt(0)" ::: "memory");
        __builtin_amdgcn_s_barrier();
        f16x8 af[8], bf4[4];
        #pragma unroll
        for (int i = 0; i < 8; i++)
            af[i] = *reinterpret_cast<const f16x8*>(&As[cur][wr * 128 + i * 16 + fr][rks]);
        #pragma unroll
        for (int j = 0; j < 4; j++)
            bf4[j] = *reinterpret_cast<const f16x8*>(&Ws[cur][wc * 64 + j * 16 + fr][rks]);
        if (t + 2 < nt) stage((t + 2) % 3, (t + 2) << 5);
        __builtin_amdgcn_s_setprio(1);
        #pragma unroll
        for (int i = 0; i < 8; i++)
            #pragma unroll
            for (int j = 0; j < 4; j++)
                acc[i][j] = __builtin_amdgcn_mfma_f32_16x16x32_f16(af[i], bf4[j], acc[i][j], 0, 0, 0);
        __builtin_amdgcn_s_setprio(0);
        cur = (cur + 1) % 3;
    }
    #pragma unroll
    for (int i = 0; i < 8; i++) {
        const int rowb = r0 + wr * 128 + i * 16 + (lane >> 4) * 4;
        #pragma unroll
        for (int j = 0; j < 4; j++) {
            const int col = c0 + wc * 64 + j * 16 + fr;
            #pragma unroll
            for (int r = 0; r < 4; r++)
                Ch[(size_t)(rowb + r) * ldc + col] = (_Float16)acc[i][j][r];
        }
    }
}

// ---------------------------------------------------------------- gate/up combine
__global__ __launch_bounds__(256) void k_gu_comb(
    const _Float16* __restrict__ gucat, const float* __restrict__ wdense,
    _Float16* __restrict__ ab)
{
    const int tok = blockIdx.x;
    const int idx = threadIdx.x;
    const int e = idx >> 4, mi8 = (idx & 15) * 8;
    const _Float16* gp = gucat + (size_t)tok * 4096 + e * 256 + mi8;
    f16x8 gv = *reinterpret_cast<const f16x8*>(gp);
    f16x8 uv = *reinterpret_cast<const f16x8*>(gp + 128);
    float wv = wdense[(size_t)e * 4096 + tok];
    f16x8 o;
    #pragma unroll
    for (int j = 0; j < 8; j++) {
        float g = (float)gv[j], u = (float)uv[j];
        float sil = g / (1.f + __expf(-g));
        o[j] = (_Float16)(sil * u * wv);
    }
    *reinterpret_cast<f16x8*>(ab + (size_t)tok * 2048 + e * 128 + mi8) = o;
}

// ------------------------------------------- per-head RMSNorm + RoPE (wave-per-head)
__global__ __launch_bounds__(256) void k_qkv_post(
    const _Float16* __restrict__ qkv,
    const float* __restrict__ cosb, const float* __restrict__ sinb,
    const float* __restrict__ qn_w, const float* __restrict__ kn_w,
    _Float16* __restrict__ qh, _Float16* __restrict__ kh)
{
    const int tok = blockIdx.x;
    const int u = blockIdx.y * 4 + (threadIdx.x >> 6);
    const int lane = threadIdx.x & 63;
    const int b = tok >> 10, l = tok & 1023;
    const float c0 = cosb[(size_t)tok * 128 + lane];
    const float c1 = cosb[(size_t)tok * 128 + lane + 64];
    const float s0 = sinb[(size_t)tok * 128 + lane];
    const float s1 = sinb[(size_t)tok * 128 + lane + 64];
    if (u < 32) {
        const _Float16* base = qkv + (size_t)tok * 5120 + u * 128;
        float v0 = (float)base[lane], v1 = (float)base[lane + 64];
        float ss = v0 * v0 + v1 * v1;
        #pragma unroll
        for (int m = 1; m < 64; m <<= 1) ss += __shfl_xor(ss, m);
        float rms = rsqrtf(ss * (1.f / 128.f) + 1e-6f);
        float n0 = v0 * rms * qn_w[lane], n1 = v1 * rms * qn_w[lane + 64];
        _Float16* o = qh + (size_t)tok * 4096 + u * 128;
        o[lane]      = (_Float16)(c0 * n0 - s0 * n1);
        o[lane + 64] = (_Float16)(c1 * n1 + s1 * n0);
    } else {
        const int kvh = u - 32;
        const _Float16* base = qkv + (size_t)tok * 5120 + 4096 + kvh * 128;
        float v0 = (float)base[lane], v1 = (float)base[lane + 64];
        float ss = v0 * v0 + v1 * v1;
        #pragma unroll
        for (int m = 1; m < 64; m <<= 1) ss += __shfl_xor(ss, m);
        float rms = rsqrtf(ss * (1.f / 128.f) + 1e-6f);
        float n0 = v0 * rms * kn_w[lane], n1 = v1 * rms * kn_w[lane + 64];
        _Float16* o = kh + (((size_t)(b * 4 + kvh)) * 1024 + l) * 128;
        o[lane]      = (_Float16)(c0 * n0 - s0 * n1);
        o[lane + 64] = (_Float16)(c1 * n1 + s1 * n0);
    }
}

// ---------------------------------------------------------------- V transpose
__global__ __launch_bounds__(256) void k_vt(
    const _Float16* __restrict__ qkv, _Float16* __restrict__ vth)
{
    const int bkv = blockIdx.x;
    const int b = bkv >> 2, kv = bkv & 3;
    const int l0 = blockIdx.y * 64, d0 = blockIdx.z * 64;
    __shared__ _Float16 T[64][72];
    const int t = threadIdx.x;
    const int r = t >> 3, c8 = (t & 7) * 8;
    #pragma unroll
    for (int rr = 0; rr < 2; rr++) {
        int l = l0 + r + rr * 32;
        *reinterpret_cast<f16x8*>(&T[r + rr * 32][c8]) =
            *reinterpret_cast<const f16x8*>(
                qkv + (size_t)(b * 1024 + l) * 5120 + 4608 + kv * 128 + d0 + c8);
    }
    __syncthreads();
    #pragma unroll
    for (int rr = 0; rr < 2; rr++) {
        int d = d0 + r + rr * 32;
        f16x8 v;
        #pragma unroll
        for (int j = 0; j < 8; j++) v[j] = T[c8 + j][r + rr * 32];
        *reinterpret_cast<f16x8*>(vth + ((size_t)(bkv * 128 + d)) * 1024 + l0 + c8) = v;
    }
}

// ---------------------------------------------------------------- attention
__global__ __launch_bounds__(256) void k_attn(
    const _Float16* __restrict__ qh, const _Float16* __restrict__ kh,
    const _Float16* __restrict__ vth, _Float16* __restrict__ oh)
{
    const int bh = blockIdx.x;
    const int g = 15 - blockIdx.y;
    const int b = bh >> 5, h = bh & 31, kv = h >> 3;
    const int tid = threadIdx.x, lane = tid & 63, wid = tid >> 6;
    const int fr = lane & 15, fg = lane >> 4;
    const int q0w = g * 64 + wid * 16;

    __shared__ __align__(16) _Float16 Ks[64][128];
    __shared__ __align__(16) _Float16 Vs[128][64];
    __shared__ __align__(16) _Float16 Ps[4][16][72];

    const _Float16* kb = kh + ((size_t)(b * 4 + kv)) * 1024 * 128;
    const _Float16* vb = vth + ((size_t)(b * 4 + kv)) * 128 * 1024;

    f16x8 aq[4];
    {
        const _Float16* qbase = qh + ((size_t)(b * 1024 + q0w + fr)) * 4096 + h * 128;
        #pragma unroll
        for (int kk = 0; kk < 4; kk++)
            aq[kk] = *reinterpret_cast<const f16x8*>(qbase + kk * 32 + fg * 8);
    }

    float m_r[4] = { -1e30f, -1e30f, -1e30f, -1e30f };
    float l_r[4] = { 0.f, 0.f, 0.f, 0.f };
    const f32x4 z4 = { 0.f, 0.f, 0.f, 0.f };
    f32x4 oacc[8];
    #pragma unroll
    for (int dj = 0; dj < 8; dj++) oacc[dj] = z4;

    const int ntiles = g + 1;
    for (int kt = 0; kt < ntiles; kt++) {
        const int key0 = kt * 64;
        #pragma unroll
        for (int i = 0; i < 4; i++) {
            int rr = 16 * wid + 4 * i + (lane >> 4);
            int c16 = (lane & 15) ^ (rr & 7);
            load16_lds(kb + (size_t)(key0 + rr) * 128 + c16 * 8,
                       &Ks[0][0] + (16 * wid + 4 * i) * 128);
        }
        #pragma unroll
        for (int i = 0; i < 4; i++) {
            int rr = 32 * wid + 8 * i + (lane >> 3);
            int c16 = (lane & 7) ^ (rr & 7);
            load16_lds(vb + (size_t)rr * 1024 + key0 + c16 * 8,
                       &Vs[0][0] + (32 * wid + 8 * i) * 64);
        }
        __syncthreads();

        f32x4 sc[4];
        #pragma unroll
        for (int j = 0; j < 4; j++) sc[j] = z4;
        #pragma unroll
        for (int j = 0; j < 4; j++) {
            #pragma unroll
            for (int kk = 0; kk < 4; kk++) {
                f16x8 bk = *reinterpret_cast<const f16x8*>(
                    &Ks[0][0] + (j * 16 + fr) * 128 + (((kk * 4 + fg) ^ (fr & 7)) * 8));
                sc[j] = __builtin_amdgcn_mfma_f32_16x16x32_f16(aq[kk], bk, sc[j], 0, 0, 0);
            }
        }

        const bool lastt = (kt == ntiles - 1);
        float pmax[4] = { -1e30f, -1e30f, -1e30f, -1e30f };
        #pragma unroll
        for (int j = 0; j < 4; j++) {
            const int key = key0 + j * 16 + fr;
            #pragma unroll
            for (int r = 0; r < 4; r++) {
                float v = sc[j][r] * 0.08838834764831845f;
                if (lastt && key > q0w + fg * 4 + r) v = -1e30f;
                sc[j][r] = v;
                pmax[r] = fmaxf(pmax[r], v);
            }
        }
        #pragma unroll
        for (int m = 1; m < 16; m <<= 1)
            #pragma unroll
            for (int r = 0; r < 4; r++) pmax[r] = fmaxf(pmax[r], __shfl_xor(pmax[r], m));
        float alpha[4];
        #pragma unroll
        for (int r = 0; r < 4; r++) {
            float mn = fmaxf(m_r[r], pmax[r]);
            alpha[r] = __expf(m_r[r] - mn);
            m_r[r] = mn;
        }
        float rs[4] = { 0.f, 0.f, 0.f, 0.f };
        #pragma unroll
        for (int j = 0; j < 4; j++)
            #pragma unroll
            for (int r = 0; r < 4; r++) {
                float p = __expf(sc[j][r] - m_r[r]);
                sc[j][r] = p;
                rs[r] += p;
            }
        #pragma unroll
        for (int m = 1; m < 16; m <<= 1)
            #pragma unroll
            for (int r = 0; r < 4; r++) rs[r] += __shfl_xor(rs[r], m);
        #pragma unroll
        for (int r = 0; r < 4; r++) l_r[r] = l_r[r] * alpha[r] + rs[r];
        #pragma unroll
        for (int dj = 0; dj < 8; dj++)
            #pragma unroll
            for (int r = 0; r < 4; r++) oacc[dj][r] *= alpha[r];

        #pragma unroll
        for (int j = 0; j < 4; j++)
            #pragma unroll
            for (int r = 0; r < 4; r++)
                Ps[wid][fg * 4 + r][j * 16 + fr] = (_Float16)sc[j][r];

        #pragma unroll
        for (int ks = 0; ks < 2; ks++) {
            f16x8 ap = *reinterpret_cast<const f16x8*>(&Ps[wid][fr][ks * 32 + fg * 8]);
            #pragma unroll
            for (int dj = 0; dj < 8; dj++) {
                f16x8 bv = *reinterpret_cast<const f16x8*>(
                    &Vs[0][0] + (dj * 16 + fr) * 64 + (((ks * 4 + fg) ^ (fr & 7)) * 8));
                oacc[dj] = __builtin_amdgcn_mfma_f32_16x16x32_f16(ap, bv, oacc[dj], 0, 0, 0);
            }
        }
        __syncthreads();
    }

    float inv[4];
    #pragma unroll
    for (int r = 0; r < 4; r++) inv[r] = 1.f / l_r[r];
    #pragma unroll
    for (int dj = 0; dj < 8; dj++)
        #pragma unroll
        for (int r = 0; r < 4; r++)
            oh[((size_t)(b * 1024 + q0w + fg * 4 + r)) * 4096 + h * 128 + dj * 16 + fr] =
                (_Float16)(oacc[dj][r] * inv[r]);
}

// ---------------------------------------------------------------- router (inline rmsnorm from x2)
__global__ __launch_bounds__(256) void k_router(
    const float* __restrict__ x2, const float* __restrict__ wm,
    const float* __restrict__ rw, float* __restrict__ wdense)
{
    const int tok = blockIdx.x * 4 + (threadIdx.x >> 6);
    const int lane = threadIdx.x & 63;
    __shared__ float lg[4][16];
    const float* hr = x2 + (size_t)tok * 2048;
    float vals[32];
    float ss = 0.f;
    #pragma unroll
    for (int i = 0; i < 32; i++) { float v = hr[i * 64 + lane]; vals[i] = v; ss += v * v; }
    #pragma unroll
    for (int m = 1; m < 64; m <<= 1) ss += __shfl_xor(ss, m);
    float r = rsqrtf(ss * (1.f / 2048.f) + 1e-6f);
    #pragma unroll
    for (int i = 0; i < 32; i++) vals[i] *= r * wm[i * 64 + lane];
    for (int e = 0; e < 16; e++) {
        float acc = 0.f;
        #pragma unroll
        for (int i = 0; i < 32; i++) acc += vals[i] * rw[(size_t)e * 2048 + i * 64 + lane];
        #pragma unroll
        for (int m = 1; m < 64; m <<= 1) acc += __shfl_xor(acc, m);
        if (lane == 0) lg[threadIdx.x >> 6][e] = acc;
    }
    __syncthreads();
    if (lane == 0) {
        float* l = lg[threadIdx.x >> 6];
        float mx = l[0];
        for (int e = 1; e < 16; e++) mx = fmaxf(mx, l[e]);
        float p[16]; float sum = 0.f;
        for (int e = 0; e < 16; e++) { p[e] = expf(l[e] - mx); sum += p[e]; }
        for (int e = 0; e < 16; e++) p[e] /= sum;
        bool sel[16]; for (int e = 0; e < 16; e++) sel[e] = false;
        float ssum = 0.f;
        for (int t = 0; t < 8; t++) {
            int bi = -1; float bv = -1.f;
            for (int e = 0; e < 16; e++) if (!sel[e] && p[e] > bv) { bv = p[e]; bi = e; }
            sel[bi] = true; ssum += bv;
        }
        for (int e = 0; e < 16; e++)
            wdense[(size_t)e * 4096 + tok] = sel[e] ? p[e] / ssum : 0.f;
    }
}

// ---------------------------------------------------------------- launch

extern "C" void kernel_launch(void* const* d_in, const int* in_sizes, int n_in,
                              void* d_out, int out_size, void* d_ws, size_t ws_size,
                              hipStream_t stream)
{
    const float* x        = (const float*)d_in[0];
    const float* cosb     = (const float*)d_in[1];
    const float* sinb     = (const float*)d_in[2];
    const float* nattn    = (const float*)d_in[3];
    const float* q_w      = (const float*)d_in[4];
    const float* k_w      = (const float*)d_in[5];
    const float* v_w      = (const float*)d_in[6];
    const float* qn_w     = (const float*)d_in[7];
    const float* kn_w     = (const float*)d_in[8];
    const float* o_w      = (const float*)d_in[9];
    const float* nmlp     = (const float*)d_in[10];
    const float* router_w = (const float*)d_in[11];
    const float* egw      = (const float*)d_in[12];
    const float* euw      = (const float*)d_in[13];
    const float* edw      = (const float*)d_in[14];

    char* w = (char*)d_ws;
    _Float16* qkvw_h = (_Float16*)(w + 0);          // 20.97 MB
    _Float16* ow_h   = (_Float16*)(w + 20971520);   // 16.78 MB
    _Float16* guw_h  = (_Float16*)(w + 37748736);   // 16.78 MB
    _Float16* dwc_h  = (_Float16*)(w + 54525952);   //  8.39 MB
    _Float16* h_h    = (_Float16*)(w + 62914560);   // 16.78 MB (aliased hm_h)
    _Float16* hm_h   = h_h;
    float*    x2     = (float*)(w + 79691776);      // 33.55 MB
    _Float16* qkv_h  = (_Float16*)(w + 113246208);  // 41.94 MB (alias o_h, ab_h)
    _Float16* o_h    = qkv_h;
    _Float16* ab_h   = qkv_h;
    _Float16* q_h    = (_Float16*)(w + 155189248);  // 33.55 MB (alias gucat)
    _Float16* gucat  = (_Float16*)(w + 155189248);
    _Float16* k_h    = (_Float16*)(w + 188743680);  //  4.19 MB
    _Float16* vt_h   = (_Float16*)(w + 192937984);  //  4.19 MB
    float*    wdense = (float*)(w + 197132288);     //  0.26 MB

    k_cast4<<<18432, 256, 0, stream>>>(q_w, k_w, v_w, o_w, qkvw_h, ow_h);
    k_cast_guw<<<4096, 256, 0, stream>>>(egw, euw, guw_h);
    k_cast_dw<<<4096, 256, 0, stream>>>(edw, dwc_h);

    k_rmsnorm<<<4096, 256, 0, stream>>>(x, nattn, h_h);
    // QKV projection split: 256^2 kernel on Q cols [0,4096), 128^2 on K/V cols [4096,5120)
    k_gemm8<<<dim3(16, 16), 512, 0, stream>>>(h_h, 2048, qkvw_h, 2048, qkv_h, 5120, 2048);
    k_gemm<<<dim3(32, 8), 256, 0, stream>>>(h_h, 2048, qkvw_h + (size_t)4096 * 2048, 2048,
                                            nullptr, qkv_h + 4096, 5120, nullptr, 2048);
    k_qkv_post<<<dim3(4096, 9), 256, 0, stream>>>(qkv_h, cosb, sinb, qn_w, kn_w, q_h, k_h);
    k_vt<<<dim3(16, 16, 2), 256, 0, stream>>>(qkv_h, vt_h);
    k_attn<<<dim3(128, 16), 256, 0, stream>>>(q_h, k_h, vt_h, o_h);
    k_gemm<<<dim3(32, 16), 256, 0, stream>>>(o_h, 4096, ow_h, 4096,
                                             x2, nullptr, 2048, x, 4096);
    k_rmsnorm<<<4096, 256, 0, stream>>>(x2, nmlp, hm_h);
    k_router<<<1024, 256, 0, stream>>>(x2, nmlp, router_w, wdense);
    k_gemm8<<<dim3(16, 16), 512, 0, stream>>>(hm_h, 2048, guw_h, 2048, gucat, 4096, 2048);
    k_gu_comb<<<4096, 256, 0, stream>>>(gucat, wdense, ab_h);
    k_gemm<<<dim3(32, 16), 256, 0, stream>>>(ab_h, 2048, dwc_h, 2048,
                                             (float*)d_out, nullptr, 2048, x2, 2048);

    (void)in_sizes; (void)n_in; (void)out_size; (void)ws_size;
}

// Round 11
// 512.596 us; speedup vs baseline: 1.3067x; 1.0308x over previous
//
#include <hip/hip_runtime.h>
#include <stdint.h>

typedef _Float16 f16x8 __attribute__((ext_vector_type(8)));
typedef _Float16 f16x4 __attribute__((ext_vector_type(4)));
typedef float    f32x4 __attribute__((ext_vector_type(4)));

__device__ __forceinline__ void load16_lds(const _Float16* g, _Float16* l) {
    __builtin_amdgcn_global_load_lds(
        (const __attribute__((address_space(1))) void*)g,
        (__attribute__((address_space(3))) void*)l, 16, 0, 0);
}

// ---------------------------------------------------------------- casts

__global__ void k_cast4(const float* __restrict__ q, const float* __restrict__ k,
                        const float* __restrict__ v, const float* __restrict__ o,
                        _Float16* __restrict__ qkvw, _Float16* __restrict__ ow)
{
    size_t i = ((size_t)blockIdx.x * 256 + threadIdx.x) * 4;
    const float* src; _Float16* dst;
    if (i < 8388608)        { src = q + i;            dst = qkvw + i; }
    else if (i < 9437184)   { src = k + (i - 8388608); dst = qkvw + i; }
    else if (i < 10485760)  { src = v + (i - 9437184); dst = qkvw + i; }
    else                    { src = o + (i - 10485760); dst = ow + (i - 10485760); }
    float4 x = *reinterpret_cast<const float4*>(src);
    f16x4 y = { (_Float16)x.x, (_Float16)x.y, (_Float16)x.z, (_Float16)x.w };
    *reinterpret_cast<f16x4*>(dst) = y;
}

// edw[e][dm][mi] (f32) -> dwc[dm][e*128+mi] (f16)
__global__ void k_cast_dw(const float* __restrict__ edw, _Float16* __restrict__ dwc) {
    int t = blockIdx.x * 256 + threadIdx.x;
    int mi4 = (t & 31) * 4;
    int dm = (t >> 5) & 2047;
    int e = t >> 16;
    float4 v = *reinterpret_cast<const float4*>(edw + (((size_t)e * 2048 + dm) << 7) + mi4);
    f16x4 o = { (_Float16)v.x, (_Float16)v.y, (_Float16)v.z, (_Float16)v.w };
    *reinterpret_cast<f16x4*>(dwc + ((size_t)dm << 11) + e * 128 + mi4) = o;
}

// egw/euw[e][mi][k] -> guw[e*256 + half*128 + mi][k] (f16)
__global__ __launch_bounds__(256) void k_cast_guw(
    const float* __restrict__ eg, const float* __restrict__ eu,
    _Float16* __restrict__ out)
{
    const int row = blockIdx.x;
    const int e = row >> 8, rem = row & 255, half = rem >> 7, mi = rem & 127;
    const float* src = (half ? eu : eg) + ((size_t)(e * 128 + mi)) * 2048;
    const int c = threadIdx.x * 8;
    float4 v0 = *reinterpret_cast<const float4*>(src + c);
    float4 v1 = *reinterpret_cast<const float4*>(src + c + 4);
    f16x8 o = { (_Float16)v0.x,(_Float16)v0.y,(_Float16)v0.z,(_Float16)v0.w,
                (_Float16)v1.x,(_Float16)v1.y,(_Float16)v1.z,(_Float16)v1.w };
    *reinterpret_cast<f16x8*>(out + (size_t)row * 2048 + c) = o;
}

// ones/zeros block for the l-column trick: row 0 = 1.0, rows 1..15 = 0.0 (16x1024 f16)
__global__ void k_ones(_Float16* __restrict__ p) {
    int i = blockIdx.x * 256 + threadIdx.x;   // 4096 threads x 4 elems
    _Float16 v = (i < 256) ? (_Float16)1.0f : (_Float16)0.0f;
    f16x4 o = { v, v, v, v };
    *reinterpret_cast<f16x4*>(p + i * 4) = o;
}

// ---------------------------------------------------------------- rmsnorm (f16 out)
__global__ __launch_bounds__(256) void k_rmsnorm(
    const float* __restrict__ x, const float* __restrict__ w,
    _Float16* __restrict__ oh)
{
    const int row = blockIdx.x, tid = threadIdx.x;
    const float* xr = x + (size_t)row * 2048;
    float4 a = *reinterpret_cast<const float4*>(xr + tid * 8);
    float4 b = *reinterpret_cast<const float4*>(xr + tid * 8 + 4);
    float ss = a.x*a.x + a.y*a.y + a.z*a.z + a.w*a.w
             + b.x*b.x + b.y*b.y + b.z*b.z + b.w*b.w;
    #pragma unroll
    for (int m = 1; m < 64; m <<= 1) ss += __shfl_xor(ss, m);
    __shared__ float red[4];
    if ((tid & 63) == 0) red[tid >> 6] = ss;
    __syncthreads();
    float tot = red[0] + red[1] + red[2] + red[3];
    float r = rsqrtf(tot * (1.f / 2048.f) + 1e-6f);
    float4 wa = *reinterpret_cast<const float4*>(w + tid * 8);
    float4 wb = *reinterpret_cast<const float4*>(w + tid * 8 + 4);
    f16x8 hv = { (_Float16)(a.x*r*wa.x), (_Float16)(a.y*r*wa.y),
                 (_Float16)(a.z*r*wa.z), (_Float16)(a.w*r*wa.w),
                 (_Float16)(b.x*r*wb.x), (_Float16)(b.y*r*wb.y),
                 (_Float16)(b.z*r*wb.z), (_Float16)(b.w*r*wb.w) };
    *reinterpret_cast<f16x8*>(oh + (size_t)row * 2048 + tid * 8) = hv;
}

// ---------------------------------------------------------------- GEMM 128x128
__global__ __launch_bounds__(256) void k_gemm(
    const _Float16* __restrict__ A, int lda,
    const _Float16* __restrict__ W, int ldw,
    float* __restrict__ Cf, _Float16* __restrict__ Ch, int ldc,
    const float* __restrict__ resid, int K)
{
    __shared__ __align__(16) _Float16 As[3][128][32];
    __shared__ __align__(16) _Float16 Ws[3][128][32];
    const int r0 = blockIdx.x * 128, c0 = blockIdx.y * 128;
    const int tid = threadIdx.x, lane = tid & 63, wid = tid >> 6;
    const int wr = wid >> 1, wc = wid & 1;
    const int sr = lane >> 2;
    const int scs = ((lane & 3) ^ ((lane >> 3) & 3)) * 8;
    const int fr = lane & 15;
    const int rks = (((lane >> 4) ^ ((fr >> 1) & 3))) * 8;
    const f32x4 z4 = { 0.f, 0.f, 0.f, 0.f };
    f32x4 acc[4][4];
    #pragma unroll
    for (int i = 0; i < 4; i++)
        #pragma unroll
        for (int j = 0; j < 4; j++) acc[i][j] = z4;

    auto stage = [&](int bf, int k0) {
        #pragma unroll
        for (int i = 0; i < 2; i++) {
            int ch = wid * 2 + i;
            load16_lds(A + (size_t)(r0 + ch * 16 + sr) * lda + k0 + scs, &As[bf][ch * 16][0]);
            load16_lds(W + (size_t)(c0 + ch * 16 + sr) * ldw + k0 + scs, &Ws[bf][ch * 16][0]);
        }
    };

    const int nt = K >> 5;
    stage(0, 0);
    if (nt > 1) stage(1, 32);
    int cur = 0;
    for (int t = 0; t < nt; t++) {
        if (t < nt - 1) asm volatile("s_waitcnt vmcnt(4)" ::: "memory");
        else            asm volatile("s_waitcnt vmcnt(0)" ::: "memory");
        __builtin_amdgcn_s_barrier();
        f16x8 af[4], bf4[4];
        #pragma unroll
        for (int i = 0; i < 4; i++)
            af[i] = *reinterpret_cast<const f16x8*>(&As[cur][wr * 64 + i * 16 + fr][rks]);
        #pragma unroll
        for (int j = 0; j < 4; j++)
            bf4[j] = *reinterpret_cast<const f16x8*>(&Ws[cur][wc * 64 + j * 16 + fr][rks]);
        if (t + 2 < nt) stage((t + 2) % 3, (t + 2) << 5);
        __builtin_amdgcn_s_setprio(1);
        #pragma unroll
        for (int i = 0; i < 4; i++)
            #pragma unroll
            for (int j = 0; j < 4; j++)
                acc[i][j] = __builtin_amdgcn_mfma_f32_16x16x32_f16(af[i], bf4[j], acc[i][j], 0, 0, 0);
        __builtin_amdgcn_s_setprio(0);
        cur = (cur + 1) % 3;
    }
    #pragma unroll
    for (int i = 0; i < 4; i++) {
        const int rowb = r0 + wr * 64 + i * 16 + (lane >> 4) * 4;
        #pragma unroll
        for (int j = 0; j < 4; j++) {
            const int col = c0 + wc * 64 + j * 16 + fr;
            #pragma unroll
            for (int r = 0; r < 4; r++) {
                size_t idx = (size_t)(rowb + r) * ldc + col;
                float v = acc[i][j][r];
                if (resid) v += resid[idx];
                if (Ch) Ch[idx] = (_Float16)v;
                else    Cf[idx] = v;
            }
        }
    }
}

// ---------------------------------------------------------------- GEMM 256x256, 8 waves
__global__ __launch_bounds__(512, 2) void k_gemm8(
    const _Float16* __restrict__ A, int lda,
    const _Float16* __restrict__ W, int ldw,
    _Float16* __restrict__ Ch, int ldc, int K)
{
    __shared__ __align__(16) _Float16 As[3][256][32];
    __shared__ __align__(16) _Float16 Ws[3][256][32];
    const int r0 = blockIdx.x * 256, c0 = blockIdx.y * 256;
    const int tid = threadIdx.x, lane = tid & 63, wid = tid >> 6;
    const int wr = wid >> 2, wc = wid & 3;
    const int rA = lane >> 2;
    const int scs = ((lane & 3) ^ ((lane >> 3) & 3)) * 8;
    const int fr = lane & 15;
    const int rks = (((lane >> 4) ^ ((fr >> 1) & 3))) * 8;
    const f32x4 z4 = { 0.f, 0.f, 0.f, 0.f };
    f32x4 acc[8][4];
    #pragma unroll
    for (int i = 0; i < 8; i++)
        #pragma unroll
        for (int j = 0; j < 4; j++) acc[i][j] = z4;

    auto stage = [&](int bf, int k0) {
        #pragma unroll
        for (int i = 0; i < 2; i++) {
            load16_lds(A + (size_t)(r0 + i * 128 + wid * 16 + rA) * lda + k0 + scs,
                       &As[bf][i * 128 + wid * 16][0]);
            load16_lds(W + (size_t)(c0 + i * 128 + wid * 16 + rA) * ldw + k0 + scs,
                       &Ws[bf][i * 128 + wid * 16][0]);
        }
    };

    const int nt = K >> 5;
    stage(0, 0);
    if (nt > 1) stage(1, 32);
    int cur = 0;
    for (int t = 0; t < nt; t++) {
        if (t < nt - 1) asm volatile("s_waitcnt vmcnt(4)" ::: "memory");
        else            asm volatile("s_waitcnt vmcnt(0)" ::: "memory");
        __builtin_amdgcn_s_barrier();
        f16x8 af[8], bf4[4];
        #pragma unroll
        for (int i = 0; i < 8; i++)
            af[i] = *reinterpret_cast<const f16x8*>(&As[cur][wr * 128 + i * 16 + fr][rks]);
        #pragma unroll
        for (int j = 0; j < 4; j++)
            bf4[j] = *reinterpret_cast<const f16x8*>(&Ws[cur][wc * 64 + j * 16 + fr][rks]);
        if (t + 2 < nt) stage((t + 2) % 3, (t + 2) << 5);
        __builtin_amdgcn_s_setprio(1);
        #pragma unroll
        for (int i = 0; i < 8; i++)
            #pragma unroll
            for (int j = 0; j < 4; j++)
                acc[i][j] = __builtin_amdgcn_mfma_f32_16x16x32_f16(af[i], bf4[j], acc[i][j], 0, 0, 0);
        __builtin_amdgcn_s_setprio(0);
        cur = (cur + 1) % 3;
    }
    #pragma unroll
    for (int i = 0; i < 8; i++) {
        const int rowb = r0 + wr * 128 + i * 16 + (lane >> 4) * 4;
        #pragma unroll
        for (int j = 0; j < 4; j++) {
            const int col = c0 + wc * 64 + j * 16 + fr;
            #pragma unroll
            for (int r = 0; r < 4; r++)
                Ch[(size_t)(rowb + r) * ldc + col] = (_Float16)acc[i][j][r];
        }
    }
}

// ---------------------------------------------------------------- gate/up combine
__global__ __launch_bounds__(256) void k_gu_comb(
    const _Float16* __restrict__ gucat, const float* __restrict__ wdense,
    _Float16* __restrict__ ab)
{
    const int tok = blockIdx.x;
    const int idx = threadIdx.x;
    const int e = idx >> 4, mi8 = (idx & 15) * 8;
    const _Float16* gp = gucat + (size_t)tok * 4096 + e * 256 + mi8;
    f16x8 gv = *reinterpret_cast<const f16x8*>(gp);
    f16x8 uv = *reinterpret_cast<const f16x8*>(gp + 128);
    float wv = wdense[(size_t)e * 4096 + tok];
    f16x8 o;
    #pragma unroll
    for (int j = 0; j < 8; j++) {
        float g = (float)gv[j], u = (float)uv[j];
        float sil = g / (1.f + __expf(-g));
        o[j] = (_Float16)(sil * u * wv);
    }
    *reinterpret_cast<f16x8*>(ab + (size_t)tok * 2048 + e * 128 + mi8) = o;
}

// ------------------------------------------- per-head RMSNorm + RoPE (wave-per-head)
// Q additionally scaled by 1/sqrt(128) * log2(e) (folded softmax scale).
__global__ __launch_bounds__(256) void k_qkv_post(
    const _Float16* __restrict__ qkv,
    const float* __restrict__ cosb, const float* __restrict__ sinb,
    const float* __restrict__ qn_w, const float* __restrict__ kn_w,
    _Float16* __restrict__ qh, _Float16* __restrict__ kh)
{
    const int tok = blockIdx.x;
    const int u = blockIdx.y * 4 + (threadIdx.x >> 6);
    const int lane = threadIdx.x & 63;
    const int b = tok >> 10, l = tok & 1023;
    const float SCL = 0.12752887074166638f;   // 0.088388347... * log2(e)
    const float c0 = cosb[(size_t)tok * 128 + lane];
    const float c1 = cosb[(size_t)tok * 128 + lane + 64];
    const float s0 = sinb[(size_t)tok * 128 + lane];
    const float s1 = sinb[(size_t)tok * 128 + lane + 64];
    if (u < 32) {
        const _Float16* base = qkv + (size_t)tok * 5120 + u * 128;
        float v0 = (float)base[lane], v1 = (float)base[lane + 64];
        float ss = v0 * v0 + v1 * v1;
        #pragma unroll
        for (int m = 1; m < 64; m <<= 1) ss += __shfl_xor(ss, m);
        float rms = rsqrtf(ss * (1.f / 128.f) + 1e-6f);
        float n0 = v0 * rms * qn_w[lane], n1 = v1 * rms * qn_w[lane + 64];
        _Float16* o = qh + (size_t)tok * 4096 + u * 128;
        o[lane]      = (_Float16)(SCL * (c0 * n0 - s0 * n1));
        o[lane + 64] = (_Float16)(SCL * (c1 * n1 + s1 * n0));
    } else {
        const int kvh = u - 32;
        const _Float16* base = qkv + (size_t)tok * 5120 + 4096 + kvh * 128;
        float v0 = (float)base[lane], v1 = (float)base[lane + 64];
        float ss = v0 * v0 + v1 * v1;
        #pragma unroll
        for (int m = 1; m < 64; m <<= 1) ss += __shfl_xor(ss, m);
        float rms = rsqrtf(ss * (1.f / 128.f) + 1e-6f);
        float n0 = v0 * rms * kn_w[lane], n1 = v1 * rms * kn_w[lane + 64];
        _Float16* o = kh + (((size_t)(b * 4 + kvh)) * 1024 + l) * 128;
        o[lane]      = (_Float16)(c0 * n0 - s0 * n1);
        o[lane + 64] = (_Float16)(c1 * n1 + s1 * n0);
    }
}

// ---------------------------------------------------------------- V transpose
__global__ __launch_bounds__(256) void k_vt(
    const _Float16* __restrict__ qkv, _Float16* __restrict__ vth)
{
    const int bkv = blockIdx.x;
    const int b = bkv >> 2, kv = bkv & 3;
    const int l0 = blockIdx.y * 64, d0 = blockIdx.z * 64;
    __shared__ _Float16 T[64][72];
    const int t = threadIdx.x;
    const int r = t >> 3, c8 = (t & 7) * 8;
    #pragma unroll
    for (int rr = 0; rr < 2; rr++) {
        int l = l0 + r + rr * 32;
        *reinterpret_cast<f16x8*>(&T[r + rr * 32][c8]) =
            *reinterpret_cast<const f16x8*>(
                qkv + (size_t)(b * 1024 + l) * 5120 + 4608 + kv * 128 + d0 + c8);
    }
    __syncthreads();
    #pragma unroll
    for (int rr = 0; rr < 2; rr++) {
        int d = d0 + r + rr * 32;
        f16x8 v;
        #pragma unroll
        for (int j = 0; j < 8; j++) v[j] = T[c8 + j][r + rr * 32];
        *reinterpret_cast<f16x8*>(vth + ((size_t)(bkv * 128 + d)) * 1024 + l0 + c8) = v;
    }
}

// ---------------------------------------------------------------- attention
// exp2-domain online softmax (scale folded into Q), defer-max THR=8,
// row-sum l via MFMA ones-column (d=128), K LDS full 4-bit XOR swizzle.
__global__ __launch_bounds__(256) void k_attn(
    const _Float16* __restrict__ qh, const _Float16* __restrict__ kh,
    const _Float16* __restrict__ vth, const _Float16* __restrict__ ones16,
    _Float16* __restrict__ oh)
{
    const int bh = blockIdx.x;
    const int g = 15 - blockIdx.y;
    const int b = bh >> 5, h = bh & 31, kv = h >> 3;
    const int tid = threadIdx.x, lane = tid & 63, wid = tid >> 6;
    const int fr = lane & 15, fg = lane >> 4;
    const int q0w = g * 64 + wid * 16;

    __shared__ __align__(16) _Float16 Ks[64][128];
    __shared__ __align__(16) _Float16 Vs[144][64];    // rows 128..143: ones/zeros
    __shared__ __align__(16) _Float16 Ps[4][16][72];

    const _Float16* kb = kh + ((size_t)(b * 4 + kv)) * 1024 * 128;
    const _Float16* vb = vth + ((size_t)(b * 4 + kv)) * 128 * 1024;

    f16x8 aq[4];
    {
        const _Float16* qbase = qh + ((size_t)(b * 1024 + q0w + fr)) * 4096 + h * 128;
        #pragma unroll
        for (int kk = 0; kk < 4; kk++)
            aq[kk] = *reinterpret_cast<const f16x8*>(qbase + kk * 32 + fg * 8);
    }

    float m_r[4] = { -1e30f, -1e30f, -1e30f, -1e30f };
    const f32x4 z4 = { 0.f, 0.f, 0.f, 0.f };
    f32x4 oacc[9];
    #pragma unroll
    for (int dj = 0; dj < 9; dj++) oacc[dj] = z4;

    const int ntiles = g + 1;
    for (int kt = 0; kt < ntiles; kt++) {
        const int key0 = kt * 64;
        // K stage: full 4-bit XOR slot swizzle (both sides)
        #pragma unroll
        for (int i = 0; i < 4; i++) {
            int rr = 16 * wid + 4 * i + (lane >> 4);
            int c16 = (lane & 15) ^ (rr & 15);
            load16_lds(kb + (size_t)(key0 + rr) * 128 + c16 * 8,
                       &Ks[0][0] + (16 * wid + 4 * i) * 128);
        }
        // V stage rows 0..127
        #pragma unroll
        for (int i = 0; i < 4; i++) {
            int rr = 32 * wid + 8 * i + (lane >> 3);
            int c16 = (lane & 7) ^ (rr & 7);
            load16_lds(vb + (size_t)rr * 1024 + key0 + c16 * 8,
                       &Vs[0][0] + (32 * wid + 8 * i) * 64);
        }
        // ones/zeros rows 128..143 (separate small buffer, same slot swizzle)
        if (wid < 2) {
            int rr = wid * 8 + (lane >> 3);            // 0..15
            int c16 = (lane & 7) ^ (rr & 7);
            load16_lds(ones16 + (size_t)rr * 1024 + key0 + c16 * 8,
                       &Vs[0][0] + (128 + wid * 8) * 64);
        }
        __syncthreads();

        f32x4 sc[4];
        #pragma unroll
        for (int j = 0; j < 4; j++) sc[j] = z4;
        #pragma unroll
        for (int j = 0; j < 4; j++) {
            #pragma unroll
            for (int kk = 0; kk < 4; kk++) {
                f16x8 bk = *reinterpret_cast<const f16x8*>(
                    &Ks[0][0] + (j * 16 + fr) * 128 + (((kk * 4 + fg) ^ fr) * 8));
                sc[j] = __builtin_amdgcn_mfma_f32_16x16x32_f16(aq[kk], bk, sc[j], 0, 0, 0);
            }
        }

        const bool lastt = (kt == ntiles - 1);
        float pmax[4] = { -1e30f, -1e30f, -1e30f, -1e30f };
        #pragma unroll
        for (int j = 0; j < 4; j++) {
            const int key = key0 + j * 16 + fr;
            #pragma unroll
            for (int r = 0; r < 4; r++) {
                float v = sc[j][r];
                if (lastt && key > q0w + fg * 4 + r) v = -1e30f;
                sc[j][r] = v;
                pmax[r] = fmaxf(pmax[r], v);
            }
        }
        #pragma unroll
        for (int m = 1; m < 16; m <<= 1)
            #pragma unroll
            for (int r = 0; r < 4; r++) pmax[r] = fmaxf(pmax[r], __shfl_xor(pmax[r], m));

        // defer-max: only rescale when some row grew past threshold
        float dm = fmaxf(fmaxf(pmax[0] - m_r[0], pmax[1] - m_r[1]),
                         fmaxf(pmax[2] - m_r[2], pmax[3] - m_r[3]));
        if (__any(dm > 8.f)) {
            #pragma unroll
            for (int r = 0; r < 4; r++) {
                float mn = fmaxf(m_r[r], pmax[r]);
                float alpha = __builtin_amdgcn_exp2f(m_r[r] - mn);
                m_r[r] = mn;
                #pragma unroll
                for (int dj = 0; dj < 9; dj++) oacc[dj][r] *= alpha;
            }
        }
        #pragma unroll
        for (int j = 0; j < 4; j++)
            #pragma unroll
            for (int r = 0; r < 4; r++)
                sc[j][r] = __builtin_amdgcn_exp2f(sc[j][r] - m_r[r]);   // <= 2^8

        #pragma unroll
        for (int j = 0; j < 4; j++)
            #pragma unroll
            for (int r = 0; r < 4; r++)
                Ps[wid][fg * 4 + r][j * 16 + fr] = (_Float16)sc[j][r];

        #pragma unroll
        for (int ks = 0; ks < 2; ks++) {
            f16x8 ap = *reinterpret_cast<const f16x8*>(&Ps[wid][fr][ks * 32 + fg * 8]);
            #pragma unroll
            for (int dj = 0; dj < 9; dj++) {
                f16x8 bv = *reinterpret_cast<const f16x8*>(
                    &Vs[0][0] + (dj * 16 + fr) * 64 + (((ks * 4 + fg) ^ (fr & 7)) * 8));
                oacc[dj] = __builtin_amdgcn_mfma_f32_16x16x32_f16(ap, bv, oacc[dj], 0, 0, 0);
            }
        }
        __syncthreads();
    }

    // l lives in oacc[8] on lanes fr==0 (d=128 ones column); broadcast per fg group
    float inv[4];
    #pragma unroll
    for (int r = 0; r < 4; r++) {
        float l = __shfl(oacc[8][r], lane & 48);
        inv[r] = 1.f / l;
    }
    #pragma unroll
    for (int dj = 0; dj < 8; dj++)
        #pragma unroll
        for (int r = 0; r < 4; r++)
            oh[((size_t)(b * 1024 + q0w + fg * 4 + r)) * 4096 + h * 128 + dj * 16 + fr] =
                (_Float16)(oacc[dj][r] * inv[r]);
}

// ---------------------------------------------------------------- router (inline rmsnorm from x2)
__global__ __launch_bounds__(256) void k_router(
    const float* __restrict__ x2, const float* __restrict__ wm,
    const float* __restrict__ rw, float* __restrict__ wdense)
{
    const int tok = blockIdx.x * 4 + (threadIdx.x >> 6);
    const int lane = threadIdx.x & 63;
    __shared__ float lg[4][16];
    const float* hr = x2 + (size_t)tok * 2048;
    float vals[32];
    float ss = 0.f;
    #pragma unroll
    for (int i = 0; i < 32; i++) { float v = hr[i * 64 + lane]; vals[i] = v; ss += v * v; }
    #pragma unroll
    for (int m = 1; m < 64; m <<= 1) ss += __shfl_xor(ss, m);
    float r = rsqrtf(ss * (1.f / 2048.f) + 1e-6f);
    #pragma unroll
    for (int i = 0; i < 32; i++) vals[i] *= r * wm[i * 64 + lane];
    for (int e = 0; e < 16; e++) {
        float acc = 0.f;
        #pragma unroll
        for (int i = 0; i < 32; i++) acc += vals[i] * rw[(size_t)e * 2048 + i * 64 + lane];
        #pragma unroll
        for (int m = 1; m < 64; m <<= 1) acc += __shfl_xor(acc, m);
        if (lane == 0) lg[threadIdx.x >> 6][e] = acc;
    }
    __syncthreads();
    if (lane == 0) {
        float* l = lg[threadIdx.x >> 6];
        float mx = l[0];
        for (int e = 1; e < 16; e++) mx = fmaxf(mx, l[e]);
        float p[16]; float sum = 0.f;
        for (int e = 0; e < 16; e++) { p[e] = expf(l[e] - mx); sum += p[e]; }
        for (int e = 0; e < 16; e++) p[e] /= sum;
        bool sel[16]; for (int e = 0; e < 16; e++) sel[e] = false;
        float ssum = 0.f;
        for (int t = 0; t < 8; t++) {
            int bi = -1; float bv = -1.f;
            for (int e = 0; e < 16; e++) if (!sel[e] && p[e] > bv) { bv = p[e]; bi = e; }
            sel[bi] = true; ssum += bv;
        }
        for (int e = 0; e < 16; e++)
            wdense[(size_t)e * 4096 + tok] = sel[e] ? p[e] / ssum : 0.f;
    }
}

// ---------------------------------------------------------------- launch

extern "C" void kernel_launch(void* const* d_in, const int* in_sizes, int n_in,
                              void* d_out, int out_size, void* d_ws, size_t ws_size,
                              hipStream_t stream)
{
    const float* x        = (const float*)d_in[0];
    const float* cosb     = (const float*)d_in[1];
    const float* sinb     = (const float*)d_in[2];
    const float* nattn    = (const float*)d_in[3];
    const float* q_w      = (const float*)d_in[4];
    const float* k_w      = (const float*)d_in[5];
    const float* v_w      = (const float*)d_in[6];
    const float* qn_w     = (const float*)d_in[7];
    const float* kn_w     = (const float*)d_in[8];
    const float* o_w      = (const float*)d_in[9];
    const float* nmlp     = (const float*)d_in[10];
    const float* router_w = (const float*)d_in[11];
    const float* egw      = (const float*)d_in[12];
    const float* euw      = (const float*)d_in[13];
    const float* edw      = (const float*)d_in[14];

    char* w = (char*)d_ws;
    _Float16* qkvw_h = (_Float16*)(w + 0);          // 20.97 MB
    _Float16* ow_h   = (_Float16*)(w + 20971520);   // 16.78 MB
    _Float16* guw_h  = (_Float16*)(w + 37748736);   // 16.78 MB
    _Float16* dwc_h  = (_Float16*)(w + 54525952);   //  8.39 MB
    _Float16* h_h    = (_Float16*)(w + 62914560);   // 16.78 MB (aliased hm_h)
    _Float16* hm_h   = h_h;
    float*    x2     = (float*)(w + 79691776);      // 33.55 MB
    _Float16* qkv_h  = (_Float16*)(w + 113246208);  // 41.94 MB (alias o_h, ab_h)
    _Float16* o_h    = qkv_h;
    _Float16* ab_h   = qkv_h;
    _Float16* q_h    = (_Float16*)(w + 155189248);  // 33.55 MB (alias gucat)
    _Float16* gucat  = (_Float16*)(w + 155189248);
    _Float16* k_h    = (_Float16*)(w + 188743680);  //  4.19 MB
    _Float16* vt_h   = (_Float16*)(w + 192937984);  //  4.19 MB
    float*    wdense = (float*)(w + 197132288);     //  0.26 MB
    _Float16* ones_h = (_Float16*)(w + 197394432);  //  32 KB (16x1024 f16)

    k_cast4<<<18432, 256, 0, stream>>>(q_w, k_w, v_w, o_w, qkvw_h, ow_h);
    k_cast_guw<<<4096, 256, 0, stream>>>(egw, euw, guw_h);
    k_cast_dw<<<4096, 256, 0, stream>>>(edw, dwc_h);
    k_ones<<<16, 256, 0, stream>>>(ones_h);

    k_rmsnorm<<<4096, 256, 0, stream>>>(x, nattn, h_h);
    k_gemm8<<<dim3(16, 16), 512, 0, stream>>>(h_h, 2048, qkvw_h, 2048, qkv_h, 5120, 2048);
    k_gemm<<<dim3(32, 8), 256, 0, stream>>>(h_h, 2048, qkvw_h + (size_t)4096 * 2048, 2048,
                                            nullptr, qkv_h + 4096, 5120, nullptr, 2048);
    k_qkv_post<<<dim3(4096, 9), 256, 0, stream>>>(qkv_h, cosb, sinb, qn_w, kn_w, q_h, k_h);
    k_vt<<<dim3(16, 16, 2), 256, 0, stream>>>(qkv_h, vt_h);
    k_attn<<<dim3(128, 16), 256, 0, stream>>>(q_h, k_h, vt_h, ones_h, o_h);
    k_gemm<<<dim3(32, 16), 256, 0, stream>>>(o_h, 4096, ow_h, 4096,
                                             x2, nullptr, 2048, x, 4096);
    k_rmsnorm<<<4096, 256, 0, stream>>>(x2, nmlp, hm_h);
    k_router<<<1024, 256, 0, stream>>>(x2, nmlp, router_w, wdense);
    k_gemm8<<<dim3(16, 16), 512, 0, stream>>>(hm_h, 2048, guw_h, 2048, gucat, 4096, 2048);
    k_gu_comb<<<4096, 256, 0, stream>>>(gucat, wdense, ab_h);
    k_gemm<<<dim3(32, 16), 256, 0, stream>>>(ab_h, 2048, dwc_h, 2048,
                                             (float*)d_out, nullptr, 2048, x2, 2048);

    (void)in_sizes; (void)n_in; (void)out_size; (void)ws_size;
}

// Round 12
// 504.748 us; speedup vs baseline: 1.3271x; 1.0155x over previous
//
#include <hip/hip_runtime.h>
#include <stdint.h>

typedef _Float16 f16x8 __attribute__((ext_vector_type(8)));
typedef _Float16 f16x4 __attribute__((ext_vector_type(4)));
typedef float    f32x4 __attribute__((ext_vector_type(4)));

__device__ __forceinline__ void load16_lds(const _Float16* g, _Float16* l) {
    __builtin_amdgcn_global_load_lds(
        (const __attribute__((address_space(1))) void*)g,
        (__attribute__((address_space(3))) void*)l, 16, 0, 0);
}

// ---------------------------------------------------------------- casts

__global__ void k_cast4(const float* __restrict__ q, const float* __restrict__ k,
                        const float* __restrict__ v, const float* __restrict__ o,
                        _Float16* __restrict__ qkvw, _Float16* __restrict__ ow)
{
    size_t i = ((size_t)blockIdx.x * 256 + threadIdx.x) * 4;
    const float* src; _Float16* dst;
    if (i < 8388608)        { src = q + i;            dst = qkvw + i; }
    else if (i < 9437184)   { src = k + (i - 8388608); dst = qkvw + i; }
    else if (i < 10485760)  { src = v + (i - 9437184); dst = qkvw + i; }
    else                    { src = o + (i - 10485760); dst = ow + (i - 10485760); }
    float4 x = *reinterpret_cast<const float4*>(src);
    f16x4 y = { (_Float16)x.x, (_Float16)x.y, (_Float16)x.z, (_Float16)x.w };
    *reinterpret_cast<f16x4*>(dst) = y;
}

// edw[e][dm][mi] (f32) -> dwc[dm][e*128+mi] (f16)
__global__ void k_cast_dw(const float* __restrict__ edw, _Float16* __restrict__ dwc) {
    int t = blockIdx.x * 256 + threadIdx.x;
    int mi4 = (t & 31) * 4;
    int dm = (t >> 5) & 2047;
    int e = t >> 16;
    float4 v = *reinterpret_cast<const float4*>(edw + (((size_t)e * 2048 + dm) << 7) + mi4);
    f16x4 o = { (_Float16)v.x, (_Float16)v.y, (_Float16)v.z, (_Float16)v.w };
    *reinterpret_cast<f16x4*>(dwc + ((size_t)dm << 11) + e * 128 + mi4) = o;
}

// egw/euw[e][mi][k] -> guw[e*256 + half*128 + mi][k] (f16)
__global__ __launch_bounds__(256) void k_cast_guw(
    const float* __restrict__ eg, const float* __restrict__ eu,
    _Float16* __restrict__ out)
{
    const int row = blockIdx.x;
    const int e = row >> 8, rem = row & 255, half = rem >> 7, mi = rem & 127;
    const float* src = (half ? eu : eg) + ((size_t)(e * 128 + mi)) * 2048;
    const int c = threadIdx.x * 8;
    float4 v0 = *reinterpret_cast<const float4*>(src + c);
    float4 v1 = *reinterpret_cast<const float4*>(src + c + 4);
    f16x8 o = { (_Float16)v0.x,(_Float16)v0.y,(_Float16)v0.z,(_Float16)v0.w,
                (_Float16)v1.x,(_Float16)v1.y,(_Float16)v1.z,(_Float16)v1.w };
    *reinterpret_cast<f16x8*>(out + (size_t)row * 2048 + c) = o;
}

// ones block 16x64: row 0 = 1.0, rows 1..15 = 0.0
__global__ void k_ones(_Float16* __restrict__ p) {
    int i = blockIdx.x * 256 + threadIdx.x;   // 256 threads x 4 elems = 1024
    _Float16 v = (i < 16) ? (_Float16)1.0f : (_Float16)0.0f;
    f16x4 o = { v, v, v, v };
    *reinterpret_cast<f16x4*>(p + i * 4) = o;
}

// ---------------------------------------------------------------- rmsnorm (f16 out)
__global__ __launch_bounds__(256) void k_rmsnorm(
    const float* __restrict__ x, const float* __restrict__ w,
    _Float16* __restrict__ oh)
{
    const int row = blockIdx.x, tid = threadIdx.x;
    const float* xr = x + (size_t)row * 2048;
    float4 a = *reinterpret_cast<const float4*>(xr + tid * 8);
    float4 b = *reinterpret_cast<const float4*>(xr + tid * 8 + 4);
    float ss = a.x*a.x + a.y*a.y + a.z*a.z + a.w*a.w
             + b.x*b.x + b.y*b.y + b.z*b.z + b.w*b.w;
    #pragma unroll
    for (int m = 1; m < 64; m <<= 1) ss += __shfl_xor(ss, m);
    __shared__ float red[4];
    if ((tid & 63) == 0) red[tid >> 6] = ss;
    __syncthreads();
    float tot = red[0] + red[1] + red[2] + red[3];
    float r = rsqrtf(tot * (1.f / 2048.f) + 1e-6f);
    float4 wa = *reinterpret_cast<const float4*>(w + tid * 8);
    float4 wb = *reinterpret_cast<const float4*>(w + tid * 8 + 4);
    f16x8 hv = { (_Float16)(a.x*r*wa.x), (_Float16)(a.y*r*wa.y),
                 (_Float16)(a.z*r*wa.z), (_Float16)(a.w*r*wa.w),
                 (_Float16)(b.x*r*wb.x), (_Float16)(b.y*r*wb.y),
                 (_Float16)(b.z*r*wb.z), (_Float16)(b.w*r*wb.w) };
    *reinterpret_cast<f16x8*>(oh + (size_t)row * 2048 + tid * 8) = hv;
}

// ---------------------------------------------------------------- GEMM 128x128
__global__ __launch_bounds__(256) void k_gemm(
    const _Float16* __restrict__ A, int lda,
    const _Float16* __restrict__ W, int ldw,
    float* __restrict__ Cf, _Float16* __restrict__ Ch, int ldc,
    const float* __restrict__ resid, int K)
{
    __shared__ __align__(16) _Float16 As[3][128][32];
    __shared__ __align__(16) _Float16 Ws[3][128][32];
    const int r0 = blockIdx.x * 128, c0 = blockIdx.y * 128;
    const int tid = threadIdx.x, lane = tid & 63, wid = tid >> 6;
    const int wr = wid >> 1, wc = wid & 1;
    const int sr = lane >> 2;
    const int scs = ((lane & 3) ^ ((lane >> 3) & 3)) * 8;
    const int fr = lane & 15;
    const int rks = (((lane >> 4) ^ ((fr >> 1) & 3))) * 8;
    const f32x4 z4 = { 0.f, 0.f, 0.f, 0.f };
    f32x4 acc[4][4];
    #pragma unroll
    for (int i = 0; i < 4; i++)
        #pragma unroll
        for (int j = 0; j < 4; j++) acc[i][j] = z4;

    auto stage = [&](int bf, int k0) {
        #pragma unroll
        for (int i = 0; i < 2; i++) {
            int ch = wid * 2 + i;
            load16_lds(A + (size_t)(r0 + ch * 16 + sr) * lda + k0 + scs, &As[bf][ch * 16][0]);
            load16_lds(W + (size_t)(c0 + ch * 16 + sr) * ldw + k0 + scs, &Ws[bf][ch * 16][0]);
        }
    };

    const int nt = K >> 5;
    stage(0, 0);
    if (nt > 1) stage(1, 32);
    int cur = 0;
    for (int t = 0; t < nt; t++) {
        if (t < nt - 1) asm volatile("s_waitcnt vmcnt(4)" ::: "memory");
        else            asm volatile("s_waitcnt vmcnt(0)" ::: "memory");
        __builtin_amdgcn_s_barrier();
        f16x8 af[4], bf4[4];
        #pragma unroll
        for (int i = 0; i < 4; i++)
            af[i] = *reinterpret_cast<const f16x8*>(&As[cur][wr * 64 + i * 16 + fr][rks]);
        #pragma unroll
        for (int j = 0; j < 4; j++)
            bf4[j] = *reinterpret_cast<const f16x8*>(&Ws[cur][wc * 64 + j * 16 + fr][rks]);
        if (t + 2 < nt) stage((t + 2) % 3, (t + 2) << 5);
        __builtin_amdgcn_s_setprio(1);
        #pragma unroll
        for (int i = 0; i < 4; i++)
            #pragma unroll
            for (int j = 0; j < 4; j++)
                acc[i][j] = __builtin_amdgcn_mfma_f32_16x16x32_f16(af[i], bf4[j], acc[i][j], 0, 0, 0);
        __builtin_amdgcn_s_setprio(0);
        cur = (cur + 1) % 3;
    }
    #pragma unroll
    for (int i = 0; i < 4; i++) {
        const int rowb = r0 + wr * 64 + i * 16 + (lane >> 4) * 4;
        #pragma unroll
        for (int j = 0; j < 4; j++) {
            const int col = c0 + wc * 64 + j * 16 + fr;
            #pragma unroll
            for (int r = 0; r < 4; r++) {
                size_t idx = (size_t)(rowb + r) * ldc + col;
                float v = acc[i][j][r];
                if (resid) v += resid[idx];
                if (Ch) Ch[idx] = (_Float16)v;
                else    Cf[idx] = v;
            }
        }
    }
}

// ---------------------------------------------------------------- GEMM 256x256, 8 waves
// gu-mode (wdense!=null): epilogue computes silu(g)*u*w_e via LDS pairing and
// writes ab[tok][e*128+mi] directly (blockIdx.y == expert).
__global__ __launch_bounds__(512, 2) void k_gemm8(
    const _Float16* __restrict__ A, int lda,
    const _Float16* __restrict__ W, int ldw,
    _Float16* __restrict__ Ch, int ldc, int K,
    const float* __restrict__ wdense, _Float16* __restrict__ ab)
{
    __shared__ __align__(16) _Float16 As[3][256][32];
    __shared__ __align__(16) _Float16 Ws[3][256][32];
    const int r0 = blockIdx.x * 256, c0 = blockIdx.y * 256;
    const int tid = threadIdx.x, lane = tid & 63, wid = tid >> 6;
    const int wr = wid >> 2, wc = wid & 3;
    const int rA = lane >> 2;
    const int scs = ((lane & 3) ^ ((lane >> 3) & 3)) * 8;
    const int fr = lane & 15, fg = lane >> 4;
    const int rks = (((lane >> 4) ^ ((fr >> 1) & 3))) * 8;
    const f32x4 z4 = { 0.f, 0.f, 0.f, 0.f };
    f32x4 acc[8][4];
    #pragma unroll
    for (int i = 0; i < 8; i++)
        #pragma unroll
        for (int j = 0; j < 4; j++) acc[i][j] = z4;

    auto stage = [&](int bf, int k0) {
        #pragma unroll
        for (int i = 0; i < 2; i++) {
            load16_lds(A + (size_t)(r0 + i * 128 + wid * 16 + rA) * lda + k0 + scs,
                       &As[bf][i * 128 + wid * 16][0]);
            load16_lds(W + (size_t)(c0 + i * 128 + wid * 16 + rA) * ldw + k0 + scs,
                       &Ws[bf][i * 128 + wid * 16][0]);
        }
    };

    const int nt = K >> 5;
    stage(0, 0);
    if (nt > 1) stage(1, 32);
    int cur = 0;
    for (int t = 0; t < nt; t++) {
        if (t < nt - 1) asm volatile("s_waitcnt vmcnt(4)" ::: "memory");
        else            asm volatile("s_waitcnt vmcnt(0)" ::: "memory");
        __builtin_amdgcn_s_barrier();
        f16x8 af[8], bf4[4];
        #pragma unroll
        for (int i = 0; i < 8; i++)
            af[i] = *reinterpret_cast<const f16x8*>(&As[cur][wr * 128 + i * 16 + fr][rks]);
        #pragma unroll
        for (int j = 0; j < 4; j++)
            bf4[j] = *reinterpret_cast<const f16x8*>(&Ws[cur][wc * 64 + j * 16 + fr][rks]);
        if (t + 2 < nt) stage((t + 2) % 3, (t + 2) << 5);
        __builtin_amdgcn_s_setprio(1);
        #pragma unroll
        for (int i = 0; i < 8; i++)
            #pragma unroll
            for (int j = 0; j < 4; j++)
                acc[i][j] = __builtin_amdgcn_mfma_f32_16x16x32_f16(af[i], bf4[j], acc[i][j], 0, 0, 0);
        __builtin_amdgcn_s_setprio(0);
        cur = (cur + 1) % 3;
    }

    if (!wdense) {
        #pragma unroll
        for (int i = 0; i < 8; i++) {
            const int rowb = r0 + wr * 128 + i * 16 + fg * 4;
            #pragma unroll
            for (int j = 0; j < 4; j++) {
                const int col = c0 + wc * 64 + j * 16 + fr;
                #pragma unroll
                for (int r = 0; r < 4; r++)
                    Ch[(size_t)(rowb + r) * ldc + col] = (_Float16)acc[i][j][r];
            }
        }
        return;
    }

    // ---------------- gu epilogue: pair g (cols 0..127) with u (cols 128..255)
    // Lg[row][mi] (256x136 f16) split: rows 0..127 in As space, 128..255 in Ws.
    _Float16* LgA = &As[0][0][0];
    _Float16* LgB = &Ws[0][0][0];
    auto lgp = [&](int row, int mi) -> _Float16* {
        return ((row < 128) ? LgA : LgB) + (size_t)(row & 127) * 136 + mi;
    };
    const int e = blockIdx.y;
    __syncthreads();                       // all K-loop LDS reads retired
    if (wc < 2) {                          // g-waves park g
        #pragma unroll
        for (int i = 0; i < 8; i++) {
            const int row = wr * 128 + i * 16 + fg * 4;
            #pragma unroll
            for (int j = 0; j < 4; j++) {
                const int mi = wc * 64 + j * 16 + fr;
                #pragma unroll
                for (int r = 0; r < 4; r++)
                    *lgp(row + r, mi) = (_Float16)acc[i][j][r];
            }
        }
    }
    __syncthreads();
    if (wc >= 2) {                         // u-waves: silu(g)*u in place
        #pragma unroll
        for (int i = 0; i < 8; i++) {
            const int row = wr * 128 + i * 16 + fg * 4;
            #pragma unroll
            for (int j = 0; j < 4; j++) {
                const int mi = (wc - 2) * 64 + j * 16 + fr;
                #pragma unroll
                for (int r = 0; r < 4; r++) {
                    float g = (float)*lgp(row + r, mi);
                    float sil = g / (1.f + __expf(-g));
                    *lgp(row + r, mi) = (_Float16)(sil * acc[i][j][r]);
                }
            }
        }
    }
    __syncthreads();
    // cooperative weighted store: 256 rows x 128 cols, f16x8 chunks
    #pragma unroll
    for (int pass = 0; pass < 8; pass++) {
        int cid = pass * 512 + tid;        // 0..4095
        int row = cid >> 4, col8 = cid & 15;
        f16x8 v = *reinterpret_cast<const f16x8*>(
            ((row < 128) ? LgA : LgB) + (size_t)(row & 127) * 136 + col8 * 8);
        float wv = wdense[(size_t)e * 4096 + r0 + row];
        f16x8 o;
        #pragma unroll
        for (int j = 0; j < 8; j++) o[j] = (_Float16)((float)v[j] * wv);
        *reinterpret_cast<f16x8*>(ab + (size_t)(r0 + row) * 2048 + e * 128 + col8 * 8) = o;
    }
}

// ------------------------------------------- per-head RMSNorm + RoPE (wave-per-head)
__global__ __launch_bounds__(256) void k_qkv_post(
    const _Float16* __restrict__ qkv,
    const float* __restrict__ cosb, const float* __restrict__ sinb,
    const float* __restrict__ qn_w, const float* __restrict__ kn_w,
    _Float16* __restrict__ qh, _Float16* __restrict__ kh)
{
    const int tok = blockIdx.x;
    const int u = blockIdx.y * 4 + (threadIdx.x >> 6);
    const int lane = threadIdx.x & 63;
    const int b = tok >> 10, l = tok & 1023;
    const float SCL = 0.12752887074166638f;   // 1/sqrt(128) * log2(e)
    const float c0 = cosb[(size_t)tok * 128 + lane];
    const float c1 = cosb[(size_t)tok * 128 + lane + 64];
    const float s0 = sinb[(size_t)tok * 128 + lane];
    const float s1 = sinb[(size_t)tok * 128 + lane + 64];
    if (u < 32) {
        const _Float16* base = qkv + (size_t)tok * 5120 + u * 128;
        float v0 = (float)base[lane], v1 = (float)base[lane + 64];
        float ss = v0 * v0 + v1 * v1;
        #pragma unroll
        for (int m = 1; m < 64; m <<= 1) ss += __shfl_xor(ss, m);
        float rms = rsqrtf(ss * (1.f / 128.f) + 1e-6f);
        float n0 = v0 * rms * qn_w[lane], n1 = v1 * rms * qn_w[lane + 64];
        _Float16* o = qh + (size_t)tok * 4096 + u * 128;
        o[lane]      = (_Float16)(SCL * (c0 * n0 - s0 * n1));
        o[lane + 64] = (_Float16)(SCL * (c1 * n1 + s1 * n0));
    } else {
        const int kvh = u - 32;
        const _Float16* base = qkv + (size_t)tok * 5120 + 4096 + kvh * 128;
        float v0 = (float)base[lane], v1 = (float)base[lane + 64];
        float ss = v0 * v0 + v1 * v1;
        #pragma unroll
        for (int m = 1; m < 64; m <<= 1) ss += __shfl_xor(ss, m);
        float rms = rsqrtf(ss * (1.f / 128.f) + 1e-6f);
        float n0 = v0 * rms * kn_w[lane], n1 = v1 * rms * kn_w[lane + 64];
        _Float16* o = kh + (((size_t)(b * 4 + kvh)) * 1024 + l) * 128;
        o[lane]      = (_Float16)(c0 * n0 - s0 * n1);
        o[lane + 64] = (_Float16)(c1 * n1 + s1 * n0);
    }
}

// ---------------------------------------------------------------- V transpose
__global__ __launch_bounds__(256) void k_vt(
    const _Float16* __restrict__ qkv, _Float16* __restrict__ vth)
{
    const int bkv = blockIdx.x;
    const int b = bkv >> 2, kv = bkv & 3;
    const int l0 = blockIdx.y * 64, d0 = blockIdx.z * 64;
    __shared__ _Float16 T[64][72];
    const int t = threadIdx.x;
    const int r = t >> 3, c8 = (t & 7) * 8;
    #pragma unroll
    for (int rr = 0; rr < 2; rr++) {
        int l = l0 + r + rr * 32;
        *reinterpret_cast<f16x8*>(&T[r + rr * 32][c8]) =
            *reinterpret_cast<const f16x8*>(
                qkv + (size_t)(b * 1024 + l) * 5120 + 4608 + kv * 128 + d0 + c8);
    }
    __syncthreads();
    #pragma unroll
    for (int rr = 0; rr < 2; rr++) {
        int d = d0 + r + rr * 32;
        f16x8 v;
        #pragma unroll
        for (int j = 0; j < 8; j++) v[j] = T[c8 + j][r + rr * 32];
        *reinterpret_cast<f16x8*>(vth + ((size_t)(bkv * 128 + d)) * 1024 + l0 + c8) = v;
    }
}

// ---------------------------------------------------------------- attention
// 2-phase double-buffered K/V (stage(kt+1) after barrier, one barrier/tile),
// exp2 softmax, defer-max, l via ones-column (staged once), XOR swizzles.
__global__ __launch_bounds__(256) void k_attn(
    const _Float16* __restrict__ qh, const _Float16* __restrict__ kh,
    const _Float16* __restrict__ vth, const _Float16* __restrict__ ones16,
    _Float16* __restrict__ oh)
{
    const int bh = blockIdx.x;
    const int g = 15 - blockIdx.y;
    const int b = bh >> 5, h = bh & 31, kv = h >> 3;
    const int tid = threadIdx.x, lane = tid & 63, wid = tid >> 6;
    const int fr = lane & 15, fg = lane >> 4;
    const int q0w = g * 64 + wid * 16;

    __shared__ __align__(16) _Float16 Ks[2][64][128];   // 32 KB
    __shared__ __align__(16) _Float16 Vs[2][128][64];   // 32 KB
    __shared__ __align__(16) _Float16 Vones[16][64];    //  2 KB
    __shared__ __align__(16) _Float16 Ps[4][16][72];    //  9 KB

    const _Float16* kb = kh + ((size_t)(b * 4 + kv)) * 1024 * 128;
    const _Float16* vb = vth + ((size_t)(b * 4 + kv)) * 128 * 1024;

    auto stage = [&](int nb, int key0) {
        #pragma unroll
        for (int i = 0; i < 4; i++) {
            int rr = 16 * wid + 4 * i + (lane >> 4);
            int c16 = (lane & 15) ^ (rr & 15);
            load16_lds(kb + (size_t)(key0 + rr) * 128 + c16 * 8,
                       &Ks[nb][0][0] + (16 * wid + 4 * i) * 128);
        }
        #pragma unroll
        for (int i = 0; i < 4; i++) {
            int rr = 32 * wid + 8 * i + (lane >> 3);
            int c16 = (lane & 7) ^ (rr & 7);
            load16_lds(vb + (size_t)rr * 1024 + key0 + c16 * 8,
                       &Vs[nb][0][0] + (32 * wid + 8 * i) * 64);
        }
    };

    f16x8 aq[4];
    {
        const _Float16* qbase = qh + ((size_t)(b * 1024 + q0w + fr)) * 4096 + h * 128;
        #pragma unroll
        for (int kk = 0; kk < 4; kk++)
            aq[kk] = *reinterpret_cast<const f16x8*>(qbase + kk * 32 + fg * 8);
    }
    // ones block: loop-invariant content, staged once (wave 0)
    if (wid == 0) {
        #pragma unroll
        for (int i = 0; i < 2; i++)
            load16_lds(ones16 + (size_t)(lane + i * 64) * 8, &Vones[0][0] + i * 512);
    }
    stage(0, 0);

    float m_r[4] = { -1e30f, -1e30f, -1e30f, -1e30f };
    const f32x4 z4 = { 0.f, 0.f, 0.f, 0.f };
    f32x4 oacc[9];
    #pragma unroll
    for (int dj = 0; dj < 9; dj++) oacc[dj] = z4;

    const int ntiles = g + 1;
    int cb = 0;
    for (int kt = 0; kt < ntiles; kt++) {
        const int key0 = kt * 64;
        asm volatile("s_waitcnt vmcnt(0)" ::: "memory");
        __builtin_amdgcn_s_barrier();
        if (kt + 1 < ntiles) stage(cb ^ 1, key0 + 64);   // fly under compute

        f32x4 sc[4];
        #pragma unroll
        for (int j = 0; j < 4; j++) sc[j] = z4;
        #pragma unroll
        for (int j = 0; j < 4; j++) {
            #pragma unroll
            for (int kk = 0; kk < 4; kk++) {
                f16x8 bk = *reinterpret_cast<const f16x8*>(
                    &Ks[cb][0][0] + (j * 16 + fr) * 128 + (((kk * 4 + fg) ^ fr) * 8));
                sc[j] = __builtin_amdgcn_mfma_f32_16x16x32_f16(aq[kk], bk, sc[j], 0, 0, 0);
            }
        }

        const bool lastt = (kt == ntiles - 1);
        float pmax[4] = { -1e30f, -1e30f, -1e30f, -1e30f };
        #pragma unroll
        for (int j = 0; j < 4; j++) {
            const int key = key0 + j * 16 + fr;
            #pragma unroll
            for (int r = 0; r < 4; r++) {
                float v = sc[j][r];
                if (lastt && key > q0w + fg * 4 + r) v = -1e30f;
                sc[j][r] = v;
                pmax[r] = fmaxf(pmax[r], v);
            }
        }
        #pragma unroll
        for (int m = 1; m < 16; m <<= 1)
            #pragma unroll
            for (int r = 0; r < 4; r++) pmax[r] = fmaxf(pmax[r], __shfl_xor(pmax[r], m));

        float dm = fmaxf(fmaxf(pmax[0] - m_r[0], pmax[1] - m_r[1]),
                         fmaxf(pmax[2] - m_r[2], pmax[3] - m_r[3]));
        if (__any(dm > 8.f)) {
            #pragma unroll
            for (int r = 0; r < 4; r++) {
                float mn = fmaxf(m_r[r], pmax[r]);
                float alpha = __builtin_amdgcn_exp2f(m_r[r] - mn);
                m_r[r] = mn;
                #pragma unroll
                for (int dj = 0; dj < 9; dj++) oacc[dj][r] *= alpha;
            }
        }
        #pragma unroll
        for (int j = 0; j < 4; j++)
            #pragma unroll
            for (int r = 0; r < 4; r++)
                sc[j][r] = __builtin_amdgcn_exp2f(sc[j][r] - m_r[r]);

        #pragma unroll
        for (int j = 0; j < 4; j++)
            #pragma unroll
            for (int r = 0; r < 4; r++)
                Ps[wid][fg * 4 + r][j * 16 + fr] = (_Float16)sc[j][r];

        #pragma unroll
        for (int ks = 0; ks < 2; ks++) {
            f16x8 ap = *reinterpret_cast<const f16x8*>(&Ps[wid][fr][ks * 32 + fg * 8]);
            #pragma unroll
            for (int dj = 0; dj < 8; dj++) {
                f16x8 bv = *reinterpret_cast<const f16x8*>(
                    &Vs[cb][0][0] + (dj * 16 + fr) * 64 + (((ks * 4 + fg) ^ (fr & 7)) * 8));
                oacc[dj] = __builtin_amdgcn_mfma_f32_16x16x32_f16(ap, bv, oacc[dj], 0, 0, 0);
            }
            f16x8 bo = *reinterpret_cast<const f16x8*>(
                &Vones[0][0] + fr * 64 + (((ks * 4 + fg) ^ (fr & 7)) * 8));
            oacc[8] = __builtin_amdgcn_mfma_f32_16x16x32_f16(ap, bo, oacc[8], 0, 0, 0);
        }
        cb ^= 1;
    }

    float inv[4];
    #pragma unroll
    for (int r = 0; r < 4; r++) {
        float l = __shfl(oacc[8][r], lane & 48);
        inv[r] = 1.f / l;
    }
    #pragma unroll
    for (int dj = 0; dj < 8; dj++)
        #pragma unroll
        for (int r = 0; r < 4; r++)
            oh[((size_t)(b * 1024 + q0w + fg * 4 + r)) * 4096 + h * 128 + dj * 16 + fr] =
                (_Float16)(oacc[dj][r] * inv[r]);
}

// ---------------------------------------------------------------- router (inline rmsnorm from x2)
__global__ __launch_bounds__(256) void k_router(
    const float* __restrict__ x2, const float* __restrict__ wm,
    const float* __restrict__ rw, float* __restrict__ wdense)
{
    const int tok = blockIdx.x * 4 + (threadIdx.x >> 6);
    const int lane = threadIdx.x & 63;
    __shared__ float lg[4][16];
    const float* hr = x2 + (size_t)tok * 2048;
    float vals[32];
    float ss = 0.f;
    #pragma unroll
    for (int i = 0; i < 32; i++) { float v = hr[i * 64 + lane]; vals[i] = v; ss += v * v; }
    #pragma unroll
    for (int m = 1; m < 64; m <<= 1) ss += __shfl_xor(ss, m);
    float r = rsqrtf(ss * (1.f / 2048.f) + 1e-6f);
    #pragma unroll
    for (int i = 0; i < 32; i++) vals[i] *= r * wm[i * 64 + lane];
    for (int e = 0; e < 16; e++) {
        float acc = 0.f;
        #pragma unroll
        for (int i = 0; i < 32; i++) acc += vals[i] * rw[(size_t)e * 2048 + i * 64 + lane];
        #pragma unroll
        for (int m = 1; m < 64; m <<= 1) acc += __shfl_xor(acc, m);
        if (lane == 0) lg[threadIdx.x >> 6][e] = acc;
    }
    __syncthreads();
    if (lane == 0) {
        float* l = lg[threadIdx.x >> 6];
        float mx = l[0];
        for (int e = 1; e < 16; e++) mx = fmaxf(mx, l[e]);
        float p[16]; float sum = 0.f;
        for (int e = 0; e < 16; e++) { p[e] = expf(l[e] - mx); sum += p[e]; }
        for (int e = 0; e < 16; e++) p[e] /= sum;
        bool sel[16]; for (int e = 0; e < 16; e++) sel[e] = false;
        float ssum = 0.f;
        for (int t = 0; t < 8; t++) {
            int bi = -1; float bv = -1.f;
            for (int e = 0; e < 16; e++) if (!sel[e] && p[e] > bv) { bv = p[e]; bi = e; }
            sel[bi] = true; ssum += bv;
        }
        for (int e = 0; e < 16; e++)
            wdense[(size_t)e * 4096 + tok] = sel[e] ? p[e] / ssum : 0.f;
    }
}

// ---------------------------------------------------------------- launch

extern "C" void kernel_launch(void* const* d_in, const int* in_sizes, int n_in,
                              void* d_out, int out_size, void* d_ws, size_t ws_size,
                              hipStream_t stream)
{
    const float* x        = (const float*)d_in[0];
    const float* cosb     = (const float*)d_in[1];
    const float* sinb     = (const float*)d_in[2];
    const float* nattn    = (const float*)d_in[3];
    const float* q_w      = (const float*)d_in[4];
    const float* k_w      = (const float*)d_in[5];
    const float* v_w      = (const float*)d_in[6];
    const float* qn_w     = (const float*)d_in[7];
    const float* kn_w     = (const float*)d_in[8];
    const float* o_w      = (const float*)d_in[9];
    const float* nmlp     = (const float*)d_in[10];
    const float* router_w = (const float*)d_in[11];
    const float* egw      = (const float*)d_in[12];
    const float* euw      = (const float*)d_in[13];
    const float* edw      = (const float*)d_in[14];

    char* w = (char*)d_ws;
    _Float16* qkvw_h = (_Float16*)(w + 0);          // 20.97 MB
    _Float16* ow_h   = (_Float16*)(w + 20971520);   // 16.78 MB
    _Float16* guw_h  = (_Float16*)(w + 37748736);   // 16.78 MB
    _Float16* dwc_h  = (_Float16*)(w + 54525952);   //  8.39 MB
    _Float16* h_h    = (_Float16*)(w + 62914560);   // 16.78 MB (aliased hm_h)
    _Float16* hm_h   = h_h;
    float*    x2     = (float*)(w + 79691776);      // 33.55 MB
    _Float16* qkv_h  = (_Float16*)(w + 113246208);  // 41.94 MB (alias o_h, ab_h)
    _Float16* o_h    = qkv_h;
    _Float16* ab_h   = qkv_h;
    _Float16* q_h    = (_Float16*)(w + 155189248);  // 33.55 MB
    _Float16* k_h    = (_Float16*)(w + 188743680);  //  4.19 MB
    _Float16* vt_h   = (_Float16*)(w + 192937984);  //  4.19 MB
    float*    wdense = (float*)(w + 197132288);     //  0.26 MB
    _Float16* ones_h = (_Float16*)(w + 197394432);  //  2 KB (16x64 f16)

    k_cast4<<<18432, 256, 0, stream>>>(q_w, k_w, v_w, o_w, qkvw_h, ow_h);
    k_cast_guw<<<4096, 256, 0, stream>>>(egw, euw, guw_h);
    k_cast_dw<<<4096, 256, 0, stream>>>(edw, dwc_h);
    k_ones<<<1, 256, 0, stream>>>(ones_h);

    k_rmsnorm<<<4096, 256, 0, stream>>>(x, nattn, h_h);
    k_gemm8<<<dim3(16, 16), 512, 0, stream>>>(h_h, 2048, qkvw_h, 2048, qkv_h, 5120, 2048,
                                              nullptr, nullptr);
    k_gemm<<<dim3(32, 8), 256, 0, stream>>>(h_h, 2048, qkvw_h + (size_t)4096 * 2048, 2048,
                                            nullptr, qkv_h + 4096, 5120, nullptr, 2048);
    k_qkv_post<<<dim3(4096, 9), 256, 0, stream>>>(qkv_h, cosb, sinb, qn_w, kn_w, q_h, k_h);
    k_vt<<<dim3(16, 16, 2), 256, 0, stream>>>(qkv_h, vt_h);
    k_attn<<<dim3(128, 16), 256, 0, stream>>>(q_h, k_h, vt_h, ones_h, o_h);
    k_gemm<<<dim3(32, 16), 256, 0, stream>>>(o_h, 4096, ow_h, 4096,
                                             x2, nullptr, 2048, x, 4096);
    k_rmsnorm<<<4096, 256, 0, stream>>>(x2, nmlp, hm_h);
    k_router<<<1024, 256, 0, stream>>>(x2, nmlp, router_w, wdense);
    // gate/up GEMM with fused silu*u*w epilogue -> ab directly
    k_gemm8<<<dim3(16, 16), 512, 0, stream>>>(hm_h, 2048, guw_h, 2048, nullptr, 0, 2048,
                                              wdense, ab_h);
    k_gemm<<<dim3(32, 16), 256, 0, stream>>>(ab_h, 2048, dwc_h, 2048,
                                             (float*)d_out, nullptr, 2048, x2, 2048);

    (void)in_sizes; (void)n_in; (void)out_size; (void)ws_size;
}

// Round 13
// 485.993 us; speedup vs baseline: 1.3783x; 1.0386x over previous
//
#include <hip/hip_runtime.h>
#include <stdint.h>

typedef _Float16 f16x8 __attribute__((ext_vector_type(8)));
typedef _Float16 f16x4 __attribute__((ext_vector_type(4)));
typedef float    f32x4 __attribute__((ext_vector_type(4)));

__device__ __forceinline__ void load16_lds(const _Float16* g, _Float16* l) {
    __builtin_amdgcn_global_load_lds(
        (const __attribute__((address_space(1))) void*)g,
        (__attribute__((address_space(3))) void*)l, 16, 0, 0);
}

// ---------------------------------------------------------------- casts

__global__ void k_cast4(const float* __restrict__ q, const float* __restrict__ k,
                        const float* __restrict__ v, const float* __restrict__ o,
                        _Float16* __restrict__ qkvw, _Float16* __restrict__ ow)
{
    size_t i = ((size_t)blockIdx.x * 256 + threadIdx.x) * 4;
    const float* src; _Float16* dst;
    if (i < 8388608)        { src = q + i;            dst = qkvw + i; }
    else if (i < 9437184)   { src = k + (i - 8388608); dst = qkvw + i; }
    else if (i < 10485760)  { src = v + (i - 9437184); dst = qkvw + i; }
    else                    { src = o + (i - 10485760); dst = ow + (i - 10485760); }
    float4 x = *reinterpret_cast<const float4*>(src);
    f16x4 y = { (_Float16)x.x, (_Float16)x.y, (_Float16)x.z, (_Float16)x.w };
    *reinterpret_cast<f16x4*>(dst) = y;
}

// edw[e][dm][mi] (f32) -> dwc[dm][e*128+mi] (f16)
__global__ void k_cast_dw(const float* __restrict__ edw, _Float16* __restrict__ dwc) {
    int t = blockIdx.x * 256 + threadIdx.x;
    int mi4 = (t & 31) * 4;
    int dm = (t >> 5) & 2047;
    int e = t >> 16;
    float4 v = *reinterpret_cast<const float4*>(edw + (((size_t)e * 2048 + dm) << 7) + mi4);
    f16x4 o = { (_Float16)v.x, (_Float16)v.y, (_Float16)v.z, (_Float16)v.w };
    *reinterpret_cast<f16x4*>(dwc + ((size_t)dm << 11) + e * 128 + mi4) = o;
}

// egw/euw[e][mi][k] -> guw[e*256 + half*128 + mi][k] (f16)
__global__ __launch_bounds__(256) void k_cast_guw(
    const float* __restrict__ eg, const float* __restrict__ eu,
    _Float16* __restrict__ out)
{
    const int row = blockIdx.x;
    const int e = row >> 8, rem = row & 255, half = rem >> 7, mi = rem & 127;
    const float* src = (half ? eu : eg) + ((size_t)(e * 128 + mi)) * 2048;
    const int c = threadIdx.x * 8;
    float4 v0 = *reinterpret_cast<const float4*>(src + c);
    float4 v1 = *reinterpret_cast<const float4*>(src + c + 4);
    f16x8 o = { (_Float16)v0.x,(_Float16)v0.y,(_Float16)v0.z,(_Float16)v0.w,
                (_Float16)v1.x,(_Float16)v1.y,(_Float16)v1.z,(_Float16)v1.w };
    *reinterpret_cast<f16x8*>(out + (size_t)row * 2048 + c) = o;
}

// ones block 16x64: row 0 = 1.0, rows 1..15 = 0.0
__global__ void k_ones(_Float16* __restrict__ p) {
    int i = blockIdx.x * 256 + threadIdx.x;
    _Float16 v = (i < 16) ? (_Float16)1.0f : (_Float16)0.0f;
    f16x4 o = { v, v, v, v };
    *reinterpret_cast<f16x4*>(p + i * 4) = o;
}

// ---------------------------------------------------------------- rmsnorm (f16 out)
__global__ __launch_bounds__(256) void k_rmsnorm(
    const float* __restrict__ x, const float* __restrict__ w,
    _Float16* __restrict__ oh)
{
    const int row = blockIdx.x, tid = threadIdx.x;
    const float* xr = x + (size_t)row * 2048;
    float4 a = *reinterpret_cast<const float4*>(xr + tid * 8);
    float4 b = *reinterpret_cast<const float4*>(xr + tid * 8 + 4);
    float ss = a.x*a.x + a.y*a.y + a.z*a.z + a.w*a.w
             + b.x*b.x + b.y*b.y + b.z*b.z + b.w*b.w;
    #pragma unroll
    for (int m = 1; m < 64; m <<= 1) ss += __shfl_xor(ss, m);
    __shared__ float red[4];
    if ((tid & 63) == 0) red[tid >> 6] = ss;
    __syncthreads();
    float tot = red[0] + red[1] + red[2] + red[3];
    float r = rsqrtf(tot * (1.f / 2048.f) + 1e-6f);
    float4 wa = *reinterpret_cast<const float4*>(w + tid * 8);
    float4 wb = *reinterpret_cast<const float4*>(w + tid * 8 + 4);
    f16x8 hv = { (_Float16)(a.x*r*wa.x), (_Float16)(a.y*r*wa.y),
                 (_Float16)(a.z*r*wa.z), (_Float16)(a.w*r*wa.w),
                 (_Float16)(b.x*r*wb.x), (_Float16)(b.y*r*wb.y),
                 (_Float16)(b.z*r*wb.z), (_Float16)(b.w*r*wb.w) };
    *reinterpret_cast<f16x8*>(oh + (size_t)row * 2048 + tid * 8) = hv;
}

// ---------------------------------------------------------------- GEMM 128x128
__global__ __launch_bounds__(256) void k_gemm(
    const _Float16* __restrict__ A, int lda,
    const _Float16* __restrict__ W, int ldw,
    float* __restrict__ Cf, _Float16* __restrict__ Ch, int ldc,
    const float* __restrict__ resid, int K)
{
    __shared__ __align__(16) _Float16 As[3][128][32];
    __shared__ __align__(16) _Float16 Ws[3][128][32];
    const int r0 = blockIdx.x * 128, c0 = blockIdx.y * 128;
    const int tid = threadIdx.x, lane = tid & 63, wid = tid >> 6;
    const int wr = wid >> 1, wc = wid & 1;
    const int sr = lane >> 2;
    const int scs = ((lane & 3) ^ ((lane >> 3) & 3)) * 8;
    const int fr = lane & 15;
    const int rks = (((lane >> 4) ^ ((fr >> 1) & 3))) * 8;
    const f32x4 z4 = { 0.f, 0.f, 0.f, 0.f };
    f32x4 acc[4][4];
    #pragma unroll
    for (int i = 0; i < 4; i++)
        #pragma unroll
        for (int j = 0; j < 4; j++) acc[i][j] = z4;

    auto stage = [&](int bf, int k0) {
        #pragma unroll
        for (int i = 0; i < 2; i++) {
            int ch = wid * 2 + i;
            load16_lds(A + (size_t)(r0 + ch * 16 + sr) * lda + k0 + scs, &As[bf][ch * 16][0]);
            load16_lds(W + (size_t)(c0 + ch * 16 + sr) * ldw + k0 + scs, &Ws[bf][ch * 16][0]);
        }
    };

    const int nt = K >> 5;
    stage(0, 0);
    if (nt > 1) stage(1, 32);
    int cur = 0;
    for (int t = 0; t < nt; t++) {
        if (t < nt - 1) asm volatile("s_waitcnt vmcnt(4)" ::: "memory");
        else            asm volatile("s_waitcnt vmcnt(0)" ::: "memory");
        __builtin_amdgcn_s_barrier();
        f16x8 af[4], bf4[4];
        #pragma unroll
        for (int i = 0; i < 4; i++)
            af[i] = *reinterpret_cast<const f16x8*>(&As[cur][wr * 64 + i * 16 + fr][rks]);
        #pragma unroll
        for (int j = 0; j < 4; j++)
            bf4[j] = *reinterpret_cast<const f16x8*>(&Ws[cur][wc * 64 + j * 16 + fr][rks]);
        if (t + 2 < nt) stage((t + 2) % 3, (t + 2) << 5);
        __builtin_amdgcn_s_setprio(1);
        #pragma unroll
        for (int i = 0; i < 4; i++)
            #pragma unroll
            for (int j = 0; j < 4; j++)
                acc[i][j] = __builtin_amdgcn_mfma_f32_16x16x32_f16(af[i], bf4[j], acc[i][j], 0, 0, 0);
        __builtin_amdgcn_s_setprio(0);
        cur = (cur + 1) % 3;
    }
    #pragma unroll
    for (int i = 0; i < 4; i++) {
        const int rowb = r0 + wr * 64 + i * 16 + (lane >> 4) * 4;
        #pragma unroll
        for (int j = 0; j < 4; j++) {
            const int col = c0 + wc * 64 + j * 16 + fr;
            #pragma unroll
            for (int r = 0; r < 4; r++) {
                size_t idx = (size_t)(rowb + r) * ldc + col;
                float v = acc[i][j][r];
                if (resid) v += resid[idx];
                if (Ch) Ch[idx] = (_Float16)v;
                else    Cf[idx] = v;
            }
        }
    }
}

// ---------------------------------------------------------------- GEMM 256x256, 8 waves
// gu-mode (wdense!=null): fused silu(g)*u*w_e epilogue -> ab.
__global__ __launch_bounds__(512, 2) void k_gemm8(
    const _Float16* __restrict__ A, int lda,
    const _Float16* __restrict__ W, int ldw,
    _Float16* __restrict__ Ch, int ldc, int K,
    const float* __restrict__ wdense, _Float16* __restrict__ ab)
{
    __shared__ __align__(16) _Float16 As[3][256][32];
    __shared__ __align__(16) _Float16 Ws[3][256][32];
    const int r0 = blockIdx.x * 256, c0 = blockIdx.y * 256;
    const int tid = threadIdx.x, lane = tid & 63, wid = tid >> 6;
    const int wr = wid >> 2, wc = wid & 3;
    const int rA = lane >> 2;
    const int scs = ((lane & 3) ^ ((lane >> 3) & 3)) * 8;
    const int fr = lane & 15, fg = lane >> 4;
    const int rks = (((lane >> 4) ^ ((fr >> 1) & 3))) * 8;
    const f32x4 z4 = { 0.f, 0.f, 0.f, 0.f };
    f32x4 acc[8][4];
    #pragma unroll
    for (int i = 0; i < 8; i++)
        #pragma unroll
        for (int j = 0; j < 4; j++) acc[i][j] = z4;

    auto stage = [&](int bf, int k0) {
        #pragma unroll
        for (int i = 0; i < 2; i++) {
            load16_lds(A + (size_t)(r0 + i * 128 + wid * 16 + rA) * lda + k0 + scs,
                       &As[bf][i * 128 + wid * 16][0]);
            load16_lds(W + (size_t)(c0 + i * 128 + wid * 16 + rA) * ldw + k0 + scs,
                       &Ws[bf][i * 128 + wid * 16][0]);
        }
    };

    const int nt = K >> 5;
    stage(0, 0);
    if (nt > 1) stage(1, 32);
    int cur = 0;
    for (int t = 0; t < nt; t++) {
        if (t < nt - 1) asm volatile("s_waitcnt vmcnt(4)" ::: "memory");
        else            asm volatile("s_waitcnt vmcnt(0)" ::: "memory");
        __builtin_amdgcn_s_barrier();
        f16x8 af[8], bf4[4];
        #pragma unroll
        for (int i = 0; i < 8; i++)
            af[i] = *reinterpret_cast<const f16x8*>(&As[cur][wr * 128 + i * 16 + fr][rks]);
        #pragma unroll
        for (int j = 0; j < 4; j++)
            bf4[j] = *reinterpret_cast<const f16x8*>(&Ws[cur][wc * 64 + j * 16 + fr][rks]);
        if (t + 2 < nt) stage((t + 2) % 3, (t + 2) << 5);
        __builtin_amdgcn_s_setprio(1);
        #pragma unroll
        for (int i = 0; i < 8; i++)
            #pragma unroll
            for (int j = 0; j < 4; j++)
                acc[i][j] = __builtin_amdgcn_mfma_f32_16x16x32_f16(af[i], bf4[j], acc[i][j], 0, 0, 0);
        __builtin_amdgcn_s_setprio(0);
        cur = (cur + 1) % 3;
    }

    if (!wdense) {
        #pragma unroll
        for (int i = 0; i < 8; i++) {
            const int rowb = r0 + wr * 128 + i * 16 + fg * 4;
            #pragma unroll
            for (int j = 0; j < 4; j++) {
                const int col = c0 + wc * 64 + j * 16 + fr;
                #pragma unroll
                for (int r = 0; r < 4; r++)
                    Ch[(size_t)(rowb + r) * ldc + col] = (_Float16)acc[i][j][r];
            }
        }
        return;
    }

    _Float16* LgA = &As[0][0][0];
    _Float16* LgB = &Ws[0][0][0];
    auto lgp = [&](int row, int mi) -> _Float16* {
        return ((row < 128) ? LgA : LgB) + (size_t)(row & 127) * 136 + mi;
    };
    const int e = blockIdx.y;
    __syncthreads();
    if (wc < 2) {
        #pragma unroll
        for (int i = 0; i < 8; i++) {
            const int row = wr * 128 + i * 16 + fg * 4;
            #pragma unroll
            for (int j = 0; j < 4; j++) {
                const int mi = wc * 64 + j * 16 + fr;
                #pragma unroll
                for (int r = 0; r < 4; r++)
                    *lgp(row + r, mi) = (_Float16)acc[i][j][r];
            }
        }
    }
    __syncthreads();
    if (wc >= 2) {
        #pragma unroll
        for (int i = 0; i < 8; i++) {
            const int row = wr * 128 + i * 16 + fg * 4;
            #pragma unroll
            for (int j = 0; j < 4; j++) {
                const int mi = (wc - 2) * 64 + j * 16 + fr;
                #pragma unroll
                for (int r = 0; r < 4; r++) {
                    float g = (float)*lgp(row + r, mi);
                    float sil = g / (1.f + __expf(-g));
                    *lgp(row + r, mi) = (_Float16)(sil * acc[i][j][r]);
                }
            }
        }
    }
    __syncthreads();
    #pragma unroll
    for (int pass = 0; pass < 8; pass++) {
        int cid = pass * 512 + tid;
        int row = cid >> 4, col8 = cid & 15;
        f16x8 v = *reinterpret_cast<const f16x8*>(
            ((row < 128) ? LgA : LgB) + (size_t)(row & 127) * 136 + col8 * 8);
        float wv = wdense[(size_t)e * 4096 + r0 + row];
        f16x8 o;
        #pragma unroll
        for (int j = 0; j < 8; j++) o[j] = (_Float16)((float)v[j] * wv);
        *reinterpret_cast<f16x8*>(ab + (size_t)(r0 + row) * 2048 + e * 128 + col8 * 8) = o;
    }
}

// ------------------------------------------- per-head RMSNorm + RoPE (wave-per-head)
__global__ __launch_bounds__(256) void k_qkv_post(
    const _Float16* __restrict__ qkv,
    const float* __restrict__ cosb, const float* __restrict__ sinb,
    const float* __restrict__ qn_w, const float* __restrict__ kn_w,
    _Float16* __restrict__ qh, _Float16* __restrict__ kh)
{
    const int tok = blockIdx.x;
    const int u = blockIdx.y * 4 + (threadIdx.x >> 6);
    const int lane = threadIdx.x & 63;
    const int b = tok >> 10, l = tok & 1023;
    const float SCL = 0.12752887074166638f;   // 1/sqrt(128) * log2(e)
    const float c0 = cosb[(size_t)tok * 128 + lane];
    const float c1 = cosb[(size_t)tok * 128 + lane + 64];
    const float s0 = sinb[(size_t)tok * 128 + lane];
    const float s1 = sinb[(size_t)tok * 128 + lane + 64];
    if (u < 32) {
        const _Float16* base = qkv + (size_t)tok * 5120 + u * 128;
        float v0 = (float)base[lane], v1 = (float)base[lane + 64];
        float ss = v0 * v0 + v1 * v1;
        #pragma unroll
        for (int m = 1; m < 64; m <<= 1) ss += __shfl_xor(ss, m);
        float rms = rsqrtf(ss * (1.f / 128.f) + 1e-6f);
        float n0 = v0 * rms * qn_w[lane], n1 = v1 * rms * qn_w[lane + 64];
        _Float16* o = qh + (size_t)tok * 4096 + u * 128;
        o[lane]      = (_Float16)(SCL * (c0 * n0 - s0 * n1));
        o[lane + 64] = (_Float16)(SCL * (c1 * n1 + s1 * n0));
    } else {
        const int kvh = u - 32;
        const _Float16* base = qkv + (size_t)tok * 5120 + 4096 + kvh * 128;
        float v0 = (float)base[lane], v1 = (float)base[lane + 64];
        float ss = v0 * v0 + v1 * v1;
        #pragma unroll
        for (int m = 1; m < 64; m <<= 1) ss += __shfl_xor(ss, m);
        float rms = rsqrtf(ss * (1.f / 128.f) + 1e-6f);
        float n0 = v0 * rms * kn_w[lane], n1 = v1 * rms * kn_w[lane + 64];
        _Float16* o = kh + (((size_t)(b * 4 + kvh)) * 1024 + l) * 128;
        o[lane]      = (_Float16)(c0 * n0 - s0 * n1);
        o[lane + 64] = (_Float16)(c1 * n1 + s1 * n0);
    }
}

// ---------------------------------------------------------------- V transpose
__global__ __launch_bounds__(256) void k_vt(
    const _Float16* __restrict__ qkv, _Float16* __restrict__ vth)
{
    const int bkv = blockIdx.x;
    const int b = bkv >> 2, kv = bkv & 3;
    const int l0 = blockIdx.y * 64, d0 = blockIdx.z * 64;
    __shared__ _Float16 T[64][72];
    const int t = threadIdx.x;
    const int r = t >> 3, c8 = (t & 7) * 8;
    #pragma unroll
    for (int rr = 0; rr < 2; rr++) {
        int l = l0 + r + rr * 32;
        *reinterpret_cast<f16x8*>(&T[r + rr * 32][c8]) =
            *reinterpret_cast<const f16x8*>(
                qkv + (size_t)(b * 1024 + l) * 5120 + 4608 + kv * 128 + d0 + c8);
    }
    __syncthreads();
    #pragma unroll
    for (int rr = 0; rr < 2; rr++) {
        int d = d0 + r + rr * 32;
        f16x8 v;
        #pragma unroll
        for (int j = 0; j < 8; j++) v[j] = T[c8 + j][r + rr * 32];
        *reinterpret_cast<f16x8*>(vth + ((size_t)(bkv * 128 + d)) * 1024 + l0 + c8) = v;
    }
}

// ---------------------------------------------------------------- attention
// 8 waves x 32 q-rows (2 m-tiles/wave) = 256 q-rows/block; grid (128 bh, 4).
// Fixed-max exp2 softmax (scores bounded: |q||k|*SCL <= 16.32, m=8 const).
// Double-buffered K/V staging under compute; l via ones-column MFMA.
__global__ __launch_bounds__(512) void k_attn(
    const _Float16* __restrict__ qh, const _Float16* __restrict__ kh,
    const _Float16* __restrict__ vth, const _Float16* __restrict__ ones16,
    _Float16* __restrict__ oh)
{
    const int bh = blockIdx.x;
    const int qb = 3 - blockIdx.y;               // longest blocks first
    const int b = bh >> 5, h = bh & 31, kv = h >> 3;
    const int tid = threadIdx.x, lane = tid & 63, wid = tid >> 6;   // wid 0..7
    const int fr = lane & 15, fg = lane >> 4;
    const int q0w = qb * 256 + wid * 32;

    __shared__ __align__(16) _Float16 Ks[2][64][128];   // 32 KB
    __shared__ __align__(16) _Float16 Vs[2][128][64];   // 32 KB
    __shared__ __align__(16) _Float16 Vones[16][64];    //  2 KB
    __shared__ __align__(16) _Float16 Ps[8][32][72];    // 36 KB

    const _Float16* kb = kh + ((size_t)(b * 4 + kv)) * 1024 * 128;
    const _Float16* vb = vth + ((size_t)(b * 4 + kv)) * 128 * 1024;

    auto stage = [&](int nb, int key0) {
        #pragma unroll
        for (int i = 0; i < 2; i++) {              // K rows wid*8 .. +7
            int rr = wid * 8 + i * 4 + (lane >> 4);
            int c16 = (lane & 15) ^ (rr & 15);
            load16_lds(kb + (size_t)(key0 + rr) * 128 + c16 * 8,
                       &Ks[nb][0][0] + (wid * 8 + i * 4) * 128);
        }
        #pragma unroll
        for (int i = 0; i < 2; i++) {              // V rows wid*16 .. +15
            int rr = wid * 16 + i * 8 + (lane >> 3);
            int c16 = (lane & 7) ^ (rr & 7);
            load16_lds(vb + (size_t)rr * 1024 + key0 + c16 * 8,
                       &Vs[nb][0][0] + (wid * 16 + i * 8) * 64);
        }
    };

    f16x8 aq[2][4];
    #pragma unroll
    for (int mi = 0; mi < 2; mi++) {
        const _Float16* qbase =
            qh + ((size_t)(b * 1024 + q0w + mi * 16 + fr)) * 4096 + h * 128;
        #pragma unroll
        for (int kk = 0; kk < 4; kk++)
            aq[mi][kk] = *reinterpret_cast<const f16x8*>(qbase + kk * 32 + fg * 8);
    }
    if (wid == 0) {
        #pragma unroll
        for (int i = 0; i < 2; i++)
            load16_lds(ones16 + (size_t)(lane + i * 64) * 8, &Vones[0][0] + i * 512);
    }
    stage(0, 0);

    const f32x4 z4 = { 0.f, 0.f, 0.f, 0.f };
    f32x4 oacc[2][9];
    #pragma unroll
    for (int mi = 0; mi < 2; mi++)
        #pragma unroll
        for (int dj = 0; dj < 9; dj++) oacc[mi][dj] = z4;

    const int ntiles = qb * 4 + 4;
    int cb = 0;
    for (int kt = 0; kt < ntiles; kt++) {
        const int key0 = kt * 64;
        asm volatile("s_waitcnt vmcnt(0)" ::: "memory");
        __builtin_amdgcn_s_barrier();
        if (kt + 1 < ntiles) stage(cb ^ 1, key0 + 64);

        if (key0 <= q0w + 31) {                    // wave has unmasked work
            f32x4 sc[2][4];
            #pragma unroll
            for (int mi = 0; mi < 2; mi++)
                #pragma unroll
                for (int j = 0; j < 4; j++) sc[mi][j] = z4;
            #pragma unroll
            for (int j = 0; j < 4; j++)
                #pragma unroll
                for (int kk = 0; kk < 4; kk++) {
                    f16x8 bk = *reinterpret_cast<const f16x8*>(
                        &Ks[cb][0][0] + (j * 16 + fr) * 128 + (((kk * 4 + fg) ^ fr) * 8));
                    #pragma unroll
                    for (int mi = 0; mi < 2; mi++)
                        sc[mi][j] = __builtin_amdgcn_mfma_f32_16x16x32_f16(
                            aq[mi][kk], bk, sc[mi][j], 0, 0, 0);
                }

            const bool maskt = (key0 + 63 > q0w);
            #pragma unroll
            for (int mi = 0; mi < 2; mi++)
                #pragma unroll
                for (int j = 0; j < 4; j++) {
                    const int key = key0 + j * 16 + fr;
                    #pragma unroll
                    for (int r = 0; r < 4; r++) {
                        float v = sc[mi][j][r];
                        if (maskt && key > q0w + mi * 16 + fg * 4 + r) v = -1e30f;
                        Ps[wid][mi * 16 + fg * 4 + r][j * 16 + fr] =
                            (_Float16)__builtin_amdgcn_exp2f(v - 8.f);
                    }
                }

            #pragma unroll
            for (int ks = 0; ks < 2; ks++) {
                f16x8 ap0 = *reinterpret_cast<const f16x8*>(
                    &Ps[wid][fr][ks * 32 + fg * 8]);
                f16x8 ap1 = *reinterpret_cast<const f16x8*>(
                    &Ps[wid][16 + fr][ks * 32 + fg * 8]);
                #pragma unroll
                for (int dj = 0; dj < 8; dj++) {
                    f16x8 bv = *reinterpret_cast<const f16x8*>(
                        &Vs[cb][0][0] + (dj * 16 + fr) * 64 + (((ks * 4 + fg) ^ (fr & 7)) * 8));
                    oacc[0][dj] = __builtin_amdgcn_mfma_f32_16x16x32_f16(ap0, bv, oacc[0][dj], 0, 0, 0);
                    oacc[1][dj] = __builtin_amdgcn_mfma_f32_16x16x32_f16(ap1, bv, oacc[1][dj], 0, 0, 0);
                }
                f16x8 bo = *reinterpret_cast<const f16x8*>(
                    &Vones[0][0] + fr * 64 + (((ks * 4 + fg) ^ (fr & 7)) * 8));
                oacc[0][8] = __builtin_amdgcn_mfma_f32_16x16x32_f16(ap0, bo, oacc[0][8], 0, 0, 0);
                oacc[1][8] = __builtin_amdgcn_mfma_f32_16x16x32_f16(ap1, bo, oacc[1][8], 0, 0, 0);
            }
        }
        cb ^= 1;
    }

    #pragma unroll
    for (int mi = 0; mi < 2; mi++) {
        float inv[4];
        #pragma unroll
        for (int r = 0; r < 4; r++) {
            float l = __shfl(oacc[mi][8][r], lane & 48);
            inv[r] = 1.f / l;
        }
        #pragma unroll
        for (int dj = 0; dj < 8; dj++)
            #pragma unroll
            for (int r = 0; r < 4; r++)
                oh[((size_t)(b * 1024 + q0w + mi * 16 + fg * 4 + r)) * 4096
                   + h * 128 + dj * 16 + fr] = (_Float16)(oacc[mi][dj][r] * inv[r]);
    }
}

// ---------------------------------------------------------------- router (inline rmsnorm from x2)
__global__ __launch_bounds__(256) void k_router(
    const float* __restrict__ x2, const float* __restrict__ wm,
    const float* __restrict__ rw, float* __restrict__ wdense)
{
    const int tok = blockIdx.x * 4 + (threadIdx.x >> 6);
    const int lane = threadIdx.x & 63;
    __shared__ float lg[4][16];
    const float* hr = x2 + (size_t)tok * 2048;
    float vals[32];
    float ss = 0.f;
    #pragma unroll
    for (int i = 0; i < 32; i++) { float v = hr[i * 64 + lane]; vals[i] = v; ss += v * v; }
    #pragma unroll
    for (int m = 1; m < 64; m <<= 1) ss += __shfl_xor(ss, m);
    float r = rsqrtf(ss * (1.f / 2048.f) + 1e-6f);
    #pragma unroll
    for (int i = 0; i < 32; i++) vals[i] *= r * wm[i * 64 + lane];
    for (int e = 0; e < 16; e++) {
        float acc = 0.f;
        #pragma unroll
        for (int i = 0; i < 32; i++) acc += vals[i] * rw[(size_t)e * 2048 + i * 64 + lane];
        #pragma unroll
        for (int m = 1; m < 64; m <<= 1) acc += __shfl_xor(acc, m);
        if (lane == 0) lg[threadIdx.x >> 6][e] = acc;
    }
    __syncthreads();
    if (lane == 0) {
        float* l = lg[threadIdx.x >> 6];
        float mx = l[0];
        for (int e = 1; e < 16; e++) mx = fmaxf(mx, l[e]);
        float p[16]; float sum = 0.f;
        for (int e = 0; e < 16; e++) { p[e] = expf(l[e] - mx); sum += p[e]; }
        for (int e = 0; e < 16; e++) p[e] /= sum;
        bool sel[16]; for (int e = 0; e < 16; e++) sel[e] = false;
        float ssum = 0.f;
        for (int t = 0; t < 8; t++) {
            int bi = -1; float bv = -1.f;
            for (int e = 0; e < 16; e++) if (!sel[e] && p[e] > bv) { bv = p[e]; bi = e; }
            sel[bi] = true; ssum += bv;
        }
        for (int e = 0; e < 16; e++)
            wdense[(size_t)e * 4096 + tok] = sel[e] ? p[e] / ssum : 0.f;
    }
}

// ---------------------------------------------------------------- launch

extern "C" void kernel_launch(void* const* d_in, const int* in_sizes, int n_in,
                              void* d_out, int out_size, void* d_ws, size_t ws_size,
                              hipStream_t stream)
{
    const float* x        = (const float*)d_in[0];
    const float* cosb     = (const float*)d_in[1];
    const float* sinb     = (const float*)d_in[2];
    const float* nattn    = (const float*)d_in[3];
    const float* q_w      = (const float*)d_in[4];
    const float* k_w      = (const float*)d_in[5];
    const float* v_w      = (const float*)d_in[6];
    const float* qn_w     = (const float*)d_in[7];
    const float* kn_w     = (const float*)d_in[8];
    const float* o_w      = (const float*)d_in[9];
    const float* nmlp     = (const float*)d_in[10];
    const float* router_w = (const float*)d_in[11];
    const float* egw      = (const float*)d_in[12];
    const float* euw      = (const float*)d_in[13];
    const float* edw      = (const float*)d_in[14];

    char* w = (char*)d_ws;
    _Float16* qkvw_h = (_Float16*)(w + 0);          // 20.97 MB
    _Float16* ow_h   = (_Float16*)(w + 20971520);   // 16.78 MB
    _Float16* guw_h  = (_Float16*)(w + 37748736);   // 16.78 MB
    _Float16* dwc_h  = (_Float16*)(w + 54525952);   //  8.39 MB
    _Float16* h_h    = (_Float16*)(w + 62914560);   // 16.78 MB (aliased hm_h)
    _Float16* hm_h   = h_h;
    float*    x2     = (float*)(w + 79691776);      // 33.55 MB
    _Float16* qkv_h  = (_Float16*)(w + 113246208);  // 41.94 MB (alias o_h, ab_h)
    _Float16* o_h    = qkv_h;
    _Float16* ab_h   = qkv_h;
    _Float16* q_h    = (_Float16*)(w + 155189248);  // 33.55 MB
    _Float16* k_h    = (_Float16*)(w + 188743680);  //  4.19 MB
    _Float16* vt_h   = (_Float16*)(w + 192937984);  //  4.19 MB
    float*    wdense = (float*)(w + 197132288);     //  0.26 MB
    _Float16* ones_h = (_Float16*)(w + 197394432);  //  2 KB (16x64 f16)

    k_cast4<<<18432, 256, 0, stream>>>(q_w, k_w, v_w, o_w, qkvw_h, ow_h);
    k_cast_guw<<<4096, 256, 0, stream>>>(egw, euw, guw_h);
    k_cast_dw<<<4096, 256, 0, stream>>>(edw, dwc_h);
    k_ones<<<1, 256, 0, stream>>>(ones_h);

    k_rmsnorm<<<4096, 256, 0, stream>>>(x, nattn, h_h);
    k_gemm8<<<dim3(16, 16), 512, 0, stream>>>(h_h, 2048, qkvw_h, 2048, qkv_h, 5120, 2048,
                                              nullptr, nullptr);
    k_gemm<<<dim3(32, 8), 256, 0, stream>>>(h_h, 2048, qkvw_h + (size_t)4096 * 2048, 2048,
                                            nullptr, qkv_h + 4096, 5120, nullptr, 2048);
    k_qkv_post<<<dim3(4096, 9), 256, 0, stream>>>(qkv_h, cosb, sinb, qn_w, kn_w, q_h, k_h);
    k_vt<<<dim3(16, 16, 2), 256, 0, stream>>>(qkv_h, vt_h);
    k_attn<<<dim3(128, 4), 512, 0, stream>>>(q_h, k_h, vt_h, ones_h, o_h);
    k_gemm<<<dim3(32, 16), 256, 0, stream>>>(o_h, 4096, ow_h, 4096,
                                             x2, nullptr, 2048, x, 4096);
    k_rmsnorm<<<4096, 256, 0, stream>>>(x2, nmlp, hm_h);
    k_router<<<1024, 256, 0, stream>>>(x2, nmlp, router_w, wdense);
    k_gemm8<<<dim3(16, 16), 512, 0, stream>>>(hm_h, 2048, guw_h, 2048, nullptr, 0, 2048,
                                              wdense, ab_h);
    k_gemm<<<dim3(32, 16), 256, 0, stream>>>(ab_h, 2048, dwc_h, 2048,
                                             (float*)d_out, nullptr, 2048, x2, 2048);

    (void)in_sizes; (void)n_in; (void)out_size; (void)ws_size;
}

// Round 14
// 481.810 us; speedup vs baseline: 1.3902x; 1.0087x over previous
//
#include <hip/hip_runtime.h>
#include <stdint.h>

typedef _Float16 f16x8 __attribute__((ext_vector_type(8)));
typedef _Float16 f16x4 __attribute__((ext_vector_type(4)));
typedef float    f32x4 __attribute__((ext_vector_type(4)));

__device__ __forceinline__ void load16_lds(const _Float16* g, _Float16* l) {
    __builtin_amdgcn_global_load_lds(
        (const __attribute__((address_space(1))) void*)g,
        (__attribute__((address_space(3))) void*)l, 16, 0, 0);
}

// ---------------------------------------------------------------- casts

__global__ void k_cast4(const float* __restrict__ q, const float* __restrict__ k,
                        const float* __restrict__ v, const float* __restrict__ o,
                        _Float16* __restrict__ qkvw, _Float16* __restrict__ ow)
{
    size_t i = ((size_t)blockIdx.x * 256 + threadIdx.x) * 4;
    const float* src; _Float16* dst;
    if (i < 8388608)        { src = q + i;            dst = qkvw + i; }
    else if (i < 9437184)   { src = k + (i - 8388608); dst = qkvw + i; }
    else if (i < 10485760)  { src = v + (i - 9437184); dst = qkvw + i; }
    else                    { src = o + (i - 10485760); dst = ow + (i - 10485760); }
    float4 x = *reinterpret_cast<const float4*>(src);
    f16x4 y = { (_Float16)x.x, (_Float16)x.y, (_Float16)x.z, (_Float16)x.w };
    *reinterpret_cast<f16x4*>(dst) = y;
}

// edw[e][dm][mi] (f32) -> dwc[dm][e*128+mi] (f16)
__global__ void k_cast_dw(const float* __restrict__ edw, _Float16* __restrict__ dwc) {
    int t = blockIdx.x * 256 + threadIdx.x;
    int mi4 = (t & 31) * 4;
    int dm = (t >> 5) & 2047;
    int e = t >> 16;
    float4 v = *reinterpret_cast<const float4*>(edw + (((size_t)e * 2048 + dm) << 7) + mi4);
    f16x4 o = { (_Float16)v.x, (_Float16)v.y, (_Float16)v.z, (_Float16)v.w };
    *reinterpret_cast<f16x4*>(dwc + ((size_t)dm << 11) + e * 128 + mi4) = o;
}

// egw/euw[e][mi][k] -> guw[e*256 + half*128 + mi][k] (f16); last block inits ones
__global__ __launch_bounds__(256) void k_cast_guw(
    const float* __restrict__ eg, const float* __restrict__ eu,
    _Float16* __restrict__ out, _Float16* __restrict__ ones16)
{
    const int row = blockIdx.x;
    if (row == 4096) {                        // ones block 16x64
        int i = threadIdx.x;
        _Float16 v = (i < 16) ? (_Float16)1.0f : (_Float16)0.0f;
        f16x4 o = { v, v, v, v };
        *reinterpret_cast<f16x4*>(ones16 + i * 4) = o;
        return;
    }
    const int e = row >> 8, rem = row & 255, half = rem >> 7, mi = rem & 127;
    const float* src = (half ? eu : eg) + ((size_t)(e * 128 + mi)) * 2048;
    const int c = threadIdx.x * 8;
    float4 v0 = *reinterpret_cast<const float4*>(src + c);
    float4 v1 = *reinterpret_cast<const float4*>(src + c + 4);
    f16x8 o = { (_Float16)v0.x,(_Float16)v0.y,(_Float16)v0.z,(_Float16)v0.w,
                (_Float16)v1.x,(_Float16)v1.y,(_Float16)v1.z,(_Float16)v1.w };
    *reinterpret_cast<f16x8*>(out + (size_t)row * 2048 + c) = o;
}

// ---------------------------------------------------------------- rmsnorm (f16 out)
__global__ __launch_bounds__(256) void k_rmsnorm(
    const float* __restrict__ x, const float* __restrict__ w,
    _Float16* __restrict__ oh)
{
    const int row = blockIdx.x, tid = threadIdx.x;
    const float* xr = x + (size_t)row * 2048;
    float4 a = *reinterpret_cast<const float4*>(xr + tid * 8);
    float4 b = *reinterpret_cast<const float4*>(xr + tid * 8 + 4);
    float ss = a.x*a.x + a.y*a.y + a.z*a.z + a.w*a.w
             + b.x*b.x + b.y*b.y + b.z*b.z + b.w*b.w;
    #pragma unroll
    for (int m = 1; m < 64; m <<= 1) ss += __shfl_xor(ss, m);
    __shared__ float red[4];
    if ((tid & 63) == 0) red[tid >> 6] = ss;
    __syncthreads();
    float tot = red[0] + red[1] + red[2] + red[3];
    float r = rsqrtf(tot * (1.f / 2048.f) + 1e-6f);
    float4 wa = *reinterpret_cast<const float4*>(w + tid * 8);
    float4 wb = *reinterpret_cast<const float4*>(w + tid * 8 + 4);
    f16x8 hv = { (_Float16)(a.x*r*wa.x), (_Float16)(a.y*r*wa.y),
                 (_Float16)(a.z*r*wa.z), (_Float16)(a.w*r*wa.w),
                 (_Float16)(b.x*r*wb.x), (_Float16)(b.y*r*wb.y),
                 (_Float16)(b.z*r*wb.z), (_Float16)(b.w*r*wb.w) };
    *reinterpret_cast<f16x8*>(oh + (size_t)row * 2048 + tid * 8) = hv;
}

// ---------------------------------------------------------------- GEMM 128x128
// (used for KV projection only)
__global__ __launch_bounds__(256) void k_gemm(
    const _Float16* __restrict__ A, int lda,
    const _Float16* __restrict__ W, int ldw,
    float* __restrict__ Cf, _Float16* __restrict__ Ch, int ldc,
    const float* __restrict__ resid, int K)
{
    __shared__ __align__(16) _Float16 As[3][128][32];
    __shared__ __align__(16) _Float16 Ws[3][128][32];
    const int r0 = blockIdx.x * 128, c0 = blockIdx.y * 128;
    const int tid = threadIdx.x, lane = tid & 63, wid = tid >> 6;
    const int wr = wid >> 1, wc = wid & 1;
    const int sr = lane >> 2;
    const int scs = ((lane & 3) ^ ((lane >> 3) & 3)) * 8;
    const int fr = lane & 15;
    const int rks = (((lane >> 4) ^ ((fr >> 1) & 3))) * 8;
    const f32x4 z4 = { 0.f, 0.f, 0.f, 0.f };
    f32x4 acc[4][4];
    #pragma unroll
    for (int i = 0; i < 4; i++)
        #pragma unroll
        for (int j = 0; j < 4; j++) acc[i][j] = z4;

    auto stage = [&](int bf, int k0) {
        #pragma unroll
        for (int i = 0; i < 2; i++) {
            int ch = wid * 2 + i;
            load16_lds(A + (size_t)(r0 + ch * 16 + sr) * lda + k0 + scs, &As[bf][ch * 16][0]);
            load16_lds(W + (size_t)(c0 + ch * 16 + sr) * ldw + k0 + scs, &Ws[bf][ch * 16][0]);
        }
    };

    const int nt = K >> 5;
    stage(0, 0);
    if (nt > 1) stage(1, 32);
    int cur = 0;
    for (int t = 0; t < nt; t++) {
        if (t < nt - 1) asm volatile("s_waitcnt vmcnt(4)" ::: "memory");
        else            asm volatile("s_waitcnt vmcnt(0)" ::: "memory");
        __builtin_amdgcn_s_barrier();
        f16x8 af[4], bf4[4];
        #pragma unroll
        for (int i = 0; i < 4; i++)
            af[i] = *reinterpret_cast<const f16x8*>(&As[cur][wr * 64 + i * 16 + fr][rks]);
        #pragma unroll
        for (int j = 0; j < 4; j++)
            bf4[j] = *reinterpret_cast<const f16x8*>(&Ws[cur][wc * 64 + j * 16 + fr][rks]);
        if (t + 2 < nt) stage((t + 2) % 3, (t + 2) << 5);
        __builtin_amdgcn_s_setprio(1);
        #pragma unroll
        for (int i = 0; i < 4; i++)
            #pragma unroll
            for (int j = 0; j < 4; j++)
                acc[i][j] = __builtin_amdgcn_mfma_f32_16x16x32_f16(af[i], bf4[j], acc[i][j], 0, 0, 0);
        __builtin_amdgcn_s_setprio(0);
        cur = (cur + 1) % 3;
    }
    #pragma unroll
    for (int i = 0; i < 4; i++) {
        const int rowb = r0 + wr * 64 + i * 16 + (lane >> 4) * 4;
        #pragma unroll
        for (int j = 0; j < 4; j++) {
            const int col = c0 + wc * 64 + j * 16 + fr;
            #pragma unroll
            for (int r = 0; r < 4; r++) {
                size_t idx = (size_t)(rowb + r) * ldc + col;
                float v = acc[i][j][r];
                if (resid) v += resid[idx];
                if (Ch) Ch[idx] = (_Float16)v;
                else    Cf[idx] = v;
            }
        }
    }
}

// ---------------------------------------------------------------- GEMM 128x256, 4 waves
// Wave-tile 128x64 (32 MFMA / 12 ds_read), 3-ring counted vmcnt(6), swizzled.
// f32 output + residual. Used for O-proj and MoE down (N=2048 -> 256 blocks).
__global__ __launch_bounds__(256, 2) void k_gemmw(
    const _Float16* __restrict__ A, int lda,
    const _Float16* __restrict__ W, int ldw,
    float* __restrict__ Cf, int ldc,
    const float* __restrict__ resid, int K)
{
    __shared__ __align__(16) _Float16 As[3][128][32];   // 24 KB
    __shared__ __align__(16) _Float16 Ws[3][256][32];   // 48 KB
    const int r0 = blockIdx.x * 128, c0 = blockIdx.y * 256;
    const int tid = threadIdx.x, lane = tid & 63, wid = tid >> 6;   // 0..3
    const int sr = lane >> 2;
    const int scs = ((lane & 3) ^ ((lane >> 3) & 3)) * 8;
    const int fr = lane & 15, fg = lane >> 4;
    const int rks = (((lane >> 4) ^ ((fr >> 1) & 3))) * 8;
    const f32x4 z4 = { 0.f, 0.f, 0.f, 0.f };
    f32x4 acc[8][4];
    #pragma unroll
    for (int i = 0; i < 8; i++)
        #pragma unroll
        for (int j = 0; j < 4; j++) acc[i][j] = z4;

    auto stage = [&](int bf, int k0) {
        #pragma unroll
        for (int i = 0; i < 2; i++) {               // A: 8 chunks of 16 rows
            int ch = wid * 2 + i;
            load16_lds(A + (size_t)(r0 + ch * 16 + sr) * lda + k0 + scs, &As[bf][ch * 16][0]);
        }
        #pragma unroll
        for (int i = 0; i < 4; i++) {               // W: 16 chunks
            int ch = wid * 4 + i;
            load16_lds(W + (size_t)(c0 + ch * 16 + sr) * ldw + k0 + scs, &Ws[bf][ch * 16][0]);
        }
    };

    const int nt = K >> 5;
    stage(0, 0);
    if (nt > 1) stage(1, 32);
    int cur = 0;
    for (int t = 0; t < nt; t++) {
        if (t < nt - 1) asm volatile("s_waitcnt vmcnt(6)" ::: "memory");
        else            asm volatile("s_waitcnt vmcnt(0)" ::: "memory");
        __builtin_amdgcn_s_barrier();
        f16x8 af[8], bf4[4];
        #pragma unroll
        for (int i = 0; i < 8; i++)
            af[i] = *reinterpret_cast<const f16x8*>(&As[cur][i * 16 + fr][rks]);
        #pragma unroll
        for (int j = 0; j < 4; j++)
            bf4[j] = *reinterpret_cast<const f16x8*>(&Ws[cur][wid * 64 + j * 16 + fr][rks]);
        if (t + 2 < nt) stage((t + 2) % 3, (t + 2) << 5);
        __builtin_amdgcn_s_setprio(1);
        #pragma unroll
        for (int i = 0; i < 8; i++)
            #pragma unroll
            for (int j = 0; j < 4; j++)
                acc[i][j] = __builtin_amdgcn_mfma_f32_16x16x32_f16(af[i], bf4[j], acc[i][j], 0, 0, 0);
        __builtin_amdgcn_s_setprio(0);
        cur = (cur + 1) % 3;
    }
    #pragma unroll
    for (int i = 0; i < 8; i++) {
        const int rowb = r0 + i * 16 + fg * 4;
        #pragma unroll
        for (int j = 0; j < 4; j++) {
            const int col = c0 + wid * 64 + j * 16 + fr;
            #pragma unroll
            for (int r = 0; r < 4; r++) {
                size_t idx = (size_t)(rowb + r) * ldc + col;
                Cf[idx] = acc[i][j][r] + resid[idx];
            }
        }
    }
}

// ---------------------------------------------------------------- GEMM 256x256, 8 waves
// gu-mode (wdense!=null): fused silu(g)*u*w_e epilogue -> ab.
__global__ __launch_bounds__(512, 2) void k_gemm8(
    const _Float16* __restrict__ A, int lda,
    const _Float16* __restrict__ W, int ldw,
    _Float16* __restrict__ Ch, int ldc, int K,
    const float* __restrict__ wdense, _Float16* __restrict__ ab)
{
    __shared__ __align__(16) _Float16 As[3][256][32];
    __shared__ __align__(16) _Float16 Ws[3][256][32];
    const int r0 = blockIdx.x * 256, c0 = blockIdx.y * 256;
    const int tid = threadIdx.x, lane = tid & 63, wid = tid >> 6;
    const int wr = wid >> 2, wc = wid & 3;
    const int rA = lane >> 2;
    const int scs = ((lane & 3) ^ ((lane >> 3) & 3)) * 8;
    const int fr = lane & 15, fg = lane >> 4;
    const int rks = (((lane >> 4) ^ ((fr >> 1) & 3))) * 8;
    const f32x4 z4 = { 0.f, 0.f, 0.f, 0.f };
    f32x4 acc[8][4];
    #pragma unroll
    for (int i = 0; i < 8; i++)
        #pragma unroll
        for (int j = 0; j < 4; j++) acc[i][j] = z4;

    auto stage = [&](int bf, int k0) {
        #pragma unroll
        for (int i = 0; i < 2; i++) {
            load16_lds(A + (size_t)(r0 + i * 128 + wid * 16 + rA) * lda + k0 + scs,
                       &As[bf][i * 128 + wid * 16][0]);
            load16_lds(W + (size_t)(c0 + i * 128 + wid * 16 + rA) * ldw + k0 + scs,
                       &Ws[bf][i * 128 + wid * 16][0]);
        }
    };

    const int nt = K >> 5;
    stage(0, 0);
    if (nt > 1) stage(1, 32);
    int cur = 0;
    for (int t = 0; t < nt; t++) {
        if (t < nt - 1) asm volatile("s_waitcnt vmcnt(4)" ::: "memory");
        else            asm volatile("s_waitcnt vmcnt(0)" ::: "memory");
        __builtin_amdgcn_s_barrier();
        f16x8 af[8], bf4[4];
        #pragma unroll
        for (int i = 0; i < 8; i++)
            af[i] = *reinterpret_cast<const f16x8*>(&As[cur][wr * 128 + i * 16 + fr][rks]);
        #pragma unroll
        for (int j = 0; j < 4; j++)
            bf4[j] = *reinterpret_cast<const f16x8*>(&Ws[cur][wc * 64 + j * 16 + fr][rks]);
        if (t + 2 < nt) stage((t + 2) % 3, (t + 2) << 5);
        __builtin_amdgcn_s_setprio(1);
        #pragma unroll
        for (int i = 0; i < 8; i++)
            #pragma unroll
            for (int j = 0; j < 4; j++)
                acc[i][j] = __builtin_amdgcn_mfma_f32_16x16x32_f16(af[i], bf4[j], acc[i][j], 0, 0, 0);
        __builtin_amdgcn_s_setprio(0);
        cur = (cur + 1) % 3;
    }

    if (!wdense) {
        #pragma unroll
        for (int i = 0; i < 8; i++) {
            const int rowb = r0 + wr * 128 + i * 16 + fg * 4;
            #pragma unroll
            for (int j = 0; j < 4; j++) {
                const int col = c0 + wc * 64 + j * 16 + fr;
                #pragma unroll
                for (int r = 0; r < 4; r++)
                    Ch[(size_t)(rowb + r) * ldc + col] = (_Float16)acc[i][j][r];
            }
        }
        return;
    }

    _Float16* LgA = &As[0][0][0];
    _Float16* LgB = &Ws[0][0][0];
    auto lgp = [&](int row, int mi) -> _Float16* {
        return ((row < 128) ? LgA : LgB) + (size_t)(row & 127) * 136 + mi;
    };
    const int e = blockIdx.y;
    __syncthreads();
    if (wc < 2) {
        #pragma unroll
        for (int i = 0; i < 8; i++) {
            const int row = wr * 128 + i * 16 + fg * 4;
            #pragma unroll
            for (int j = 0; j < 4; j++) {
                const int mi = wc * 64 + j * 16 + fr;
                #pragma unroll
                for (int r = 0; r < 4; r++)
                    *lgp(row + r, mi) = (_Float16)acc[i][j][r];
            }
        }
    }
    __syncthreads();
    if (wc >= 2) {
        #pragma unroll
        for (int i = 0; i < 8; i++) {
            const int row = wr * 128 + i * 16 + fg * 4;
            #pragma unroll
            for (int j = 0; j < 4; j++) {
                const int mi = (wc - 2) * 64 + j * 16 + fr;
                #pragma unroll
                for (int r = 0; r < 4; r++) {
                    float g = (float)*lgp(row + r, mi);
                    float sil = g / (1.f + __expf(-g));
                    *lgp(row + r, mi) = (_Float16)(sil * acc[i][j][r]);
                }
            }
        }
    }
    __syncthreads();
    #pragma unroll
    for (int pass = 0; pass < 8; pass++) {
        int cid = pass * 512 + tid;
        int row = cid >> 4, col8 = cid & 15;
        f16x8 v = *reinterpret_cast<const f16x8*>(
            ((row < 128) ? LgA : LgB) + (size_t)(row & 127) * 136 + col8 * 8);
        float wv = wdense[(size_t)e * 4096 + r0 + row];
        f16x8 o;
        #pragma unroll
        for (int j = 0; j < 8; j++) o[j] = (_Float16)((float)v[j] * wv);
        *reinterpret_cast<f16x8*>(ab + (size_t)(r0 + row) * 2048 + e * 128 + col8 * 8) = o;
    }
}

// ------------------------------------------- per-head RMSNorm + RoPE (wave-per-head)
__global__ __launch_bounds__(256) void k_qkv_post(
    const _Float16* __restrict__ qkv,
    const float* __restrict__ cosb, const float* __restrict__ sinb,
    const float* __restrict__ qn_w, const float* __restrict__ kn_w,
    _Float16* __restrict__ qh, _Float16* __restrict__ kh)
{
    const int tok = blockIdx.x;
    const int u = blockIdx.y * 4 + (threadIdx.x >> 6);
    const int lane = threadIdx.x & 63;
    const int b = tok >> 10, l = tok & 1023;
    const float SCL = 0.12752887074166638f;   // 1/sqrt(128) * log2(e)
    const float c0 = cosb[(size_t)tok * 128 + lane];
    const float c1 = cosb[(size_t)tok * 128 + lane + 64];
    const float s0 = sinb[(size_t)tok * 128 + lane];
    const float s1 = sinb[(size_t)tok * 128 + lane + 64];
    if (u < 32) {
        const _Float16* base = qkv + (size_t)tok * 5120 + u * 128;
        float v0 = (float)base[lane], v1 = (float)base[lane + 64];
        float ss = v0 * v0 + v1 * v1;
        #pragma unroll
        for (int m = 1; m < 64; m <<= 1) ss += __shfl_xor(ss, m);
        float rms = rsqrtf(ss * (1.f / 128.f) + 1e-6f);
        float n0 = v0 * rms * qn_w[lane], n1 = v1 * rms * qn_w[lane + 64];
        _Float16* o = qh + (size_t)tok * 4096 + u * 128;
        o[lane]      = (_Float16)(SCL * (c0 * n0 - s0 * n1));
        o[lane + 64] = (_Float16)(SCL * (c1 * n1 + s1 * n0));
    } else {
        const int kvh = u - 32;
        const _Float16* base = qkv + (size_t)tok * 5120 + 4096 + kvh * 128;
        float v0 = (float)base[lane], v1 = (float)base[lane + 64];
        float ss = v0 * v0 + v1 * v1;
        #pragma unroll
        for (int m = 1; m < 64; m <<= 1) ss += __shfl_xor(ss, m);
        float rms = rsqrtf(ss * (1.f / 128.f) + 1e-6f);
        float n0 = v0 * rms * kn_w[lane], n1 = v1 * rms * kn_w[lane + 64];
        _Float16* o = kh + (((size_t)(b * 4 + kvh)) * 1024 + l) * 128;
        o[lane]      = (_Float16)(c0 * n0 - s0 * n1);
        o[lane + 64] = (_Float16)(c1 * n1 + s1 * n0);
    }
}

// ---------------------------------------------------------------- V transpose
__global__ __launch_bounds__(256) void k_vt(
    const _Float16* __restrict__ qkv, _Float16* __restrict__ vth)
{
    const int bkv = blockIdx.x;
    const int b = bkv >> 2, kv = bkv & 3;
    const int l0 = blockIdx.y * 64, d0 = blockIdx.z * 64;
    __shared__ _Float16 T[64][72];
    const int t = threadIdx.x;
    const int r = t >> 3, c8 = (t & 7) * 8;
    #pragma unroll
    for (int rr = 0; rr < 2; rr++) {
        int l = l0 + r + rr * 32;
        *reinterpret_cast<f16x8*>(&T[r + rr * 32][c8]) =
            *reinterpret_cast<const f16x8*>(
                qkv + (size_t)(b * 1024 + l) * 5120 + 4608 + kv * 128 + d0 + c8);
    }
    __syncthreads();
    #pragma unroll
    for (int rr = 0; rr < 2; rr++) {
        int d = d0 + r + rr * 32;
        f16x8 v;
        #pragma unroll
        for (int j = 0; j < 8; j++) v[j] = T[c8 + j][r + rr * 32];
        *reinterpret_cast<f16x8*>(vth + ((size_t)(bkv * 128 + d)) * 1024 + l0 + c8) = v;
    }
}

// ---------------------------------------------------------------- attention
// 8 waves x 32 q-rows; fixed-max exp2 softmax; dbuf K/V; l via ones-column.
__global__ __launch_bounds__(512) void k_attn(
    const _Float16* __restrict__ qh, const _Float16* __restrict__ kh,
    const _Float16* __restrict__ vth, const _Float16* __restrict__ ones16,
    _Float16* __restrict__ oh)
{
    const int bh = blockIdx.x;
    const int qb = 3 - blockIdx.y;
    const int b = bh >> 5, h = bh & 31, kv = h >> 3;
    const int tid = threadIdx.x, lane = tid & 63, wid = tid >> 6;
    const int fr = lane & 15, fg = lane >> 4;
    const int q0w = qb * 256 + wid * 32;

    __shared__ __align__(16) _Float16 Ks[2][64][128];
    __shared__ __align__(16) _Float16 Vs[2][128][64];
    __shared__ __align__(16) _Float16 Vones[16][64];
    __shared__ __align__(16) _Float16 Ps[8][32][72];

    const _Float16* kb = kh + ((size_t)(b * 4 + kv)) * 1024 * 128;
    const _Float16* vb = vth + ((size_t)(b * 4 + kv)) * 128 * 1024;

    auto stage = [&](int nb, int key0) {
        #pragma unroll
        for (int i = 0; i < 2; i++) {
            int rr = wid * 8 + i * 4 + (lane >> 4);
            int c16 = (lane & 15) ^ (rr & 15);
            load16_lds(kb + (size_t)(key0 + rr) * 128 + c16 * 8,
                       &Ks[nb][0][0] + (wid * 8 + i * 4) * 128);
        }
        #pragma unroll
        for (int i = 0; i < 2; i++) {
            int rr = wid * 16 + i * 8 + (lane >> 3);
            int c16 = (lane & 7) ^ (rr & 7);
            load16_lds(vb + (size_t)rr * 1024 + key0 + c16 * 8,
                       &Vs[nb][0][0] + (wid * 16 + i * 8) * 64);
        }
    };

    f16x8 aq[2][4];
    #pragma unroll
    for (int mi = 0; mi < 2; mi++) {
        const _Float16* qbase =
            qh + ((size_t)(b * 1024 + q0w + mi * 16 + fr)) * 4096 + h * 128;
        #pragma unroll
        for (int kk = 0; kk < 4; kk++)
            aq[mi][kk] = *reinterpret_cast<const f16x8*>(qbase + kk * 32 + fg * 8);
    }
    if (wid == 0) {
        #pragma unroll
        for (int i = 0; i < 2; i++)
            load16_lds(ones16 + (size_t)(lane + i * 64) * 8, &Vones[0][0] + i * 512);
    }
    stage(0, 0);

    const f32x4 z4 = { 0.f, 0.f, 0.f, 0.f };
    f32x4 oacc[2][9];
    #pragma unroll
    for (int mi = 0; mi < 2; mi++)
        #pragma unroll
        for (int dj = 0; dj < 9; dj++) oacc[mi][dj] = z4;

    const int ntiles = qb * 4 + 4;
    int cb = 0;
    for (int kt = 0; kt < ntiles; kt++) {
        const int key0 = kt * 64;
        asm volatile("s_waitcnt vmcnt(0)" ::: "memory");
        __builtin_amdgcn_s_barrier();
        if (kt + 1 < ntiles) stage(cb ^ 1, key0 + 64);

        if (key0 <= q0w + 31) {
            f32x4 sc[2][4];
            #pragma unroll
            for (int mi = 0; mi < 2; mi++)
                #pragma unroll
                for (int j = 0; j < 4; j++) sc[mi][j] = z4;
            #pragma unroll
            for (int j = 0; j < 4; j++)
                #pragma unroll
                for (int kk = 0; kk < 4; kk++) {
                    f16x8 bk = *reinterpret_cast<const f16x8*>(
                        &Ks[cb][0][0] + (j * 16 + fr) * 128 + (((kk * 4 + fg) ^ fr) * 8));
                    #pragma unroll
                    for (int mi = 0; mi < 2; mi++)
                        sc[mi][j] = __builtin_amdgcn_mfma_f32_16x16x32_f16(
                            aq[mi][kk], bk, sc[mi][j], 0, 0, 0);
                }

            const bool maskt = (key0 + 63 > q0w);
            #pragma unroll
            for (int mi = 0; mi < 2; mi++)
                #pragma unroll
                for (int j = 0; j < 4; j++) {
                    const int key = key0 + j * 16 + fr;
                    #pragma unroll
                    for (int r = 0; r < 4; r++) {
                        float v = sc[mi][j][r];
                        if (maskt && key > q0w + mi * 16 + fg * 4 + r) v = -1e30f;
                        Ps[wid][mi * 16 + fg * 4 + r][j * 16 + fr] =
                            (_Float16)__builtin_amdgcn_exp2f(v - 8.f);
                    }
                }

            #pragma unroll
            for (int ks = 0; ks < 2; ks++) {
                f16x8 ap0 = *reinterpret_cast<const f16x8*>(
                    &Ps[wid][fr][ks * 32 + fg * 8]);
                f16x8 ap1 = *reinterpret_cast<const f16x8*>(
                    &Ps[wid][16 + fr][ks * 32 + fg * 8]);
                #pragma unroll
                for (int dj = 0; dj < 8; dj++) {
                    f16x8 bv = *reinterpret_cast<const f16x8*>(
                        &Vs[cb][0][0] + (dj * 16 + fr) * 64 + (((ks * 4 + fg) ^ (fr & 7)) * 8));
                    oacc[0][dj] = __builtin_amdgcn_mfma_f32_16x16x32_f16(ap0, bv, oacc[0][dj], 0, 0, 0);
                    oacc[1][dj] = __builtin_amdgcn_mfma_f32_16x16x32_f16(ap1, bv, oacc[1][dj], 0, 0, 0);
                }
                f16x8 bo = *reinterpret_cast<const f16x8*>(
                    &Vones[0][0] + fr * 64 + (((ks * 4 + fg) ^ (fr & 7)) * 8));
                oacc[0][8] = __builtin_amdgcn_mfma_f32_16x16x32_f16(ap0, bo, oacc[0][8], 0, 0, 0);
                oacc[1][8] = __builtin_amdgcn_mfma_f32_16x16x32_f16(ap1, bo, oacc[1][8], 0, 0, 0);
            }
        }
        cb ^= 1;
    }

    #pragma unroll
    for (int mi = 0; mi < 2; mi++) {
        float inv[4];
        #pragma unroll
        for (int r = 0; r < 4; r++) {
            float l = __shfl(oacc[mi][8][r], lane & 48);
            inv[r] = 1.f / l;
        }
        #pragma unroll
        for (int dj = 0; dj < 8; dj++)
            #pragma unroll
            for (int r = 0; r < 4; r++)
                oh[((size_t)(b * 1024 + q0w + mi * 16 + fg * 4 + r)) * 4096
                   + h * 128 + dj * 16 + fr] = (_Float16)(oacc[mi][dj][r] * inv[r]);
    }
}

// ---------------------------------------------------------------- router (inline rmsnorm from x2)
__global__ __launch_bounds__(256) void k_router(
    const float* __restrict__ x2, const float* __restrict__ wm,
    const float* __restrict__ rw, float* __restrict__ wdense)
{
    const int tok = blockIdx.x * 4 + (threadIdx.x >> 6);
    const int lane = threadIdx.x & 63;
    __shared__ float lg[4][16];
    const float* hr = x2 + (size_t)tok * 2048;
    float vals[32];
    float ss = 0.f;
    #pragma unroll
    for (int i = 0; i < 32; i++) { float v = hr[i * 64 + lane]; vals[i] = v; ss += v * v; }
    #pragma unroll
    for (int m = 1; m < 64; m <<= 1) ss += __shfl_xor(ss, m);
    float r = rsqrtf(ss * (1.f / 2048.f) + 1e-6f);
    #pragma unroll
    for (int i = 0; i < 32; i++) vals[i] *= r * wm[i * 64 + lane];
    for (int e = 0; e < 16; e++) {
        float acc = 0.f;
        #pragma unroll
        for (int i = 0; i < 32; i++) acc += vals[i] * rw[(size_t)e * 2048 + i * 64 + lane];
        #pragma unroll
        for (int m = 1; m < 64; m <<= 1) acc += __shfl_xor(acc, m);
        if (lane == 0) lg[threadIdx.x >> 6][e] = acc;
    }
    __syncthreads();
    if (lane == 0) {
        float* l = lg[threadIdx.x >> 6];
        float mx = l[0];
        for (int e = 1; e < 16; e++) mx = fmaxf(mx, l[e]);
        float p[16]; float sum = 0.f;
        for (int e = 0; e < 16; e++) { p[e] = expf(l[e] - mx); sum += p[e]; }
        for (int e = 0; e < 16; e++) p[e] /= sum;
        bool sel[16]; for (int e = 0; e < 16; e++) sel[e] = false;
        float ssum = 0.f;
        for (int t = 0; t < 8; t++) {
            int bi = -1; float bv = -1.f;
            for (int e = 0; e < 16; e++) if (!sel[e] && p[e] > bv) { bv = p[e]; bi = e; }
            sel[bi] = true; ssum += bv;
        }
        for (int e = 0; e < 16; e++)
            wdense[(size_t)e * 4096 + tok] = sel[e] ? p[e] / ssum : 0.f;
    }
}

// ---------------------------------------------------------------- launch

extern "C" void kernel_launch(void* const* d_in, const int* in_sizes, int n_in,
                              void* d_out, int out_size, void* d_ws, size_t ws_size,
                              hipStream_t stream)
{
    const float* x        = (const float*)d_in[0];
    const float* cosb     = (const float*)d_in[1];
    const float* sinb     = (const float*)d_in[2];
    const float* nattn    = (const float*)d_in[3];
    const float* q_w      = (const float*)d_in[4];
    const float* k_w      = (const float*)d_in[5];
    const float* v_w      = (const float*)d_in[6];
    const float* qn_w     = (const float*)d_in[7];
    const float* kn_w     = (const float*)d_in[8];
    const float* o_w      = (const float*)d_in[9];
    const float* nmlp     = (const float*)d_in[10];
    const float* router_w = (const float*)d_in[11];
    const float* egw      = (const float*)d_in[12];
    const float* euw      = (const float*)d_in[13];
    const float* edw      = (const float*)d_in[14];

    char* w = (char*)d_ws;
    _Float16* qkvw_h = (_Float16*)(w + 0);          // 20.97 MB
    _Float16* ow_h   = (_Float16*)(w + 20971520);   // 16.78 MB
    _Float16* guw_h  = (_Float16*)(w + 37748736);   // 16.78 MB
    _Float16* dwc_h  = (_Float16*)(w + 54525952);   //  8.39 MB
    _Float16* h_h    = (_Float16*)(w + 62914560);   // 16.78 MB (aliased hm_h)
    _Float16* hm_h   = h_h;
    float*    x2     = (float*)(w + 79691776);      // 33.55 MB
    _Float16* qkv_h  = (_Float16*)(w + 113246208);  // 41.94 MB (alias o_h, ab_h)
    _Float16* o_h    = qkv_h;
    _Float16* ab_h   = qkv_h;
    _Float16* q_h    = (_Float16*)(w + 155189248);  // 33.55 MB
    _Float16* k_h    = (_Float16*)(w + 188743680);  //  4.19 MB
    _Float16* vt_h   = (_Float16*)(w + 192937984);  //  4.19 MB
    float*    wdense = (float*)(w + 197132288);     //  0.26 MB
    _Float16* ones_h = (_Float16*)(w + 197394432);  //  2 KB (16x64 f16)

    k_cast4<<<18432, 256, 0, stream>>>(q_w, k_w, v_w, o_w, qkvw_h, ow_h);
    k_cast_guw<<<4097, 256, 0, stream>>>(egw, euw, guw_h, ones_h);
    k_cast_dw<<<4096, 256, 0, stream>>>(edw, dwc_h);

    k_rmsnorm<<<4096, 256, 0, stream>>>(x, nattn, h_h);
    k_gemm8<<<dim3(16, 16), 512, 0, stream>>>(h_h, 2048, qkvw_h, 2048, qkv_h, 5120, 2048,
                                              nullptr, nullptr);
    k_gemm<<<dim3(32, 8), 256, 0, stream>>>(h_h, 2048, qkvw_h + (size_t)4096 * 2048, 2048,
                                            nullptr, qkv_h + 4096, 5120, nullptr, 2048);
    k_qkv_post<<<dim3(4096, 9), 256, 0, stream>>>(qkv_h, cosb, sinb, qn_w, kn_w, q_h, k_h);
    k_vt<<<dim3(16, 16, 2), 256, 0, stream>>>(qkv_h, vt_h);
    k_attn<<<dim3(128, 4), 512, 0, stream>>>(q_h, k_h, vt_h, ones_h, o_h);
    // O-proj + residual (128x256-tile 4-wave kernel, grid 256 blocks)
    k_gemmw<<<dim3(32, 8), 256, 0, stream>>>(o_h, 4096, ow_h, 4096, x2, 2048, x, 4096);
    k_rmsnorm<<<4096, 256, 0, stream>>>(x2, nmlp, hm_h);
    k_router<<<1024, 256, 0, stream>>>(x2, nmlp, router_w, wdense);
    k_gemm8<<<dim3(16, 16), 512, 0, stream>>>(hm_h, 2048, guw_h, 2048, nullptr, 0, 2048,
                                              wdense, ab_h);
    // MoE down + residual
    k_gemmw<<<dim3(32, 8), 256, 0, stream>>>(ab_h, 2048, dwc_h, 2048,
                                             (float*)d_out, 2048, x2, 2048);

    (void)in_sizes; (void)n_in; (void)out_size; (void)ws_size;
}